// Round 7
// baseline (922.780 us; speedup 1.0000x reference)
//
#include <hip/hip_runtime.h>
#include <hip/hip_bf16.h>
#include <cstdint>
#include <cstddef>

#define H 512
#define NFEAT 1024
#define BATCH 16384

using bf16 = __hip_bfloat16;
using bf16x8 = __attribute__((ext_vector_type(8))) __bf16;
using f32x4 = __attribute__((ext_vector_type(4))) float;
using f32x16 = __attribute__((ext_vector_type(16))) float;

// ---------------------------------------------------------------------------
// async global -> LDS, 16 bytes per lane
// ---------------------------------------------------------------------------
__device__ __forceinline__ void gload16(void* lds, const void* g) {
  __builtin_amdgcn_global_load_lds(
      (__attribute__((address_space(1))) void*)g,
      (__attribute__((address_space(3))) void*)lds,
      16, 0, 0);
}

// ---------------------------------------------------------------------------
// prep: per matrix, compute a[], b[] for core = diag(d) + a*1^T + b*u^T
// Closed-form Cayley (rank-2 Woodbury), verified R0-R6.
// ---------------------------------------------------------------------------
__global__ void prep_kernel(const float* __restrict__ er, const float* __restrict__ ed,
                            const float* __restrict__ dr, const float* __restrict__ dd,
                            float* __restrict__ ab) {
  const int mat = blockIdx.x;          // 0..7
  const int lane = threadIdx.x;        // 0..63
  const float* u = (mat < 4) ? (er + mat * H) : (dr + (mat - 4) * H);
  const float* d = (mat < 4) ? (ed + mat * H) : (dd + (mat - 4) * H);

  double s = 0.0, q = 0.0;
  for (int k = 0; k < 8; ++k) {
    double v = (double)u[lane + 64 * k];
    s += v;
    q += v * v;
  }
  for (int off = 32; off; off >>= 1) {
    s += __shfl_down(s, off);
    q += __shfl_down(q, off);
  }
  s = __shfl(s, 0);
  q = __shfl(q, 0);

  const double det = 1.0 - s * s + (double)H * q;
  const double cuv = 2.0 * (1.0 + s) / det;
  const double cuu = -2.0 * (double)H / det;
  const double cvv = -2.0 * q / det;
  const double cvu = -2.0 * (1.0 - s) / det;

  float* a = ab + mat * 1024;
  float* b = a + H;
  for (int k = 0; k < 8; ++k) {
    int idx = lane + 64 * k;
    double ui = (double)u[idx], di = (double)d[idx];
    a[idx] = (float)(di * (cuv * ui + cvv));
    b[idx] = (float)(di * (cuu * ui + cvu));
  }
}

// ---------------------------------------------------------------------------
// prep2: stride-4-residue inclusive prefix tables over a, a_rev, d, d_rev.
// ---------------------------------------------------------------------------
__global__ __launch_bounds__(256) void prep2_kernel(
    const float* __restrict__ er, const float* __restrict__ ed,
    const float* __restrict__ dr, const float* __restrict__ dd,
    const float* __restrict__ ab, float* __restrict__ Tpref) {
  __shared__ float buf[4][512];
  __shared__ float tmp[4][512];
  const int mat = blockIdx.x;
  const float* d = (mat < 4) ? (ed + mat * H) : (dd + (mat - 4) * H);
  const float* a = ab + mat * 1024;
  const int t = threadIdx.x;
  for (int m = t; m < 512; m += 256) {
    buf[0][m] = a[m];
    buf[1][m] = a[511 - m];
    buf[2][m] = d[m];
    buf[3][m] = d[511 - m];
  }
  __syncthreads();
  for (int s = 4; s <= 256; s <<= 1) {
    for (int m = t; m < 512; m += 256)
#pragma unroll
      for (int q = 0; q < 4; ++q) tmp[q][m] = (m >= s) ? buf[q][m - s] : 0.f;
    __syncthreads();
    for (int m = t; m < 512; m += 256)
#pragma unroll
      for (int q = 0; q < 4; ++q) buf[q][m] += tmp[q][m];
    __syncthreads();
  }
  float* tp = Tpref + mat * 2048;
  for (int m = t; m < 512; m += 256) {
    tp[m] = buf[0][m];
    tp[512 + m] = buf[1][m];
    tp[1024 + m] = buf[2][m];
    tp[1536 + m] = buf[3][m];
  }
}

// ---------------------------------------------------------------------------
// build v3 (unchanged from R2): prefix tables + quad b*u loop.
// ---------------------------------------------------------------------------
__global__ __launch_bounds__(256) void build_kernel(
    const float* __restrict__ er, const float* __restrict__ ed,
    const float* __restrict__ dr, const float* __restrict__ dd,
    const float* __restrict__ ab, const float* __restrict__ Tpref,
    bf16* __restrict__ Lh, bf16* __restrict__ Ll) {
  __shared__ __align__(16) float arr4[4][520];
  __shared__ __align__(16) float4 up[132];
  __shared__ float pa[512], parev[512], pd[512], pdrev[512], sdl[512];

  const int i = blockIdx.x;
  const int mat = blockIdx.y;
  const float* u = (mat < 4) ? (er + mat * H) : (dr + (mat - 4) * H);
  const float* d = (mat < 4) ? (ed + mat * H) : (dd + (mat - 4) * H);
  const float* a = ab + mat * 1024;
  const float* b = a + H;
  const float* tp = Tpref + mat * 2048;
  const int t = threadIdx.x;

  for (int m = t; m < 520; m += 256) {
    arr4[0][m] = (m < 512) ? u[m] : 0.f;
    arr4[1][m] = (m >= 1 && m <= 512) ? b[m - 1] : 0.f;
    arr4[2][m] = (m >= 2 && m <= 513) ? u[513 - m] : 0.f;
    arr4[3][m] = (m >= 3 && m <= 514) ? b[514 - m] : 0.f;
  }
  for (int m = t; m < 512; m += 256) {
    pa[m] = tp[m];
    parev[m] = tp[512 + m];
    pd[m] = tp[1024 + m];
    pdrev[m] = tp[1536 + m];
    sdl[m] = d[m];
  }
  if (t < 132) {
    const int k4 = 4 * t;
    float4 v;
    int p0 = i - k4;
    v.x = (p0 >= 0 && p0 < 512) ? b[p0] : 0.f;
    int p1 = i - k4 - 1;
    v.y = (p1 >= 0 && p1 < 512) ? u[511 - p1] : 0.f;
    int p2 = i - k4 - 2;
    v.z = (p2 >= 0 && p2 < 512) ? b[511 - p2] : 0.f;
    int p3 = i - k4 - 3;
    v.w = (p3 >= 0 && p3 < 512) ? u[p3] : 0.f;
    up[t] = v;
  }
  __syncthreads();

  const float* upf = (const float*)up;
  const int j0 = t * 4;

  int lo_[4], hi_[4];
#pragma unroll
  for (int c = 0; c < 4; ++c) {
    const int jc = j0 + c;
    lo_[c] = max(0, max(i, jc) - 511);
    hi_[c] = min(512, min(i, jc));
  }
  const int CL = lo_[3];
  const int CH = hi_[0];

  float acc[4] = {0.f, 0.f, 0.f, 0.f};

#pragma unroll
  for (int c = 0; c < 4; ++c) {
    const int jc = j0 + c;
    const int lo = lo_[c], hi = hi_[c];
    if (lo > hi) continue;
    float v = 0.f;
    {
      int o1 = lo + ((0 - lo) & 3), o2 = hi - ((hi - 0) & 3);
      if (o1 <= o2) { int mx = i - o1, mn = i - o2; v += pa[mx] - (mn >= 4 ? pa[mn - 4] : 0.f); }
    }
    {
      int o1 = lo + ((1 - lo) & 3), o2 = hi - ((hi - 1) & 3);
      if (o1 <= o2) { int mx = jc - o1, mn = jc - o2; v += pa[mx] - (mn >= 4 ? pa[mn - 4] : 0.f); }
    }
    {
      int o1 = lo + ((2 - lo) & 3), o2 = hi - ((hi - 2) & 3);
      if (o1 <= o2) { int mx = i - o1, mn = i - o2; v += parev[mx] - (mn >= 4 ? parev[mn - 4] : 0.f); }
    }
    {
      int o1 = lo + ((3 - lo) & 3), o2 = hi - ((hi - 3) & 3);
      if (o1 <= o2) { int mx = jc - o1, mn = jc - o2; v += parev[mx] - (mn >= 4 ? parev[mn - 4] : 0.f); }
    }
    if (i == jc) {
      {
        int o1 = lo + ((0 - lo) & 3), o2 = hi - ((hi - 0) & 3);
        if (o1 <= o2) { int mx = i - o1, mn = i - o2; v += pd[mx] - (mn >= 4 ? pd[mn - 4] : 0.f); }
      }
      {
        int o1 = lo + ((2 - lo) & 3), o2 = hi - ((hi - 2) & 3);
        if (o1 <= o2) { int mx = i - o1, mn = i - o2; v += pdrev[mx] - (mn >= 4 ? pdrev[mn - 4] : 0.f); }
      }
    }
    const int m2 = i + jc - 511;
    if (m2 >= 0 && !(m2 & 1)) {
      const int os = m2 >> 1;
      if (os >= lo && os <= hi) {
        const int r = os & 3;
        if (r == 1) v += sdl[jc - os];
        else if (r == 3) v += sdl[511 - (jc - os)];
      }
    }
    acc[c] = v;
  }

  if (CL > CH) {
#pragma unroll
    for (int c = 0; c < 4; ++c) {
      const int jc = j0 + c;
      for (int o = lo_[c]; o <= hi_[c]; ++o) {
        const int r = o & 3;
        acc[c] += upf[o] * arr4[r][jc - o + r];
      }
    }
  } else {
#pragma unroll
    for (int c = 0; c < 4; ++c) {
      const int jc = j0 + c;
      const int he = min(hi_[c], CL - 1);
      for (int o = lo_[c]; o <= he; ++o) {
        const int r = o & 3;
        acc[c] += upf[o] * arr4[r][jc - o + r];
      }
      const int ls = max(lo_[c], CH + 1);
      for (int o = ls; o <= hi_[c]; ++o) {
        const int r = o & 3;
        acc[c] += upf[o] * arr4[r][jc - o + r];
      }
    }
    const int QL = (CL + 3) & ~3;
    for (int o = CL; o < QL && o <= CH; ++o) {
      const int r = o & 3;
      const float uvv = upf[o];
      const float4 wv = *(const float4*)&arr4[r][j0 - o + r];
      acc[0] += uvv * wv.x; acc[1] += uvv * wv.y;
      acc[2] += uvv * wv.z; acc[3] += uvv * wv.w;
    }
    int ob = QL;
    for (; ob + 3 <= CH; ob += 4) {
      const float4 uv = up[ob >> 2];
      const int x = j0 - ob;
      const float4 w0 = *(const float4*)&arr4[0][x];
      const float4 w1 = *(const float4*)&arr4[1][x];
      const float4 w2 = *(const float4*)&arr4[2][x];
      const float4 w3 = *(const float4*)&arr4[3][x];
      acc[0] += uv.x * w0.x + uv.y * w1.x + uv.z * w2.x + uv.w * w3.x;
      acc[1] += uv.x * w0.y + uv.y * w1.y + uv.z * w2.y + uv.w * w3.y;
      acc[2] += uv.x * w0.z + uv.y * w1.z + uv.z * w2.z + uv.w * w3.z;
      acc[3] += uv.x * w0.w + uv.y * w1.w + uv.z * w2.w + uv.w * w3.w;
    }
    for (int o = ob; o <= CH; ++o) {
      const int r = o & 3;
      const float uvv = upf[o];
      const float4 wv = *(const float4*)&arr4[r][j0 - o + r];
      acc[0] += uvv * wv.x; acc[1] += uvv * wv.y;
      acc[2] += uvv * wv.z; acc[3] += uvv * wv.w;
    }
  }

  const size_t off = ((size_t)mat << 20) + ((size_t)i << 10) + (size_t)j0;
  union { bf16 v[4]; ushort4 s; } Hu, Lu;
#pragma unroll
  for (int c = 0; c < 4; ++c) {
    const bf16 hb = __float2bfloat16(acc[c]);
    Hu.v[c] = hb;
    Lu.v[c] = __float2bfloat16(acc[c] - __bfloat162float(hb));
  }
  *(ushort4*)(Lh + off) = Hu.s;
  *(ushort4*)(Ll + off) = Lu.s;
}

// ---------------------------------------------------------------------------
// split fp32 -> (hi, lo) bf16
// ---------------------------------------------------------------------------
__global__ void split_kernel(const float* __restrict__ x, bf16* __restrict__ h,
                             bf16* __restrict__ l) {
  const int n4 = BATCH * NFEAT / 4;
  int idx = blockIdx.x * blockDim.x + threadIdx.x;
  int stride = gridDim.x * blockDim.x;
  for (int i = idx; i < n4; i += stride) {
    float4 v = ((const float4*)x)[i];
    float vv[4] = {v.x, v.y, v.z, v.w};
    union { bf16 b[4]; short4 s; } Hu, Lu;
#pragma unroll
    for (int c = 0; c < 4; ++c) {
      bf16 hb = __float2bfloat16(vv[c]);
      Hu.b[c] = hb;
      Lu.b[c] = __float2bfloat16(vv[c] - __bfloat162float(hb));
    }
    ((short4*)h)[i] = Hu.s;
    ((short4*)l)[i] = Lu.s;
  }
}

// ---------------------------------------------------------------------------
// split-bf16 GEMM v5:  Y[r][c] = sum_k S[r][k] * L[c][k]  (Y = S @ L^T)
// acc += Ah*Bh + Ah*Bl + Al*Bh (fp32 accum).
// 256x256 tile, BK=32, 8 waves (2Mx4N, wave 128x64), mfma_f32_32x32x16.
// v5 schedule: 2 phases/tile, ALL 8 stage-gloads issued at phase 0 (dest
// buffer free from tile start) so the tile-end vmcnt(0) waits on loads
// ~2 phases (~2000 cyc) old -> near-zero drain. B-fragments held in
// registers across both phases. Raw s_barrier + setprio(1) MFMA clusters.
// XCD swizzle: XCD x <- col-block x>>1, rows ((x&1)*32 + chunk): per-XCD
// B-panel (1 MB) L2-resident, A streamed exactly once.
// MODE bit0: write fp32 Yf; bit1: write split (Yh, Yl)
// ---------------------------------------------------------------------------
template <int MODE>
__global__ __launch_bounds__(512, 2) void gemm3_kernel(
    const bf16* __restrict__ Ah, const bf16* __restrict__ Al,
    const bf16* __restrict__ Bh, const bf16* __restrict__ Bl,
    float* __restrict__ Yf, bf16* __restrict__ Yh, bf16* __restrict__ Yl) {
  __shared__ __align__(16) bf16 smem[2 * 4 * 8192];  // 128 KiB

  const int tid = threadIdx.x;   // 0..511
  const int lane = tid & 63;
  const int wave = tid >> 6;     // 0..7
  const int wr = wave >> 2;      // 0..1 : 128-row half
  const int wc = wave & 3;       // 0..3 : 64-col quarter

  // XCD-aware bijective swizzle: grid (64,4) -> 256 blocks, 8 XCDs.
  // XCD x = pdisp&7 handles col-block x>>1, row-blocks (x&1)*32 + chunk.
  const int pdisp = blockIdx.x + (blockIdx.y << 6);
  const int xcd = pdisp & 7;
  const int chk = pdisp >> 3;            // 0..31
  const int row0 = ((((xcd & 1) << 5) | chk)) * 256;
  const int col0 = (xcd >> 1) * 256;

  // staging: per K-tile, per array: 2 gload16/thread (rows q*128 + tid>>2)
  const int gsrc = (tid & 3) ^ ((tid >> 3) & 3);   // inverse-swizzled src granule
  const int dst = tid * 8;                          // linear dest elems (+q*4096)
  const size_t abase = (size_t)(row0 + (tid >> 2)) * NFEAT + gsrc * 8;
  const size_t bbase = (size_t)(col0 + (tid >> 2)) * NFEAT + gsrc * 8;

  auto STAGE2 = [&](int nb, int arr, const bf16* __restrict__ src, size_t base, int k0) {
    bf16* d = smem + nb * 32768 + arr * 8192 + dst;
    gload16(d, src + base + k0);
    gload16(d + 4096, src + base + 131072 + k0);   // +128 rows
  };

  // frag-read byte offsets: row r, k-step ks, k-half hb
  const int l31 = lane & 31;
  const int hb = lane >> 5;
  int aoffB[4][2], boffB[2][2];
#pragma unroll
  for (int m = 0; m < 4; ++m) {
    const int r = wr * 128 + m * 32 + l31;
#pragma unroll
    for (int ks = 0; ks < 2; ++ks)
      aoffB[m][ks] = r * 64 + ((((ks << 1) | hb) ^ ((r >> 1) & 3)) << 4);
  }
#pragma unroll
  for (int n = 0; n < 2; ++n) {
    const int r = wc * 64 + n * 32 + l31;
#pragma unroll
    for (int ks = 0; ks < 2; ++ks)
      boffB[n][ks] = r * 64 + ((((ks << 1) | hb) ^ ((r >> 1) & 3)) << 4);
  }

  auto LD = [](const char* base, int off) { return *(const bf16x8*)(base + off); };
  auto TRIPLE = [](f32x16& ac, bf16x8 ah, bf16x8 al, bf16x8 bh, bf16x8 bl) {
    ac = __builtin_amdgcn_mfma_f32_32x32x16_bf16(ah, bh, ac, 0, 0, 0);
    ac = __builtin_amdgcn_mfma_f32_32x32x16_bf16(ah, bl, ac, 0, 0, 0);
    ac = __builtin_amdgcn_mfma_f32_32x32x16_bf16(al, bh, ac, 0, 0, 0);
  };

  f32x16 acc[4][2] = {};

  // prologue: stage tile 0 into buffer 0
  STAGE2(0, 0, Ah, abase, 0);
  STAGE2(0, 1, Al, abase, 0);
  STAGE2(0, 2, Bh, bbase, 0);
  STAGE2(0, 3, Bl, bbase, 0);
  asm volatile("s_waitcnt vmcnt(0)" ::: "memory");
  __builtin_amdgcn_s_barrier();

  for (int t = 0; t < 32; ++t) {
    const int buf = t & 1;
    const int nb = buf ^ 1;
    const int k1 = (t + 1) * 32;
    const char* pAh = (const char*)(smem + buf * 32768);
    const char* pAl = pAh + 16384;
    const char* pBh = pAh + 32768;
    const char* pBl = pAh + 49152;
    const bool pf = (t < 31);

    bf16x8 gah[2][2], gal[2][2], fbh[2][2], fbl[2][2];

    // ---- Phase 0: issue ALL stages for t+1; read A m0/m1 + all B; MFMA ----
    if (pf) {
      STAGE2(nb, 0, Ah, abase, k1);
      STAGE2(nb, 1, Al, abase, k1);
      STAGE2(nb, 2, Bh, bbase, k1);
      STAGE2(nb, 3, Bl, bbase, k1);
    }
#pragma unroll
    for (int mi = 0; mi < 2; ++mi)
#pragma unroll
      for (int ks = 0; ks < 2; ++ks) {
        gah[mi][ks] = LD(pAh, aoffB[mi][ks]);
        gal[mi][ks] = LD(pAl, aoffB[mi][ks]);
      }
#pragma unroll
    for (int n = 0; n < 2; ++n)
#pragma unroll
      for (int ks = 0; ks < 2; ++ks) {
        fbh[n][ks] = LD(pBh, boffB[n][ks]);
        fbl[n][ks] = LD(pBl, boffB[n][ks]);
      }
    __builtin_amdgcn_s_barrier();
    __builtin_amdgcn_s_setprio(1);
#pragma unroll
    for (int ks = 0; ks < 2; ++ks)
#pragma unroll
      for (int mi = 0; mi < 2; ++mi)
#pragma unroll
        for (int n = 0; n < 2; ++n)
          TRIPLE(acc[mi][n], gah[mi][ks], gal[mi][ks], fbh[n][ks], fbl[n][ks]);
    __builtin_amdgcn_s_setprio(0);
    __builtin_amdgcn_s_barrier();

    // ---- Phase 1: read A m2/m3; MFMA with cached B frags ----
#pragma unroll
    for (int mi = 0; mi < 2; ++mi)
#pragma unroll
      for (int ks = 0; ks < 2; ++ks) {
        gah[mi][ks] = LD(pAh, aoffB[2 + mi][ks]);
        gal[mi][ks] = LD(pAl, aoffB[2 + mi][ks]);
      }
    __builtin_amdgcn_s_barrier();
    __builtin_amdgcn_s_setprio(1);
#pragma unroll
    for (int ks = 0; ks < 2; ++ks)
#pragma unroll
      for (int mi = 0; mi < 2; ++mi)
#pragma unroll
        for (int n = 0; n < 2; ++n)
          TRIPLE(acc[2 + mi][n], gah[mi][ks], gal[mi][ks], fbh[n][ks], fbl[n][ks]);
    __builtin_amdgcn_s_setprio(0);
    // next buffer must be fully staged before swap; loads are ~2 phases old
    if (pf) asm volatile("s_waitcnt vmcnt(0)" ::: "memory");
    __builtin_amdgcn_s_barrier();
  }

  // epilogue: 32x32 C/D layout: col = lane&31, row = (r&3)+8*(r>>2)+4*(lane>>5)
  const int ocol0 = col0 + wc * 64 + l31;
  const int rb = (lane >> 5) << 2;
#pragma unroll
  for (int m = 0; m < 4; ++m)
#pragma unroll
    for (int n = 0; n < 2; ++n)
#pragma unroll
      for (int r = 0; r < 16; ++r) {
        const int grow = row0 + wr * 128 + m * 32 + (r & 3) + ((r >> 2) << 3) + rb;
        const int gcol = ocol0 + n * 32;
        const size_t off = (size_t)grow * NFEAT + (size_t)gcol;
        const float v = acc[m][n][r];
        if (MODE & 1) Yf[off] = v;
        if (MODE & 2) {
          bf16 hbv = __float2bfloat16(v);
          Yh[off] = hbv;
          Yl[off] = __float2bfloat16(v - __bfloat162float(hbv));
        }
      }
}

// ---------------------------------------------------------------------------
// launch
// ---------------------------------------------------------------------------
extern "C" void kernel_launch(void* const* d_in, const int* in_sizes, int n_in,
                              void* d_out, int out_size, void* d_ws, size_t ws_size,
                              hipStream_t stream) {
  (void)in_sizes; (void)n_in; (void)out_size; (void)ws_size;
  const float* x  = (const float*)d_in[0];
  const float* er = (const float*)d_in[1];
  const float* ed = (const float*)d_in[2];
  const float* dr = (const float*)d_in[3];
  const float* dd = (const float*)d_in[4];

  float* O0 = (float*)d_out;                       // bottleneck (fp32, 64 MB)
  float* O1 = O0 + (size_t)BATCH * NFEAT;          // out (fp32, 64 MB)

  // d_ws layout: Lh (16MB) | Ll (16MB) | ab (32KB) | Ph (32MB) | Pl (32MB)
  bf16* Lh = (bf16*)d_ws;
  bf16* Ll = Lh + ((size_t)8 << 20);
  float* ab = (float*)(Ll + ((size_t)8 << 20));
  bf16* Ph = (bf16*)(ab + 8 * 1024);
  bf16* Pl = Ph + (size_t)BATCH * NFEAT;
  // Tpref (64KB) at start of d_out: consumed by build, overwritten by layer 4.
  float* Tpref = O0;
  // d_out second half doubles as bf16 hi/lo ping buffer until layer 8 overwrites it
  bf16* Qh = (bf16*)O1;
  bf16* Ql = Qh + (size_t)BATCH * NFEAT;

  prep_kernel<<<8, 64, 0, stream>>>(er, ed, dr, dd, ab);
  prep2_kernel<<<8, 256, 0, stream>>>(er, ed, dr, dd, ab, Tpref);
  build_kernel<<<dim3(1024, 8), 256, 0, stream>>>(er, ed, dr, dd, ab, Tpref, Lh, Ll);
  split_kernel<<<4096, 256, 0, stream>>>(x, Qh, Ql);

  const dim3 g(64, 4);
  const size_t LM = (size_t)1 << 20;
  // encoder
  gemm3_kernel<2><<<g, 512, 0, stream>>>(Qh, Ql, Lh + 0 * LM, Ll + 0 * LM, nullptr, Ph, Pl);
  gemm3_kernel<2><<<g, 512, 0, stream>>>(Ph, Pl, Lh + 1 * LM, Ll + 1 * LM, nullptr, Qh, Ql);
  gemm3_kernel<2><<<g, 512, 0, stream>>>(Qh, Ql, Lh + 2 * LM, Ll + 2 * LM, nullptr, Ph, Pl);
  gemm3_kernel<3><<<g, 512, 0, stream>>>(Ph, Pl, Lh + 3 * LM, Ll + 3 * LM, O0, Qh, Ql);
  // decoder
  gemm3_kernel<2><<<g, 512, 0, stream>>>(Qh, Ql, Lh + 4 * LM, Ll + 4 * LM, nullptr, Ph, Pl);
  gemm3_kernel<2><<<g, 512, 0, stream>>>(Ph, Pl, Lh + 5 * LM, Ll + 5 * LM, nullptr, Qh, Ql);
  gemm3_kernel<2><<<g, 512, 0, stream>>>(Qh, Ql, Lh + 6 * LM, Ll + 6 * LM, nullptr, Ph, Pl);
  gemm3_kernel<1><<<g, 512, 0, stream>>>(Ph, Pl, Lh + 7 * LM, Ll + 7 * LM, O1, nullptr, nullptr);
}

// Round 8
// 511.890 us; speedup vs baseline: 1.8027x; 1.8027x over previous
//
#include <hip/hip_runtime.h>
#include <hip/hip_bf16.h>
#include <cstdint>
#include <cstddef>

#define H 512
#define NFEAT 1024
#define BATCH 16384

using bf16 = __hip_bfloat16;
using bf16x8 = __attribute__((ext_vector_type(8))) __bf16;
using f32x4 = __attribute__((ext_vector_type(4))) float;
using f32x16 = __attribute__((ext_vector_type(16))) float;

// ---------------------------------------------------------------------------
// async global -> LDS, 16 bytes per lane
// ---------------------------------------------------------------------------
__device__ __forceinline__ void gload16(void* lds, const void* g) {
  __builtin_amdgcn_global_load_lds(
      (__attribute__((address_space(1))) void*)g,
      (__attribute__((address_space(3))) void*)lds,
      16, 0, 0);
}

// ---------------------------------------------------------------------------
// prep: per matrix, compute a[], b[] for core = diag(d) + a*1^T + b*u^T
// Closed-form Cayley (rank-2 Woodbury), verified R0-R7.
// ---------------------------------------------------------------------------
__global__ void prep_kernel(const float* __restrict__ er, const float* __restrict__ ed,
                            const float* __restrict__ dr, const float* __restrict__ dd,
                            float* __restrict__ ab) {
  const int mat = blockIdx.x;          // 0..7
  const int lane = threadIdx.x;        // 0..63
  const float* u = (mat < 4) ? (er + mat * H) : (dr + (mat - 4) * H);
  const float* d = (mat < 4) ? (ed + mat * H) : (dd + (mat - 4) * H);

  double s = 0.0, q = 0.0;
  for (int k = 0; k < 8; ++k) {
    double v = (double)u[lane + 64 * k];
    s += v;
    q += v * v;
  }
  for (int off = 32; off; off >>= 1) {
    s += __shfl_down(s, off);
    q += __shfl_down(q, off);
  }
  s = __shfl(s, 0);
  q = __shfl(q, 0);

  const double det = 1.0 - s * s + (double)H * q;
  const double cuv = 2.0 * (1.0 + s) / det;
  const double cuu = -2.0 * (double)H / det;
  const double cvv = -2.0 * q / det;
  const double cvu = -2.0 * (1.0 - s) / det;

  float* a = ab + mat * 1024;
  float* b = a + H;
  for (int k = 0; k < 8; ++k) {
    int idx = lane + 64 * k;
    double ui = (double)u[idx], di = (double)d[idx];
    a[idx] = (float)(di * (cuv * ui + cvv));
    b[idx] = (float)(di * (cuu * ui + cvu));
  }
}

// ---------------------------------------------------------------------------
// prep2: stride-4-residue inclusive prefix tables over a, a_rev, d, d_rev.
// ---------------------------------------------------------------------------
__global__ __launch_bounds__(256) void prep2_kernel(
    const float* __restrict__ er, const float* __restrict__ ed,
    const float* __restrict__ dr, const float* __restrict__ dd,
    const float* __restrict__ ab, float* __restrict__ Tpref) {
  __shared__ float buf[4][512];
  __shared__ float tmp[4][512];
  const int mat = blockIdx.x;
  const float* d = (mat < 4) ? (ed + mat * H) : (dd + (mat - 4) * H);
  const float* a = ab + mat * 1024;
  const int t = threadIdx.x;
  for (int m = t; m < 512; m += 256) {
    buf[0][m] = a[m];
    buf[1][m] = a[511 - m];
    buf[2][m] = d[m];
    buf[3][m] = d[511 - m];
  }
  __syncthreads();
  for (int s = 4; s <= 256; s <<= 1) {
    for (int m = t; m < 512; m += 256)
#pragma unroll
      for (int q = 0; q < 4; ++q) tmp[q][m] = (m >= s) ? buf[q][m - s] : 0.f;
    __syncthreads();
    for (int m = t; m < 512; m += 256)
#pragma unroll
      for (int q = 0; q < 4; ++q) buf[q][m] += tmp[q][m];
    __syncthreads();
  }
  float* tp = Tpref + mat * 2048;
  for (int m = t; m < 512; m += 256) {
    tp[m] = buf[0][m];
    tp[512 + m] = buf[1][m];
    tp[1024 + m] = buf[2][m];
    tp[1536 + m] = buf[3][m];
  }
}

// ---------------------------------------------------------------------------
// build v3 (unchanged from R2): prefix tables + quad b*u loop.
// ---------------------------------------------------------------------------
__global__ __launch_bounds__(256) void build_kernel(
    const float* __restrict__ er, const float* __restrict__ ed,
    const float* __restrict__ dr, const float* __restrict__ dd,
    const float* __restrict__ ab, const float* __restrict__ Tpref,
    bf16* __restrict__ Lh, bf16* __restrict__ Ll) {
  __shared__ __align__(16) float arr4[4][520];
  __shared__ __align__(16) float4 up[132];
  __shared__ float pa[512], parev[512], pd[512], pdrev[512], sdl[512];

  const int i = blockIdx.x;
  const int mat = blockIdx.y;
  const float* u = (mat < 4) ? (er + mat * H) : (dr + (mat - 4) * H);
  const float* d = (mat < 4) ? (ed + mat * H) : (dd + (mat - 4) * H);
  const float* a = ab + mat * 1024;
  const float* b = a + H;
  const float* tp = Tpref + mat * 2048;
  const int t = threadIdx.x;

  for (int m = t; m < 520; m += 256) {
    arr4[0][m] = (m < 512) ? u[m] : 0.f;
    arr4[1][m] = (m >= 1 && m <= 512) ? b[m - 1] : 0.f;
    arr4[2][m] = (m >= 2 && m <= 513) ? u[513 - m] : 0.f;
    arr4[3][m] = (m >= 3 && m <= 514) ? b[514 - m] : 0.f;
  }
  for (int m = t; m < 512; m += 256) {
    pa[m] = tp[m];
    parev[m] = tp[512 + m];
    pd[m] = tp[1024 + m];
    pdrev[m] = tp[1536 + m];
    sdl[m] = d[m];
  }
  if (t < 132) {
    const int k4 = 4 * t;
    float4 v;
    int p0 = i - k4;
    v.x = (p0 >= 0 && p0 < 512) ? b[p0] : 0.f;
    int p1 = i - k4 - 1;
    v.y = (p1 >= 0 && p1 < 512) ? u[511 - p1] : 0.f;
    int p2 = i - k4 - 2;
    v.z = (p2 >= 0 && p2 < 512) ? b[511 - p2] : 0.f;
    int p3 = i - k4 - 3;
    v.w = (p3 >= 0 && p3 < 512) ? u[p3] : 0.f;
    up[t] = v;
  }
  __syncthreads();

  const float* upf = (const float*)up;
  const int j0 = t * 4;

  int lo_[4], hi_[4];
#pragma unroll
  for (int c = 0; c < 4; ++c) {
    const int jc = j0 + c;
    lo_[c] = max(0, max(i, jc) - 511);
    hi_[c] = min(512, min(i, jc));
  }
  const int CL = lo_[3];
  const int CH = hi_[0];

  float acc[4] = {0.f, 0.f, 0.f, 0.f};

#pragma unroll
  for (int c = 0; c < 4; ++c) {
    const int jc = j0 + c;
    const int lo = lo_[c], hi = hi_[c];
    if (lo > hi) continue;
    float v = 0.f;
    {
      int o1 = lo + ((0 - lo) & 3), o2 = hi - ((hi - 0) & 3);
      if (o1 <= o2) { int mx = i - o1, mn = i - o2; v += pa[mx] - (mn >= 4 ? pa[mn - 4] : 0.f); }
    }
    {
      int o1 = lo + ((1 - lo) & 3), o2 = hi - ((hi - 1) & 3);
      if (o1 <= o2) { int mx = jc - o1, mn = jc - o2; v += pa[mx] - (mn >= 4 ? pa[mn - 4] : 0.f); }
    }
    {
      int o1 = lo + ((2 - lo) & 3), o2 = hi - ((hi - 2) & 3);
      if (o1 <= o2) { int mx = i - o1, mn = i - o2; v += parev[mx] - (mn >= 4 ? parev[mn - 4] : 0.f); }
    }
    {
      int o1 = lo + ((3 - lo) & 3), o2 = hi - ((hi - 3) & 3);
      if (o1 <= o2) { int mx = jc - o1, mn = jc - o2; v += parev[mx] - (mn >= 4 ? parev[mn - 4] : 0.f); }
    }
    if (i == jc) {
      {
        int o1 = lo + ((0 - lo) & 3), o2 = hi - ((hi - 0) & 3);
        if (o1 <= o2) { int mx = i - o1, mn = i - o2; v += pd[mx] - (mn >= 4 ? pd[mn - 4] : 0.f); }
      }
      {
        int o1 = lo + ((2 - lo) & 3), o2 = hi - ((hi - 2) & 3);
        if (o1 <= o2) { int mx = i - o1, mn = i - o2; v += pdrev[mx] - (mn >= 4 ? pdrev[mn - 4] : 0.f); }
      }
    }
    const int m2 = i + jc - 511;
    if (m2 >= 0 && !(m2 & 1)) {
      const int os = m2 >> 1;
      if (os >= lo && os <= hi) {
        const int r = os & 3;
        if (r == 1) v += sdl[jc - os];
        else if (r == 3) v += sdl[511 - (jc - os)];
      }
    }
    acc[c] = v;
  }

  if (CL > CH) {
#pragma unroll
    for (int c = 0; c < 4; ++c) {
      const int jc = j0 + c;
      for (int o = lo_[c]; o <= hi_[c]; ++o) {
        const int r = o & 3;
        acc[c] += upf[o] * arr4[r][jc - o + r];
      }
    }
  } else {
#pragma unroll
    for (int c = 0; c < 4; ++c) {
      const int jc = j0 + c;
      const int he = min(hi_[c], CL - 1);
      for (int o = lo_[c]; o <= he; ++o) {
        const int r = o & 3;
        acc[c] += upf[o] * arr4[r][jc - o + r];
      }
      const int ls = max(lo_[c], CH + 1);
      for (int o = ls; o <= hi_[c]; ++o) {
        const int r = o & 3;
        acc[c] += upf[o] * arr4[r][jc - o + r];
      }
    }
    const int QL = (CL + 3) & ~3;
    for (int o = CL; o < QL && o <= CH; ++o) {
      const int r = o & 3;
      const float uvv = upf[o];
      const float4 wv = *(const float4*)&arr4[r][j0 - o + r];
      acc[0] += uvv * wv.x; acc[1] += uvv * wv.y;
      acc[2] += uvv * wv.z; acc[3] += uvv * wv.w;
    }
    int ob = QL;
    for (; ob + 3 <= CH; ob += 4) {
      const float4 uv = up[ob >> 2];
      const int x = j0 - ob;
      const float4 w0 = *(const float4*)&arr4[0][x];
      const float4 w1 = *(const float4*)&arr4[1][x];
      const float4 w2 = *(const float4*)&arr4[2][x];
      const float4 w3 = *(const float4*)&arr4[3][x];
      acc[0] += uv.x * w0.x + uv.y * w1.x + uv.z * w2.x + uv.w * w3.x;
      acc[1] += uv.x * w0.y + uv.y * w1.y + uv.z * w2.y + uv.w * w3.y;
      acc[2] += uv.x * w0.z + uv.y * w1.z + uv.z * w2.z + uv.w * w3.z;
      acc[3] += uv.x * w0.w + uv.y * w1.w + uv.z * w2.w + uv.w * w3.w;
    }
    for (int o = ob; o <= CH; ++o) {
      const int r = o & 3;
      const float uvv = upf[o];
      const float4 wv = *(const float4*)&arr4[r][j0 - o + r];
      acc[0] += uvv * wv.x; acc[1] += uvv * wv.y;
      acc[2] += uvv * wv.z; acc[3] += uvv * wv.w;
    }
  }

  const size_t off = ((size_t)mat << 20) + ((size_t)i << 10) + (size_t)j0;
  union { bf16 v[4]; ushort4 s; } Hu, Lu;
#pragma unroll
  for (int c = 0; c < 4; ++c) {
    const bf16 hb = __float2bfloat16(acc[c]);
    Hu.v[c] = hb;
    Lu.v[c] = __float2bfloat16(acc[c] - __bfloat162float(hb));
  }
  *(ushort4*)(Lh + off) = Hu.s;
  *(ushort4*)(Ll + off) = Lu.s;
}

// ---------------------------------------------------------------------------
// split fp32 -> (hi, lo) bf16
// ---------------------------------------------------------------------------
__global__ void split_kernel(const float* __restrict__ x, bf16* __restrict__ h,
                             bf16* __restrict__ l) {
  const int n4 = BATCH * NFEAT / 4;
  int idx = blockIdx.x * blockDim.x + threadIdx.x;
  int stride = gridDim.x * blockDim.x;
  for (int i = idx; i < n4; i += stride) {
    float4 v = ((const float4*)x)[i];
    float vv[4] = {v.x, v.y, v.z, v.w};
    union { bf16 b[4]; short4 s; } Hu, Lu;
#pragma unroll
    for (int c = 0; c < 4; ++c) {
      bf16 hb = __float2bfloat16(vv[c]);
      Hu.b[c] = hb;
      Lu.b[c] = __float2bfloat16(vv[c] - __bfloat162float(hb));
    }
    ((short4*)h)[i] = Hu.s;
    ((short4*)l)[i] = Lu.s;
  }
}

// ---------------------------------------------------------------------------
// transpose: D = S^T for a 1024x1024 bf16 pair (hi, lo).
// Transposing hi/lo separately is exact (pure data movement).
// ---------------------------------------------------------------------------
__global__ __launch_bounds__(256) void transpose_kernel(
    const bf16* __restrict__ Sh, const bf16* __restrict__ Sl,
    bf16* __restrict__ Dh, bf16* __restrict__ Dl) {
  __shared__ ushort th[64][72], tl[64][72];
  const int i0 = blockIdx.x * 64, j0 = blockIdx.y * 64;
  const int tid = threadIdx.x;
  const int rr = tid >> 4;         // 0..15
  const int cc = (tid & 15) * 4;   // 0..60
#pragma unroll
  for (int it = 0; it < 4; ++it) {
    const int row = it * 16 + rr;
    const size_t so = (size_t)(i0 + row) * 1024 + j0 + cc;
    ushort4 vh = *(const ushort4*)((const ushort*)Sh + so);
    ushort4 vl = *(const ushort4*)((const ushort*)Sl + so);
    th[row][cc] = vh.x; th[row][cc + 1] = vh.y; th[row][cc + 2] = vh.z; th[row][cc + 3] = vh.w;
    tl[row][cc] = vl.x; tl[row][cc + 1] = vl.y; tl[row][cc + 2] = vl.z; tl[row][cc + 3] = vl.w;
  }
  __syncthreads();
#pragma unroll
  for (int it = 0; it < 4; ++it) {
    const int row = it * 16 + rr;   // output row index within tile (j-local)
    ushort4 oh, ol;
    oh.x = th[cc][row];     oh.y = th[cc + 1][row];
    oh.z = th[cc + 2][row]; oh.w = th[cc + 3][row];
    ol.x = tl[cc][row];     ol.y = tl[cc + 1][row];
    ol.z = tl[cc + 2][row]; ol.w = tl[cc + 3][row];
    const size_t dofs = (size_t)(j0 + row) * 1024 + i0 + cc;
    *(ushort4*)((ushort*)Dh + dofs) = oh;
    *(ushort4*)((ushort*)Dl + dofs) = ol;
  }
}

// ---------------------------------------------------------------------------
// chain GEMM: Y = A * B^T for 1024x1024 split-bf16 operands, split output.
// 64x64 tile, 4 waves (2x2 of 32x32), BK=64, simple 2-barrier loop.
// acc += Ah*Bh + Ah*Bl + Al*Bh (fp32).
// ---------------------------------------------------------------------------
__global__ __launch_bounds__(256) void chaingemm_kernel(
    const bf16* __restrict__ Ah, const bf16* __restrict__ Al,
    const bf16* __restrict__ Bh, const bf16* __restrict__ Bl,
    bf16* __restrict__ Yh, bf16* __restrict__ Yl) {
  __shared__ __align__(16) bf16 s[4][4096];  // Ah | Al | Bh | Bl, 8KB each

  const int tid = threadIdx.x;
  const int lane = tid & 63;
  const int wave = tid >> 6;
  const int wr = wave >> 1, wc = wave & 1;
  const int r0 = blockIdx.x * 64, c0 = blockIdx.y * 64;
  const int srow = tid >> 3;        // 0..31
  const int sc = (tid & 7) * 8;     // elem col within BK=64
  const int dst = tid * 8;          // linear dest elems (q=0); +2048 for q=1
  const int l31 = lane & 31;
  const int kh = (lane >> 5) * 8;   // k-half elem offset

  f32x16 acc = {};

  for (int t = 0; t < 16; ++t) {
    const int k0 = t * 64;
    __syncthreads();  // previous iteration's LDS reads complete
#pragma unroll
    for (int q = 0; q < 2; ++q) {
      const size_t ga = (size_t)(r0 + q * 32 + srow) * 1024 + sc + k0;
      const size_t gb = (size_t)(c0 + q * 32 + srow) * 1024 + sc + k0;
      gload16(&s[0][q * 2048 + dst], Ah + ga);
      gload16(&s[1][q * 2048 + dst], Al + ga);
      gload16(&s[2][q * 2048 + dst], Bh + gb);
      gload16(&s[3][q * 2048 + dst], Bl + gb);
    }
    asm volatile("s_waitcnt vmcnt(0)" ::: "memory");
    __syncthreads();

    const int ar = wr * 32 + l31;
    const int br = wc * 32 + l31;
#pragma unroll
    for (int ks = 0; ks < 4; ++ks) {
      bf16x8 ah = *(const bf16x8*)&s[0][ar * 64 + ks * 16 + kh];
      bf16x8 al = *(const bf16x8*)&s[1][ar * 64 + ks * 16 + kh];
      bf16x8 bh = *(const bf16x8*)&s[2][br * 64 + ks * 16 + kh];
      bf16x8 bl = *(const bf16x8*)&s[3][br * 64 + ks * 16 + kh];
      acc = __builtin_amdgcn_mfma_f32_32x32x16_bf16(ah, bh, acc, 0, 0, 0);
      acc = __builtin_amdgcn_mfma_f32_32x32x16_bf16(ah, bl, acc, 0, 0, 0);
      acc = __builtin_amdgcn_mfma_f32_32x32x16_bf16(al, bh, acc, 0, 0, 0);
    }
  }

  // epilogue: 32x32 C/D: col = lane&31, row = (r&3)+8*(r>>2)+4*(lane>>5)
  const int oc = c0 + wc * 32 + l31;
  const int rb = (lane >> 5) << 2;
#pragma unroll
  for (int r = 0; r < 16; ++r) {
    const int gr = r0 + wr * 32 + (r & 3) + ((r >> 2) << 3) + rb;
    const size_t off = (size_t)gr * 1024 + oc;
    const float v = acc[r];
    const bf16 hb = __float2bfloat16(v);
    Yh[off] = hb;
    Yl[off] = __float2bfloat16(v - __bfloat162float(hb));
  }
}

// ---------------------------------------------------------------------------
// split-bf16 GEMM (unchanged from R6): Y = A * B^T, 256x256 tile, BK=32,
// 8 waves, dbuf LDS, 2 phases/tile, early staging, raw s_barrier + setprio.
// MODE bit0: write fp32 Yf; bit1: write split (Yh, Yl)
// ---------------------------------------------------------------------------
template <int MODE>
__global__ __launch_bounds__(512, 2) void gemm3_kernel(
    const bf16* __restrict__ Ah, const bf16* __restrict__ Al,
    const bf16* __restrict__ Bh, const bf16* __restrict__ Bl,
    float* __restrict__ Yf, bf16* __restrict__ Yh, bf16* __restrict__ Yl) {
  __shared__ __align__(16) bf16 smem[2 * 4 * 8192];  // 128 KiB

  const int tid = threadIdx.x;
  const int lane = tid & 63;
  const int wave = tid >> 6;
  const int wr = wave >> 2;
  const int wc = wave & 3;

  const int pdisp = blockIdx.x + (blockIdx.y << 6);
  const int xcd = pdisp & 7;
  const int chk = pdisp >> 3;
  const int row0 = ((((xcd & 1) << 5) | chk)) * 256;
  const int col0 = (xcd >> 1) * 256;

  const int gsrc = (tid & 3) ^ ((tid >> 3) & 3);
  const int dst = tid * 8;
  const size_t abase = (size_t)(row0 + (tid >> 2)) * NFEAT + gsrc * 8;
  const size_t bbase = (size_t)(col0 + (tid >> 2)) * NFEAT + gsrc * 8;

  auto STAGE2 = [&](int nb, int arr, const bf16* __restrict__ src, size_t base, int k0) {
    bf16* d = smem + nb * 32768 + arr * 8192 + dst;
    gload16(d, src + base + k0);
    gload16(d + 4096, src + base + 131072 + k0);
  };

  const int l31 = lane & 31;
  const int hb = lane >> 5;
  int aoffB[4][2], boffB[2][2];
#pragma unroll
  for (int m = 0; m < 4; ++m) {
    const int r = wr * 128 + m * 32 + l31;
#pragma unroll
    for (int ks = 0; ks < 2; ++ks)
      aoffB[m][ks] = r * 64 + ((((ks << 1) | hb) ^ ((r >> 1) & 3)) << 4);
  }
#pragma unroll
  for (int n = 0; n < 2; ++n) {
    const int r = wc * 64 + n * 32 + l31;
#pragma unroll
    for (int ks = 0; ks < 2; ++ks)
      boffB[n][ks] = r * 64 + ((((ks << 1) | hb) ^ ((r >> 1) & 3)) << 4);
  }

  auto LD = [](const char* base, int off) { return *(const bf16x8*)(base + off); };
  auto TRIPLE = [](f32x16& ac, bf16x8 ah, bf16x8 al, bf16x8 bh, bf16x8 bl) {
    ac = __builtin_amdgcn_mfma_f32_32x32x16_bf16(ah, bh, ac, 0, 0, 0);
    ac = __builtin_amdgcn_mfma_f32_32x32x16_bf16(ah, bl, ac, 0, 0, 0);
    ac = __builtin_amdgcn_mfma_f32_32x32x16_bf16(al, bh, ac, 0, 0, 0);
  };

  f32x16 acc[4][2] = {};

  STAGE2(0, 0, Ah, abase, 0);
  STAGE2(0, 1, Al, abase, 0);
  STAGE2(0, 2, Bh, bbase, 0);
  STAGE2(0, 3, Bl, bbase, 0);
  asm volatile("s_waitcnt vmcnt(0)" ::: "memory");
  __builtin_amdgcn_s_barrier();

  for (int t = 0; t < 32; ++t) {
    const int buf = t & 1;
    const int nb = buf ^ 1;
    const int k1 = (t + 1) * 32;
    const char* pAh = (const char*)(smem + buf * 32768);
    const char* pAl = pAh + 16384;
    const char* pBh = pAh + 32768;
    const char* pBl = pAh + 49152;
    const bool pf = (t < 31);

    bf16x8 gah[2][2], gal[2][2], fbh[2][2], fbl[2][2];

    if (pf) {
      STAGE2(nb, 0, Ah, abase, k1);
      STAGE2(nb, 1, Al, abase, k1);
      STAGE2(nb, 2, Bh, bbase, k1);
      STAGE2(nb, 3, Bl, bbase, k1);
    }
#pragma unroll
    for (int mi = 0; mi < 2; ++mi)
#pragma unroll
      for (int ks = 0; ks < 2; ++ks) {
        gah[mi][ks] = LD(pAh, aoffB[mi][ks]);
        gal[mi][ks] = LD(pAl, aoffB[mi][ks]);
      }
#pragma unroll
    for (int n = 0; n < 2; ++n)
#pragma unroll
      for (int ks = 0; ks < 2; ++ks) {
        fbh[n][ks] = LD(pBh, boffB[n][ks]);
        fbl[n][ks] = LD(pBl, boffB[n][ks]);
      }
    __builtin_amdgcn_s_barrier();
    __builtin_amdgcn_s_setprio(1);
#pragma unroll
    for (int ks = 0; ks < 2; ++ks)
#pragma unroll
      for (int mi = 0; mi < 2; ++mi)
#pragma unroll
        for (int n = 0; n < 2; ++n)
          TRIPLE(acc[mi][n], gah[mi][ks], gal[mi][ks], fbh[n][ks], fbl[n][ks]);
    __builtin_amdgcn_s_setprio(0);
    __builtin_amdgcn_s_barrier();

#pragma unroll
    for (int mi = 0; mi < 2; ++mi)
#pragma unroll
      for (int ks = 0; ks < 2; ++ks) {
        gah[mi][ks] = LD(pAh, aoffB[2 + mi][ks]);
        gal[mi][ks] = LD(pAl, aoffB[2 + mi][ks]);
      }
    __builtin_amdgcn_s_barrier();
    __builtin_amdgcn_s_setprio(1);
#pragma unroll
    for (int ks = 0; ks < 2; ++ks)
#pragma unroll
      for (int mi = 0; mi < 2; ++mi)
#pragma unroll
        for (int n = 0; n < 2; ++n)
          TRIPLE(acc[2 + mi][n], gah[mi][ks], gal[mi][ks], fbh[n][ks], fbl[n][ks]);
    __builtin_amdgcn_s_setprio(0);
    if (pf) asm volatile("s_waitcnt vmcnt(0)" ::: "memory");
    __builtin_amdgcn_s_barrier();
  }

  const int ocol0 = col0 + wc * 64 + l31;
  const int rb = (lane >> 5) << 2;
#pragma unroll
  for (int m = 0; m < 4; ++m)
#pragma unroll
    for (int n = 0; n < 2; ++n)
#pragma unroll
      for (int r = 0; r < 16; ++r) {
        const int grow = row0 + wr * 128 + m * 32 + (r & 3) + ((r >> 2) << 3) + rb;
        const int gcol = ocol0 + n * 32;
        const size_t off = (size_t)grow * NFEAT + (size_t)gcol;
        const float v = acc[m][n][r];
        if (MODE & 1) Yf[off] = v;
        if (MODE & 2) {
          bf16 hbv = __float2bfloat16(v);
          Yh[off] = hbv;
          Yl[off] = __float2bfloat16(v - __bfloat162float(hbv));
        }
      }
}

// ---------------------------------------------------------------------------
// launch: build 8 L-matrices -> fold each stage's 4 matrices into one via
// the transposed chain K = L1^T L2^T L3^T L4^T (only 2 transposes/stage),
// then run 2 big GEMMs instead of 8.
// ---------------------------------------------------------------------------
extern "C" void kernel_launch(void* const* d_in, const int* in_sizes, int n_in,
                              void* d_out, int out_size, void* d_ws, size_t ws_size,
                              hipStream_t stream) {
  (void)in_sizes; (void)n_in; (void)out_size; (void)ws_size;
  const float* x  = (const float*)d_in[0];
  const float* er = (const float*)d_in[1];
  const float* ed = (const float*)d_in[2];
  const float* dr = (const float*)d_in[3];
  const float* dd = (const float*)d_in[4];

  float* O0 = (float*)d_out;                       // bottleneck (fp32, 64 MB)
  float* O1 = O0 + (size_t)BATCH * NFEAT;          // out (fp32, 64 MB)

  // d_ws: Lh (16MB) | Ll (16MB) | ab (32KB) | Ph (32MB) | Pl (32MB)
  bf16* Lh = (bf16*)d_ws;
  bf16* Ll = Lh + ((size_t)8 << 20);
  float* ab = (float*)(Ll + ((size_t)8 << 20));
  bf16* Ph = (bf16*)(ab + 8 * 1024);
  bf16* Pl = Ph + (size_t)BATCH * NFEAT;

  const size_t LM = (size_t)1 << 20;  // elems per 1024x1024 matrix

  // O0 region scratch (dead before big GEMM 1): Tpref @0 (64KB),
  // chain temps @1MB: T (hi,lo), Ka (hi,lo), Kb (hi,lo) -- 12MB total.
  float* Tpref = O0;
  bf16* Th  = (bf16*)(O0 + (1 << 18));   // byte offset 1MB
  bf16* Tl  = Th + LM;
  bf16* KaH = Tl + LM;
  bf16* KaL = KaH + LM;
  bf16* KbH = KaL + LM;
  bf16* KbL = KbH + LM;

  // Menc/Mdec land in dead L1..L4 slots of Lh after the chains.
  bf16* MeH = Lh + 0 * LM;
  bf16* MeL = Lh + 1 * LM;
  bf16* MdH = Lh + 2 * LM;
  bf16* MdL = Lh + 3 * LM;

  // x split lives in O1 (dead once big GEMM 1 done; big2 overwrites O1).
  bf16* Qh = (bf16*)O1;
  bf16* Ql = Qh + (size_t)BATCH * NFEAT;

  prep_kernel<<<8, 64, 0, stream>>>(er, ed, dr, dd, ab);
  prep2_kernel<<<8, 256, 0, stream>>>(er, ed, dr, dd, ab, Tpref);
  build_kernel<<<dim3(1024, 8), 256, 0, stream>>>(er, ed, dr, dd, ab, Tpref, Lh, Ll);
  split_kernel<<<4096, 256, 0, stream>>>(x, Qh, Ql);

  const dim3 tg(16, 16);
  // encoder chain: K4 = L1^T L2^T L3^T L4^T ; Menc = K4^T = L4 L3 L2 L1
  transpose_kernel<<<tg, 256, 0, stream>>>(Lh + 0 * LM, Ll + 0 * LM, Th, Tl);
  chaingemm_kernel<<<tg, 256, 0, stream>>>(Th, Tl, Lh + 1 * LM, Ll + 1 * LM, KaH, KaL);
  chaingemm_kernel<<<tg, 256, 0, stream>>>(KaH, KaL, Lh + 2 * LM, Ll + 2 * LM, KbH, KbL);
  chaingemm_kernel<<<tg, 256, 0, stream>>>(KbH, KbL, Lh + 3 * LM, Ll + 3 * LM, KaH, KaL);
  transpose_kernel<<<tg, 256, 0, stream>>>(KaH, KaL, MeH, MeL);
  // decoder chain: Mdec = L8 L7 L6 L5
  transpose_kernel<<<tg, 256, 0, stream>>>(Lh + 4 * LM, Ll + 4 * LM, Th, Tl);
  chaingemm_kernel<<<tg, 256, 0, stream>>>(Th, Tl, Lh + 5 * LM, Ll + 5 * LM, KbH, KbL);
  chaingemm_kernel<<<tg, 256, 0, stream>>>(KbH, KbL, Lh + 6 * LM, Ll + 6 * LM, KaH, KaL);
  chaingemm_kernel<<<tg, 256, 0, stream>>>(KaH, KaL, Lh + 7 * LM, Ll + 7 * LM, KbH, KbL);
  transpose_kernel<<<tg, 256, 0, stream>>>(KbH, KbL, MdH, MdL);

  // two big GEMMs
  const dim3 g(64, 4);
  gemm3_kernel<3><<<g, 512, 0, stream>>>(Qh, Ql, MeH, MeL, O0, Ph, Pl);
  gemm3_kernel<1><<<g, 512, 0, stream>>>(Ph, Pl, MdH, MdL, O1, nullptr, nullptr);
}

// Round 9
// 397.325 us; speedup vs baseline: 2.3225x; 1.2883x over previous
//
#include <hip/hip_runtime.h>
#include <hip/hip_bf16.h>
#include <cstdint>
#include <cstddef>

#define H 512
#define NFEAT 1024
#define BATCH 16384

using bf16 = __hip_bfloat16;
using bf16x8 = __attribute__((ext_vector_type(8))) __bf16;
using f32x4 = __attribute__((ext_vector_type(4))) float;
using f32x16 = __attribute__((ext_vector_type(16))) float;

// ---------------------------------------------------------------------------
// async global -> LDS, 16 bytes per lane
// ---------------------------------------------------------------------------
__device__ __forceinline__ void gload16(void* lds, const void* g) {
  __builtin_amdgcn_global_load_lds(
      (__attribute__((address_space(1))) void*)g,
      (__attribute__((address_space(3))) void*)lds,
      16, 0, 0);
}

// ---------------------------------------------------------------------------
// prep: per matrix, compute a[], b[] for core = diag(d) + a*1^T + b*u^T
// Closed-form Cayley (rank-2 Woodbury), verified R0-R8.
// ---------------------------------------------------------------------------
__global__ void prep_kernel(const float* __restrict__ er, const float* __restrict__ ed,
                            const float* __restrict__ dr, const float* __restrict__ dd,
                            float* __restrict__ ab) {
  const int mat = blockIdx.x;          // 0..7
  const int lane = threadIdx.x;        // 0..63
  const float* u = (mat < 4) ? (er + mat * H) : (dr + (mat - 4) * H);
  const float* d = (mat < 4) ? (ed + mat * H) : (dd + (mat - 4) * H);

  double s = 0.0, q = 0.0;
  for (int k = 0; k < 8; ++k) {
    double v = (double)u[lane + 64 * k];
    s += v;
    q += v * v;
  }
  for (int off = 32; off; off >>= 1) {
    s += __shfl_down(s, off);
    q += __shfl_down(q, off);
  }
  s = __shfl(s, 0);
  q = __shfl(q, 0);

  const double det = 1.0 - s * s + (double)H * q;
  const double cuv = 2.0 * (1.0 + s) / det;
  const double cuu = -2.0 * (double)H / det;
  const double cvv = -2.0 * q / det;
  const double cvu = -2.0 * (1.0 - s) / det;

  float* a = ab + mat * 1024;
  float* b = a + H;
  for (int k = 0; k < 8; ++k) {
    int idx = lane + 64 * k;
    double ui = (double)u[idx], di = (double)d[idx];
    a[idx] = (float)(di * (cuv * ui + cvv));
    b[idx] = (float)(di * (cuu * ui + cvu));
  }
}

// ---------------------------------------------------------------------------
// prep2: stride-4-residue inclusive prefix tables over a, a_rev, d, d_rev.
// ---------------------------------------------------------------------------
__global__ __launch_bounds__(256) void prep2_kernel(
    const float* __restrict__ er, const float* __restrict__ ed,
    const float* __restrict__ dr, const float* __restrict__ dd,
    const float* __restrict__ ab, float* __restrict__ Tpref) {
  __shared__ float buf[4][512];
  __shared__ float tmp[4][512];
  const int mat = blockIdx.x;
  const float* d = (mat < 4) ? (ed + mat * H) : (dd + (mat - 4) * H);
  const float* a = ab + mat * 1024;
  const int t = threadIdx.x;
  for (int m = t; m < 512; m += 256) {
    buf[0][m] = a[m];
    buf[1][m] = a[511 - m];
    buf[2][m] = d[m];
    buf[3][m] = d[511 - m];
  }
  __syncthreads();
  for (int s = 4; s <= 256; s <<= 1) {
    for (int m = t; m < 512; m += 256)
#pragma unroll
      for (int q = 0; q < 4; ++q) tmp[q][m] = (m >= s) ? buf[q][m - s] : 0.f;
    __syncthreads();
    for (int m = t; m < 512; m += 256)
#pragma unroll
      for (int q = 0; q < 4; ++q) buf[q][m] += tmp[q][m];
    __syncthreads();
  }
  float* tp = Tpref + mat * 2048;
  for (int m = t; m < 512; m += 256) {
    tp[m] = buf[0][m];
    tp[512 + m] = buf[1][m];
    tp[1024 + m] = buf[2][m];
    tp[1536 + m] = buf[3][m];
  }
}

// ---------------------------------------------------------------------------
// build v3 (unchanged from R2): prefix tables + quad b*u loop.
// ---------------------------------------------------------------------------
__global__ __launch_bounds__(256) void build_kernel(
    const float* __restrict__ er, const float* __restrict__ ed,
    const float* __restrict__ dr, const float* __restrict__ dd,
    const float* __restrict__ ab, const float* __restrict__ Tpref,
    bf16* __restrict__ Lh, bf16* __restrict__ Ll) {
  __shared__ __align__(16) float arr4[4][520];
  __shared__ __align__(16) float4 up[132];
  __shared__ float pa[512], parev[512], pd[512], pdrev[512], sdl[512];

  const int i = blockIdx.x;
  const int mat = blockIdx.y;
  const float* u = (mat < 4) ? (er + mat * H) : (dr + (mat - 4) * H);
  const float* d = (mat < 4) ? (ed + mat * H) : (dd + (mat - 4) * H);
  const float* a = ab + mat * 1024;
  const float* b = a + H;
  const float* tp = Tpref + mat * 2048;
  const int t = threadIdx.x;

  for (int m = t; m < 520; m += 256) {
    arr4[0][m] = (m < 512) ? u[m] : 0.f;
    arr4[1][m] = (m >= 1 && m <= 512) ? b[m - 1] : 0.f;
    arr4[2][m] = (m >= 2 && m <= 513) ? u[513 - m] : 0.f;
    arr4[3][m] = (m >= 3 && m <= 514) ? b[514 - m] : 0.f;
  }
  for (int m = t; m < 512; m += 256) {
    pa[m] = tp[m];
    parev[m] = tp[512 + m];
    pd[m] = tp[1024 + m];
    pdrev[m] = tp[1536 + m];
    sdl[m] = d[m];
  }
  if (t < 132) {
    const int k4 = 4 * t;
    float4 v;
    int p0 = i - k4;
    v.x = (p0 >= 0 && p0 < 512) ? b[p0] : 0.f;
    int p1 = i - k4 - 1;
    v.y = (p1 >= 0 && p1 < 512) ? u[511 - p1] : 0.f;
    int p2 = i - k4 - 2;
    v.z = (p2 >= 0 && p2 < 512) ? b[511 - p2] : 0.f;
    int p3 = i - k4 - 3;
    v.w = (p3 >= 0 && p3 < 512) ? u[p3] : 0.f;
    up[t] = v;
  }
  __syncthreads();

  const float* upf = (const float*)up;
  const int j0 = t * 4;

  int lo_[4], hi_[4];
#pragma unroll
  for (int c = 0; c < 4; ++c) {
    const int jc = j0 + c;
    lo_[c] = max(0, max(i, jc) - 511);
    hi_[c] = min(512, min(i, jc));
  }
  const int CL = lo_[3];
  const int CH = hi_[0];

  float acc[4] = {0.f, 0.f, 0.f, 0.f};

#pragma unroll
  for (int c = 0; c < 4; ++c) {
    const int jc = j0 + c;
    const int lo = lo_[c], hi = hi_[c];
    if (lo > hi) continue;
    float v = 0.f;
    {
      int o1 = lo + ((0 - lo) & 3), o2 = hi - ((hi - 0) & 3);
      if (o1 <= o2) { int mx = i - o1, mn = i - o2; v += pa[mx] - (mn >= 4 ? pa[mn - 4] : 0.f); }
    }
    {
      int o1 = lo + ((1 - lo) & 3), o2 = hi - ((hi - 1) & 3);
      if (o1 <= o2) { int mx = jc - o1, mn = jc - o2; v += pa[mx] - (mn >= 4 ? pa[mn - 4] : 0.f); }
    }
    {
      int o1 = lo + ((2 - lo) & 3), o2 = hi - ((hi - 2) & 3);
      if (o1 <= o2) { int mx = i - o1, mn = i - o2; v += parev[mx] - (mn >= 4 ? parev[mn - 4] : 0.f); }
    }
    {
      int o1 = lo + ((3 - lo) & 3), o2 = hi - ((hi - 3) & 3);
      if (o1 <= o2) { int mx = jc - o1, mn = jc - o2; v += parev[mx] - (mn >= 4 ? parev[mn - 4] : 0.f); }
    }
    if (i == jc) {
      {
        int o1 = lo + ((0 - lo) & 3), o2 = hi - ((hi - 0) & 3);
        if (o1 <= o2) { int mx = i - o1, mn = i - o2; v += pd[mx] - (mn >= 4 ? pd[mn - 4] : 0.f); }
      }
      {
        int o1 = lo + ((2 - lo) & 3), o2 = hi - ((hi - 2) & 3);
        if (o1 <= o2) { int mx = i - o1, mn = i - o2; v += pdrev[mx] - (mn >= 4 ? pdrev[mn - 4] : 0.f); }
      }
    }
    const int m2 = i + jc - 511;
    if (m2 >= 0 && !(m2 & 1)) {
      const int os = m2 >> 1;
      if (os >= lo && os <= hi) {
        const int r = os & 3;
        if (r == 1) v += sdl[jc - os];
        else if (r == 3) v += sdl[511 - (jc - os)];
      }
    }
    acc[c] = v;
  }

  if (CL > CH) {
#pragma unroll
    for (int c = 0; c < 4; ++c) {
      const int jc = j0 + c;
      for (int o = lo_[c]; o <= hi_[c]; ++o) {
        const int r = o & 3;
        acc[c] += upf[o] * arr4[r][jc - o + r];
      }
    }
  } else {
#pragma unroll
    for (int c = 0; c < 4; ++c) {
      const int jc = j0 + c;
      const int he = min(hi_[c], CL - 1);
      for (int o = lo_[c]; o <= he; ++o) {
        const int r = o & 3;
        acc[c] += upf[o] * arr4[r][jc - o + r];
      }
      const int ls = max(lo_[c], CH + 1);
      for (int o = ls; o <= hi_[c]; ++o) {
        const int r = o & 3;
        acc[c] += upf[o] * arr4[r][jc - o + r];
      }
    }
    const int QL = (CL + 3) & ~3;
    for (int o = CL; o < QL && o <= CH; ++o) {
      const int r = o & 3;
      const float uvv = upf[o];
      const float4 wv = *(const float4*)&arr4[r][j0 - o + r];
      acc[0] += uvv * wv.x; acc[1] += uvv * wv.y;
      acc[2] += uvv * wv.z; acc[3] += uvv * wv.w;
    }
    int ob = QL;
    for (; ob + 3 <= CH; ob += 4) {
      const float4 uv = up[ob >> 2];
      const int x = j0 - ob;
      const float4 w0 = *(const float4*)&arr4[0][x];
      const float4 w1 = *(const float4*)&arr4[1][x];
      const float4 w2 = *(const float4*)&arr4[2][x];
      const float4 w3 = *(const float4*)&arr4[3][x];
      acc[0] += uv.x * w0.x + uv.y * w1.x + uv.z * w2.x + uv.w * w3.x;
      acc[1] += uv.x * w0.y + uv.y * w1.y + uv.z * w2.y + uv.w * w3.y;
      acc[2] += uv.x * w0.z + uv.y * w1.z + uv.z * w2.z + uv.w * w3.z;
      acc[3] += uv.x * w0.w + uv.y * w1.w + uv.z * w2.w + uv.w * w3.w;
    }
    for (int o = ob; o <= CH; ++o) {
      const int r = o & 3;
      const float uvv = upf[o];
      const float4 wv = *(const float4*)&arr4[r][j0 - o + r];
      acc[0] += uvv * wv.x; acc[1] += uvv * wv.y;
      acc[2] += uvv * wv.z; acc[3] += uvv * wv.w;
    }
  }

  const size_t off = ((size_t)mat << 20) + ((size_t)i << 10) + (size_t)j0;
  union { bf16 v[4]; ushort4 s; } Hu, Lu;
#pragma unroll
  for (int c = 0; c < 4; ++c) {
    const bf16 hb = __float2bfloat16(acc[c]);
    Hu.v[c] = hb;
    Lu.v[c] = __float2bfloat16(acc[c] - __bfloat162float(hb));
  }
  *(ushort4*)(Lh + off) = Hu.s;
  *(ushort4*)(Ll + off) = Lu.s;
}

// ---------------------------------------------------------------------------
// split fp32 -> hi bf16 only (x-side is single-bf16 in the 2-pass GEMM)
// ---------------------------------------------------------------------------
__global__ void splith_kernel(const float* __restrict__ x, bf16* __restrict__ h) {
  const int n4 = BATCH * NFEAT / 4;
  int idx = blockIdx.x * blockDim.x + threadIdx.x;
  int stride = gridDim.x * blockDim.x;
  for (int i = idx; i < n4; i += stride) {
    float4 v = ((const float4*)x)[i];
    union { bf16 b[4]; short4 s; } Hu;
    Hu.b[0] = __float2bfloat16(v.x);
    Hu.b[1] = __float2bfloat16(v.y);
    Hu.b[2] = __float2bfloat16(v.z);
    Hu.b[3] = __float2bfloat16(v.w);
    ((short4*)h)[i] = Hu.s;
  }
}

// ---------------------------------------------------------------------------
// batched transpose (z selects set): D = S^T for 1024x1024 bf16 pair.
// ---------------------------------------------------------------------------
__global__ __launch_bounds__(256) void transpose2_kernel(
    const bf16* __restrict__ S0h, const bf16* __restrict__ S0l,
    bf16* __restrict__ D0h, bf16* __restrict__ D0l,
    const bf16* __restrict__ S1h, const bf16* __restrict__ S1l,
    bf16* __restrict__ D1h, bf16* __restrict__ D1l) {
  const bf16* Sh = blockIdx.z ? S1h : S0h;
  const bf16* Sl = blockIdx.z ? S1l : S0l;
  bf16* Dh = blockIdx.z ? D1h : D0h;
  bf16* Dl = blockIdx.z ? D1l : D0l;
  __shared__ ushort th[64][72], tl[64][72];
  const int i0 = blockIdx.x * 64, j0 = blockIdx.y * 64;
  const int tid = threadIdx.x;
  const int rr = tid >> 4;
  const int cc = (tid & 15) * 4;
#pragma unroll
  for (int it = 0; it < 4; ++it) {
    const int row = it * 16 + rr;
    const size_t so = (size_t)(i0 + row) * 1024 + j0 + cc;
    ushort4 vh = *(const ushort4*)((const ushort*)Sh + so);
    ushort4 vl = *(const ushort4*)((const ushort*)Sl + so);
    th[row][cc] = vh.x; th[row][cc + 1] = vh.y; th[row][cc + 2] = vh.z; th[row][cc + 3] = vh.w;
    tl[row][cc] = vl.x; tl[row][cc + 1] = vl.y; tl[row][cc + 2] = vl.z; tl[row][cc + 3] = vl.w;
  }
  __syncthreads();
#pragma unroll
  for (int it = 0; it < 4; ++it) {
    const int row = it * 16 + rr;
    ushort4 oh, ol;
    oh.x = th[cc][row];     oh.y = th[cc + 1][row];
    oh.z = th[cc + 2][row]; oh.w = th[cc + 3][row];
    ol.x = tl[cc][row];     ol.y = tl[cc + 1][row];
    ol.z = tl[cc + 2][row]; ol.w = tl[cc + 3][row];
    const size_t dofs = (size_t)(j0 + row) * 1024 + i0 + cc;
    *(ushort4*)((ushort*)Dh + dofs) = oh;
    *(ushort4*)((ushort*)Dl + dofs) = ol;
  }
}

// ---------------------------------------------------------------------------
// batched chain GEMM (z selects set): Y = A * B^T, 1024x1024 split operands,
// split output. 64x64 tile, 4 waves, BK=64. 3-pass (high precision).
// Internals identical to R8's validated chaingemm.
// ---------------------------------------------------------------------------
__global__ __launch_bounds__(256) void chaingemm2_kernel(
    const bf16* __restrict__ A0h, const bf16* __restrict__ A0l,
    const bf16* __restrict__ B0h, const bf16* __restrict__ B0l,
    bf16* __restrict__ Y0h, bf16* __restrict__ Y0l,
    const bf16* __restrict__ A1h, const bf16* __restrict__ A1l,
    const bf16* __restrict__ B1h, const bf16* __restrict__ B1l,
    bf16* __restrict__ Y1h, bf16* __restrict__ Y1l) {
  const bf16* Ah = blockIdx.z ? A1h : A0h;
  const bf16* Al = blockIdx.z ? A1l : A0l;
  const bf16* Bh = blockIdx.z ? B1h : B0h;
  const bf16* Bl = blockIdx.z ? B1l : B0l;
  bf16* Yh = blockIdx.z ? Y1h : Y0h;
  bf16* Yl = blockIdx.z ? Y1l : Y0l;

  __shared__ __align__(16) bf16 s[4][4096];

  const int tid = threadIdx.x;
  const int lane = tid & 63;
  const int wave = tid >> 6;
  const int wr = wave >> 1, wc = wave & 1;
  const int r0 = blockIdx.x * 64, c0 = blockIdx.y * 64;
  const int srow = tid >> 3;
  const int sc = (tid & 7) * 8;
  const int dst = tid * 8;
  const int l31 = lane & 31;
  const int kh = (lane >> 5) * 8;

  f32x16 acc = {};

  for (int t = 0; t < 16; ++t) {
    const int k0 = t * 64;
    __syncthreads();
#pragma unroll
    for (int q = 0; q < 2; ++q) {
      const size_t ga = (size_t)(r0 + q * 32 + srow) * 1024 + sc + k0;
      const size_t gb = (size_t)(c0 + q * 32 + srow) * 1024 + sc + k0;
      gload16(&s[0][q * 2048 + dst], Ah + ga);
      gload16(&s[1][q * 2048 + dst], Al + ga);
      gload16(&s[2][q * 2048 + dst], Bh + gb);
      gload16(&s[3][q * 2048 + dst], Bl + gb);
    }
    asm volatile("s_waitcnt vmcnt(0)" ::: "memory");
    __syncthreads();

    const int ar = wr * 32 + l31;
    const int br = wc * 32 + l31;
#pragma unroll
    for (int ks = 0; ks < 4; ++ks) {
      bf16x8 ah = *(const bf16x8*)&s[0][ar * 64 + ks * 16 + kh];
      bf16x8 al = *(const bf16x8*)&s[1][ar * 64 + ks * 16 + kh];
      bf16x8 bh = *(const bf16x8*)&s[2][br * 64 + ks * 16 + kh];
      bf16x8 bl = *(const bf16x8*)&s[3][br * 64 + ks * 16 + kh];
      acc = __builtin_amdgcn_mfma_f32_32x32x16_bf16(ah, bh, acc, 0, 0, 0);
      acc = __builtin_amdgcn_mfma_f32_32x32x16_bf16(ah, bl, acc, 0, 0, 0);
      acc = __builtin_amdgcn_mfma_f32_32x32x16_bf16(al, bh, acc, 0, 0, 0);
    }
  }

  const int oc = c0 + wc * 32 + l31;
  const int rb = (lane >> 5) << 2;
#pragma unroll
  for (int r = 0; r < 16; ++r) {
    const int gr = r0 + wr * 32 + (r & 3) + ((r >> 2) << 3) + rb;
    const size_t off = (size_t)gr * 1024 + oc;
    const float v = acc[r];
    const bf16 hb = __float2bfloat16(v);
    Yh[off] = hb;
    Yl[off] = __float2bfloat16(v - __bfloat162float(hb));
  }
}

// ---------------------------------------------------------------------------
// fused 2-pass big GEMM: Y[r][c] = sum_k xh[r][k] * Mcat[c][k], c in [0,2048)
//   c <  1024 -> O0[r][c]        (bottleneck = x Menc^T)
//   c >= 1024 -> O1[r][c-1024]   (out        = x Mtot^T)
// acc += A*Bh + A*Bl (fp32). 256x256 tile, BK=32, 8 waves, dbuf LDS (96KB),
// 2 phases/tile, early staging, raw s_barrier + setprio.
// Block swizzle (R5-style): each XCD owns one 256-col panel (B L2-resident),
// streams all 64 row-chunks.
// ---------------------------------------------------------------------------
__global__ __launch_bounds__(512, 1) void gemmbig_kernel(
    const bf16* __restrict__ A, const bf16* __restrict__ Bh_,
    const bf16* __restrict__ Bl_, float* __restrict__ Y0,
    float* __restrict__ Y1) {
  __shared__ __align__(16) bf16 smem[2 * 3 * 8192];  // 96 KiB

  const int tid = threadIdx.x;
  const int lane = tid & 63;
  const int wave = tid >> 6;
  const int wr = wave >> 2;
  const int wc = wave & 3;

  // grid (64, 8) -> 512 blocks; XCD k owns col-panel k.
  const int pdisp = blockIdx.x + (blockIdx.y << 6);
  const int xcd = pdisp & 7;
  const int chk = pdisp >> 3;          // 0..63
  const int row0 = chk * 256;
  const int col0 = xcd * 256;          // 0..1792 (B row index into Mcat)

  const int gsrc = (tid & 3) ^ ((tid >> 3) & 3);
  const int dst = tid * 8;
  const size_t abase = (size_t)(row0 + (tid >> 2)) * NFEAT + gsrc * 8;
  const size_t bbase = (size_t)(col0 + (tid >> 2)) * NFEAT + gsrc * 8;

  auto STAGE2 = [&](int nb, int arr, const bf16* __restrict__ src, size_t base, int k0) {
    bf16* d = smem + nb * 24576 + arr * 8192 + dst;
    gload16(d, src + base + k0);
    gload16(d + 4096, src + base + 131072 + k0);
  };

  const int l31 = lane & 31;
  const int hb = lane >> 5;
  int aoffB[4][2], boffB[2][2];
#pragma unroll
  for (int m = 0; m < 4; ++m) {
    const int r = wr * 128 + m * 32 + l31;
#pragma unroll
    for (int ks = 0; ks < 2; ++ks)
      aoffB[m][ks] = r * 64 + ((((ks << 1) | hb) ^ ((r >> 1) & 3)) << 4);
  }
#pragma unroll
  for (int n = 0; n < 2; ++n) {
    const int r = wc * 64 + n * 32 + l31;
#pragma unroll
    for (int ks = 0; ks < 2; ++ks)
      boffB[n][ks] = r * 64 + ((((ks << 1) | hb) ^ ((r >> 1) & 3)) << 4);
  }

  auto LD = [](const char* base, int off) { return *(const bf16x8*)(base + off); };

  f32x16 acc[4][2] = {};

  STAGE2(0, 0, A, abase, 0);
  STAGE2(0, 1, Bh_, bbase, 0);
  STAGE2(0, 2, Bl_, bbase, 0);
  asm volatile("s_waitcnt vmcnt(0)" ::: "memory");
  __builtin_amdgcn_s_barrier();

  for (int t = 0; t < 32; ++t) {
    const int buf = t & 1;
    const int nb = buf ^ 1;
    const int k1 = (t + 1) * 32;
    const char* pA = (const char*)(smem + buf * 24576);
    const char* pBh = pA + 16384;
    const char* pBl = pA + 32768;
    const bool pf = (t < 31);

    bf16x8 ga[2][2], fbh[2][2], fbl[2][2];

    // ---- Phase 0: stage all for t+1; A m0/m1 + all B; MFMA ----
    if (pf) {
      STAGE2(nb, 0, A, abase, k1);
      STAGE2(nb, 1, Bh_, bbase, k1);
      STAGE2(nb, 2, Bl_, bbase, k1);
    }
#pragma unroll
    for (int mi = 0; mi < 2; ++mi)
#pragma unroll
      for (int ks = 0; ks < 2; ++ks)
        ga[mi][ks] = LD(pA, aoffB[mi][ks]);
#pragma unroll
    for (int n = 0; n < 2; ++n)
#pragma unroll
      for (int ks = 0; ks < 2; ++ks) {
        fbh[n][ks] = LD(pBh, boffB[n][ks]);
        fbl[n][ks] = LD(pBl, boffB[n][ks]);
      }
    __builtin_amdgcn_s_barrier();
    __builtin_amdgcn_s_setprio(1);
#pragma unroll
    for (int ks = 0; ks < 2; ++ks)
#pragma unroll
      for (int mi = 0; mi < 2; ++mi)
#pragma unroll
        for (int n = 0; n < 2; ++n) {
          acc[mi][n] = __builtin_amdgcn_mfma_f32_32x32x16_bf16(ga[mi][ks], fbh[n][ks], acc[mi][n], 0, 0, 0);
          acc[mi][n] = __builtin_amdgcn_mfma_f32_32x32x16_bf16(ga[mi][ks], fbl[n][ks], acc[mi][n], 0, 0, 0);
        }
    __builtin_amdgcn_s_setprio(0);
    __builtin_amdgcn_s_barrier();

    // ---- Phase 1: A m2/m3; MFMA with cached B frags ----
#pragma unroll
    for (int mi = 0; mi < 2; ++mi)
#pragma unroll
      for (int ks = 0; ks < 2; ++ks)
        ga[mi][ks] = LD(pA, aoffB[2 + mi][ks]);
    __builtin_amdgcn_s_barrier();
    __builtin_amdgcn_s_setprio(1);
#pragma unroll
    for (int ks = 0; ks < 2; ++ks)
#pragma unroll
      for (int mi = 0; mi < 2; ++mi)
#pragma unroll
        for (int n = 0; n < 2; ++n) {
          acc[2 + mi][n] = __builtin_amdgcn_mfma_f32_32x32x16_bf16(ga[mi][ks], fbh[n][ks], acc[2 + mi][n], 0, 0, 0);
          acc[2 + mi][n] = __builtin_amdgcn_mfma_f32_32x32x16_bf16(ga[mi][ks], fbl[n][ks], acc[2 + mi][n], 0, 0, 0);
        }
    __builtin_amdgcn_s_setprio(0);
    if (pf) asm volatile("s_waitcnt vmcnt(0)" ::: "memory");
    __builtin_amdgcn_s_barrier();
  }

  // epilogue: 32x32 C/D: col = lane&31, row = (r&3)+8*(r>>2)+4*(lane>>5)
  float* Yb = (col0 < 1024) ? Y0 : (Y1 - 1024);
  const int ocol0 = col0 + wc * 64 + l31;
  const int rb = (lane >> 5) << 2;
#pragma unroll
  for (int m = 0; m < 4; ++m)
#pragma unroll
    for (int n = 0; n < 2; ++n)
#pragma unroll
      for (int r = 0; r < 16; ++r) {
        const int grow = row0 + wr * 128 + m * 32 + (r & 3) + ((r >> 2) << 3) + rb;
        const int gcol = ocol0 + n * 32;
        Yb[(size_t)grow * NFEAT + (size_t)gcol] = acc[m][n][r];
      }
}

// ---------------------------------------------------------------------------
// launch: build 8 L's -> fold to Menc, Mdec, Mtot = Mdec*Menc ->
// ONE fused big GEMM produces both outputs from x.
// ---------------------------------------------------------------------------
extern "C" void kernel_launch(void* const* d_in, const int* in_sizes, int n_in,
                              void* d_out, int out_size, void* d_ws, size_t ws_size,
                              hipStream_t stream) {
  (void)in_sizes; (void)n_in; (void)out_size; (void)ws_size;
  const float* x  = (const float*)d_in[0];
  const float* er = (const float*)d_in[1];
  const float* ed = (const float*)d_in[2];
  const float* dr = (const float*)d_in[3];
  const float* dd = (const float*)d_in[4];

  float* O0 = (float*)d_out;                       // bottleneck (fp32, 64 MB)
  float* O1 = O0 + (size_t)BATCH * NFEAT;          // out (fp32, 64 MB)

  const size_t LM = (size_t)1 << 20;  // elems per 1024x1024 matrix

  // d_ws: Lh (16MB) | Ll (16MB) | ab (32KB) | Qh (32MB)
  bf16* Lh = (bf16*)d_ws;
  bf16* Ll = Lh + 8 * LM;
  float* ab = (float*)(Ll + 8 * LM);
  bf16* Qh = (bf16*)(ab + 8 * 1024);

  // O0 region scratch (fully consumed before the big GEMM writes O0):
  // Tpref @0 (64KB); 16 chain slots @1MB (32MB).
  float* Tpref = O0;
  bf16* SB = (bf16*)((char*)O0 + (1 << 20));
  auto slot = [&](int s) { return SB + (size_t)s * LM; };
  bf16 *TheH = slot(0), *TheL = slot(1), *ThdH = slot(2), *ThdL = slot(3);
  bf16 *KaeH = slot(4), *KaeL = slot(5), *KadH = slot(6), *KadL = slot(7);
  bf16 *KbeH = slot(8), *KbeL = slot(9), *KbdH = slot(10), *KbdL = slot(11);
  bf16 *KceH = slot(12), *KceL = slot(13), *KcdH = slot(14), *KcdL = slot(15);

  // After the chain, all L slots are dead: Mcat (2048x1024 h+l) and Mdec
  // live in the Lh/Ll regions.
  bf16* McatH = Lh;              // rows 0-1023 = Menc, 1024-2047 = Mtot
  bf16* McatL = Lh + 2 * LM;
  bf16* MdH = Ll;
  bf16* MdL = Ll + LM;

  prep_kernel<<<8, 64, 0, stream>>>(er, ed, dr, dd, ab);
  prep2_kernel<<<8, 256, 0, stream>>>(er, ed, dr, dd, ab, Tpref);
  build_kernel<<<dim3(1024, 8), 256, 0, stream>>>(er, ed, dr, dd, ab, Tpref, Lh, Ll);
  splith_kernel<<<4096, 256, 0, stream>>>(x, Qh);

  const dim3 tg2(16, 16, 2);
  const dim3 tg1(16, 16, 1);
  // batched chains: enc (z=0) uses L1..L4, dec (z=1) uses L5..L8.
  transpose2_kernel<<<tg2, 256, 0, stream>>>(
      Lh + 0 * LM, Ll + 0 * LM, TheH, TheL,
      Lh + 4 * LM, Ll + 4 * LM, ThdH, ThdL);
  chaingemm2_kernel<<<tg2, 256, 0, stream>>>(
      TheH, TheL, Lh + 1 * LM, Ll + 1 * LM, KaeH, KaeL,
      ThdH, ThdL, Lh + 5 * LM, Ll + 5 * LM, KadH, KadL);
  chaingemm2_kernel<<<tg2, 256, 0, stream>>>(
      KaeH, KaeL, Lh + 2 * LM, Ll + 2 * LM, KbeH, KbeL,
      KadH, KadL, Lh + 6 * LM, Ll + 6 * LM, KbdH, KbdL);
  chaingemm2_kernel<<<tg2, 256, 0, stream>>>(
      KbeH, KbeL, Lh + 3 * LM, Ll + 3 * LM, KceH, KceL,
      KbdH, KbdL, Lh + 7 * LM, Ll + 7 * LM, KcdH, KcdL);
  // Kce = Menc^T, Kcd = Mdec^T.  Menc -> Mcat rows 0-1023; Mdec -> MdH/MdL.
  transpose2_kernel<<<tg2, 256, 0, stream>>>(
      KceH, KceL, McatH, McatL,
      KcdH, KcdL, MdH, MdL);
  // Mtot = Mdec * Menc = chaingemm(Mdec, Kce) -> Mcat rows 1024-2047.
  chaingemm2_kernel<<<tg1, 256, 0, stream>>>(
      MdH, MdL, KceH, KceL, McatH + LM, McatL + LM,
      MdH, MdL, KceH, KceL, McatH + LM, McatL + LM);

  // fused big GEMM: both outputs from x in one dispatch.
  gemmbig_kernel<<<dim3(64, 8), 512, 0, stream>>>(Qh, McatH, McatL, O0, O1);
}

// Round 10
// 344.304 us; speedup vs baseline: 2.6801x; 1.1540x over previous
//
#include <hip/hip_runtime.h>
#include <hip/hip_bf16.h>
#include <cstdint>
#include <cstddef>

#define H 512
#define NFEAT 1024
#define BATCH 16384

using bf16 = __hip_bfloat16;
using bf16x8 = __attribute__((ext_vector_type(8))) __bf16;
using f32x4 = __attribute__((ext_vector_type(4))) float;
using f32x16 = __attribute__((ext_vector_type(16))) float;

// ---------------------------------------------------------------------------
// async global -> LDS, 16 bytes per lane
// ---------------------------------------------------------------------------
__device__ __forceinline__ void gload16(void* lds, const void* g) {
  __builtin_amdgcn_global_load_lds(
      (__attribute__((address_space(1))) void*)g,
      (__attribute__((address_space(3))) void*)lds,
      16, 0, 0);
}

// ---------------------------------------------------------------------------
// prep: per matrix, compute a[], b[] for core = diag(d) + a*1^T + b*u^T
// Closed-form Cayley (rank-2 Woodbury), verified R0-R9.
// ---------------------------------------------------------------------------
__global__ void prep_kernel(const float* __restrict__ er, const float* __restrict__ ed,
                            const float* __restrict__ dr, const float* __restrict__ dd,
                            float* __restrict__ ab) {
  const int mat = blockIdx.x;          // 0..7
  const int lane = threadIdx.x;        // 0..63
  const float* u = (mat < 4) ? (er + mat * H) : (dr + (mat - 4) * H);
  const float* d = (mat < 4) ? (ed + mat * H) : (dd + (mat - 4) * H);

  double s = 0.0, q = 0.0;
  for (int k = 0; k < 8; ++k) {
    double v = (double)u[lane + 64 * k];
    s += v;
    q += v * v;
  }
  for (int off = 32; off; off >>= 1) {
    s += __shfl_down(s, off);
    q += __shfl_down(q, off);
  }
  s = __shfl(s, 0);
  q = __shfl(q, 0);

  const double det = 1.0 - s * s + (double)H * q;
  const double cuv = 2.0 * (1.0 + s) / det;
  const double cuu = -2.0 * (double)H / det;
  const double cvv = -2.0 * q / det;
  const double cvu = -2.0 * (1.0 - s) / det;

  float* a = ab + mat * 1024;
  float* b = a + H;
  for (int k = 0; k < 8; ++k) {
    int idx = lane + 64 * k;
    double ui = (double)u[idx], di = (double)d[idx];
    a[idx] = (float)(di * (cuv * ui + cvv));
    b[idx] = (float)(di * (cuu * ui + cvu));
  }
}

// ---------------------------------------------------------------------------
// prep2: stride-4-residue inclusive prefix tables over a, a_rev, d, d_rev.
// ---------------------------------------------------------------------------
__global__ __launch_bounds__(256) void prep2_kernel(
    const float* __restrict__ er, const float* __restrict__ ed,
    const float* __restrict__ dr, const float* __restrict__ dd,
    const float* __restrict__ ab, float* __restrict__ Tpref) {
  __shared__ float buf[4][512];
  __shared__ float tmp[4][512];
  const int mat = blockIdx.x;
  const float* d = (mat < 4) ? (ed + mat * H) : (dd + (mat - 4) * H);
  const float* a = ab + mat * 1024;
  const int t = threadIdx.x;
  for (int m = t; m < 512; m += 256) {
    buf[0][m] = a[m];
    buf[1][m] = a[511 - m];
    buf[2][m] = d[m];
    buf[3][m] = d[511 - m];
  }
  __syncthreads();
  for (int s = 4; s <= 256; s <<= 1) {
    for (int m = t; m < 512; m += 256)
#pragma unroll
      for (int q = 0; q < 4; ++q) tmp[q][m] = (m >= s) ? buf[q][m - s] : 0.f;
    __syncthreads();
    for (int m = t; m < 512; m += 256)
#pragma unroll
      for (int q = 0; q < 4; ++q) buf[q][m] += tmp[q][m];
    __syncthreads();
  }
  float* tp = Tpref + mat * 2048;
  for (int m = t; m < 512; m += 256) {
    tp[m] = buf[0][m];
    tp[512 + m] = buf[1][m];
    tp[1024 + m] = buf[2][m];
    tp[1536 + m] = buf[3][m];
  }
}

// ---------------------------------------------------------------------------
// build v3 (unchanged from R2): prefix tables + quad b*u loop.
// ---------------------------------------------------------------------------
__global__ __launch_bounds__(256) void build_kernel(
    const float* __restrict__ er, const float* __restrict__ ed,
    const float* __restrict__ dr, const float* __restrict__ dd,
    const float* __restrict__ ab, const float* __restrict__ Tpref,
    bf16* __restrict__ Lh, bf16* __restrict__ Ll) {
  __shared__ __align__(16) float arr4[4][520];
  __shared__ __align__(16) float4 up[132];
  __shared__ float pa[512], parev[512], pd[512], pdrev[512], sdl[512];

  const int i = blockIdx.x;
  const int mat = blockIdx.y;
  const float* u = (mat < 4) ? (er + mat * H) : (dr + (mat - 4) * H);
  const float* d = (mat < 4) ? (ed + mat * H) : (dd + (mat - 4) * H);
  const float* a = ab + mat * 1024;
  const float* b = a + H;
  const float* tp = Tpref + mat * 2048;
  const int t = threadIdx.x;

  for (int m = t; m < 520; m += 256) {
    arr4[0][m] = (m < 512) ? u[m] : 0.f;
    arr4[1][m] = (m >= 1 && m <= 512) ? b[m - 1] : 0.f;
    arr4[2][m] = (m >= 2 && m <= 513) ? u[513 - m] : 0.f;
    arr4[3][m] = (m >= 3 && m <= 514) ? b[514 - m] : 0.f;
  }
  for (int m = t; m < 512; m += 256) {
    pa[m] = tp[m];
    parev[m] = tp[512 + m];
    pd[m] = tp[1024 + m];
    pdrev[m] = tp[1536 + m];
    sdl[m] = d[m];
  }
  if (t < 132) {
    const int k4 = 4 * t;
    float4 v;
    int p0 = i - k4;
    v.x = (p0 >= 0 && p0 < 512) ? b[p0] : 0.f;
    int p1 = i - k4 - 1;
    v.y = (p1 >= 0 && p1 < 512) ? u[511 - p1] : 0.f;
    int p2 = i - k4 - 2;
    v.z = (p2 >= 0 && p2 < 512) ? b[511 - p2] : 0.f;
    int p3 = i - k4 - 3;
    v.w = (p3 >= 0 && p3 < 512) ? u[p3] : 0.f;
    up[t] = v;
  }
  __syncthreads();

  const float* upf = (const float*)up;
  const int j0 = t * 4;

  int lo_[4], hi_[4];
#pragma unroll
  for (int c = 0; c < 4; ++c) {
    const int jc = j0 + c;
    lo_[c] = max(0, max(i, jc) - 511);
    hi_[c] = min(512, min(i, jc));
  }
  const int CL = lo_[3];
  const int CH = hi_[0];

  float acc[4] = {0.f, 0.f, 0.f, 0.f};

#pragma unroll
  for (int c = 0; c < 4; ++c) {
    const int jc = j0 + c;
    const int lo = lo_[c], hi = hi_[c];
    if (lo > hi) continue;
    float v = 0.f;
    {
      int o1 = lo + ((0 - lo) & 3), o2 = hi - ((hi - 0) & 3);
      if (o1 <= o2) { int mx = i - o1, mn = i - o2; v += pa[mx] - (mn >= 4 ? pa[mn - 4] : 0.f); }
    }
    {
      int o1 = lo + ((1 - lo) & 3), o2 = hi - ((hi - 1) & 3);
      if (o1 <= o2) { int mx = jc - o1, mn = jc - o2; v += pa[mx] - (mn >= 4 ? pa[mn - 4] : 0.f); }
    }
    {
      int o1 = lo + ((2 - lo) & 3), o2 = hi - ((hi - 2) & 3);
      if (o1 <= o2) { int mx = i - o1, mn = i - o2; v += parev[mx] - (mn >= 4 ? parev[mn - 4] : 0.f); }
    }
    {
      int o1 = lo + ((3 - lo) & 3), o2 = hi - ((hi - 3) & 3);
      if (o1 <= o2) { int mx = jc - o1, mn = jc - o2; v += parev[mx] - (mn >= 4 ? parev[mn - 4] : 0.f); }
    }
    if (i == jc) {
      {
        int o1 = lo + ((0 - lo) & 3), o2 = hi - ((hi - 0) & 3);
        if (o1 <= o2) { int mx = i - o1, mn = i - o2; v += pd[mx] - (mn >= 4 ? pd[mn - 4] : 0.f); }
      }
      {
        int o1 = lo + ((2 - lo) & 3), o2 = hi - ((hi - 2) & 3);
        if (o1 <= o2) { int mx = i - o1, mn = i - o2; v += pdrev[mx] - (mn >= 4 ? pdrev[mn - 4] : 0.f); }
      }
    }
    const int m2 = i + jc - 511;
    if (m2 >= 0 && !(m2 & 1)) {
      const int os = m2 >> 1;
      if (os >= lo && os <= hi) {
        const int r = os & 3;
        if (r == 1) v += sdl[jc - os];
        else if (r == 3) v += sdl[511 - (jc - os)];
      }
    }
    acc[c] = v;
  }

  if (CL > CH) {
#pragma unroll
    for (int c = 0; c < 4; ++c) {
      const int jc = j0 + c;
      for (int o = lo_[c]; o <= hi_[c]; ++o) {
        const int r = o & 3;
        acc[c] += upf[o] * arr4[r][jc - o + r];
      }
    }
  } else {
#pragma unroll
    for (int c = 0; c < 4; ++c) {
      const int jc = j0 + c;
      const int he = min(hi_[c], CL - 1);
      for (int o = lo_[c]; o <= he; ++o) {
        const int r = o & 3;
        acc[c] += upf[o] * arr4[r][jc - o + r];
      }
      const int ls = max(lo_[c], CH + 1);
      for (int o = ls; o <= hi_[c]; ++o) {
        const int r = o & 3;
        acc[c] += upf[o] * arr4[r][jc - o + r];
      }
    }
    const int QL = (CL + 3) & ~3;
    for (int o = CL; o < QL && o <= CH; ++o) {
      const int r = o & 3;
      const float uvv = upf[o];
      const float4 wv = *(const float4*)&arr4[r][j0 - o + r];
      acc[0] += uvv * wv.x; acc[1] += uvv * wv.y;
      acc[2] += uvv * wv.z; acc[3] += uvv * wv.w;
    }
    int ob = QL;
    for (; ob + 3 <= CH; ob += 4) {
      const float4 uv = up[ob >> 2];
      const int x = j0 - ob;
      const float4 w0 = *(const float4*)&arr4[0][x];
      const float4 w1 = *(const float4*)&arr4[1][x];
      const float4 w2 = *(const float4*)&arr4[2][x];
      const float4 w3 = *(const float4*)&arr4[3][x];
      acc[0] += uv.x * w0.x + uv.y * w1.x + uv.z * w2.x + uv.w * w3.x;
      acc[1] += uv.x * w0.y + uv.y * w1.y + uv.z * w2.y + uv.w * w3.y;
      acc[2] += uv.x * w0.z + uv.y * w1.z + uv.z * w2.z + uv.w * w3.z;
      acc[3] += uv.x * w0.w + uv.y * w1.w + uv.z * w2.w + uv.w * w3.w;
    }
    for (int o = ob; o <= CH; ++o) {
      const int r = o & 3;
      const float uvv = upf[o];
      const float4 wv = *(const float4*)&arr4[r][j0 - o + r];
      acc[0] += uvv * wv.x; acc[1] += uvv * wv.y;
      acc[2] += uvv * wv.z; acc[3] += uvv * wv.w;
    }
  }

  const size_t off = ((size_t)mat << 20) + ((size_t)i << 10) + (size_t)j0;
  union { bf16 v[4]; ushort4 s; } Hu, Lu;
#pragma unroll
  for (int c = 0; c < 4; ++c) {
    const bf16 hb = __float2bfloat16(acc[c]);
    Hu.v[c] = hb;
    Lu.v[c] = __float2bfloat16(acc[c] - __bfloat162float(hb));
  }
  *(ushort4*)(Lh + off) = Hu.s;
  *(ushort4*)(Ll + off) = Lu.s;
}

// ---------------------------------------------------------------------------
// split fp32 -> hi bf16 only (x-side is single-bf16 in the big GEMM)
// ---------------------------------------------------------------------------
__global__ void splith_kernel(const float* __restrict__ x, bf16* __restrict__ h) {
  const int n4 = BATCH * NFEAT / 4;
  int idx = blockIdx.x * blockDim.x + threadIdx.x;
  int stride = gridDim.x * blockDim.x;
  for (int i = idx; i < n4; i += stride) {
    float4 v = ((const float4*)x)[i];
    union { bf16 b[4]; short4 s; } Hu;
    Hu.b[0] = __float2bfloat16(v.x);
    Hu.b[1] = __float2bfloat16(v.y);
    Hu.b[2] = __float2bfloat16(v.z);
    Hu.b[3] = __float2bfloat16(v.w);
    ((short4*)h)[i] = Hu.s;
  }
}

// ---------------------------------------------------------------------------
// batched transpose (z selects set): D = S^T for 1024x1024 bf16 pair.
// ---------------------------------------------------------------------------
__global__ __launch_bounds__(256) void transpose2_kernel(
    const bf16* __restrict__ S0h, const bf16* __restrict__ S0l,
    bf16* __restrict__ D0h, bf16* __restrict__ D0l,
    const bf16* __restrict__ S1h, const bf16* __restrict__ S1l,
    bf16* __restrict__ D1h, bf16* __restrict__ D1l) {
  const bf16* Sh = blockIdx.z ? S1h : S0h;
  const bf16* Sl = blockIdx.z ? S1l : S0l;
  bf16* Dh = blockIdx.z ? D1h : D0h;
  bf16* Dl = blockIdx.z ? D1l : D0l;
  __shared__ ushort th[64][72], tl[64][72];
  const int i0 = blockIdx.x * 64, j0 = blockIdx.y * 64;
  const int tid = threadIdx.x;
  const int rr = tid >> 4;
  const int cc = (tid & 15) * 4;
#pragma unroll
  for (int it = 0; it < 4; ++it) {
    const int row = it * 16 + rr;
    const size_t so = (size_t)(i0 + row) * 1024 + j0 + cc;
    ushort4 vh = *(const ushort4*)((const ushort*)Sh + so);
    ushort4 vl = *(const ushort4*)((const ushort*)Sl + so);
    th[row][cc] = vh.x; th[row][cc + 1] = vh.y; th[row][cc + 2] = vh.z; th[row][cc + 3] = vh.w;
    tl[row][cc] = vl.x; tl[row][cc + 1] = vl.y; tl[row][cc + 2] = vl.z; tl[row][cc + 3] = vl.w;
  }
  __syncthreads();
#pragma unroll
  for (int it = 0; it < 4; ++it) {
    const int row = it * 16 + rr;
    ushort4 oh, ol;
    oh.x = th[cc][row];     oh.y = th[cc + 1][row];
    oh.z = th[cc + 2][row]; oh.w = th[cc + 3][row];
    ol.x = tl[cc][row];     ol.y = tl[cc + 1][row];
    ol.z = tl[cc + 2][row]; ol.w = tl[cc + 3][row];
    const size_t dofs = (size_t)(j0 + row) * 1024 + i0 + cc;
    *(ushort4*)((ushort*)Dh + dofs) = oh;
    *(ushort4*)((ushort*)Dl + dofs) = ol;
  }
}

// ---------------------------------------------------------------------------
// batched chain GEMM (z selects set): Y = A * B^T, 1024x1024 split operands,
// split output. 64x64 tile, 4 waves, BK=64. 3-pass (high precision).
// ---------------------------------------------------------------------------
__global__ __launch_bounds__(256) void chaingemm2_kernel(
    const bf16* __restrict__ A0h, const bf16* __restrict__ A0l,
    const bf16* __restrict__ B0h, const bf16* __restrict__ B0l,
    bf16* __restrict__ Y0h, bf16* __restrict__ Y0l,
    const bf16* __restrict__ A1h, const bf16* __restrict__ A1l,
    const bf16* __restrict__ B1h, const bf16* __restrict__ B1l,
    bf16* __restrict__ Y1h, bf16* __restrict__ Y1l) {
  const bf16* Ah = blockIdx.z ? A1h : A0h;
  const bf16* Al = blockIdx.z ? A1l : A0l;
  const bf16* Bh = blockIdx.z ? B1h : B0h;
  const bf16* Bl = blockIdx.z ? B1l : B0l;
  bf16* Yh = blockIdx.z ? Y1h : Y0h;
  bf16* Yl = blockIdx.z ? Y1l : Y0l;

  __shared__ __align__(16) bf16 s[4][4096];

  const int tid = threadIdx.x;
  const int lane = tid & 63;
  const int wave = tid >> 6;
  const int wr = wave >> 1, wc = wave & 1;
  const int r0 = blockIdx.x * 64, c0 = blockIdx.y * 64;
  const int srow = tid >> 3;
  const int sc = (tid & 7) * 8;
  const int dst = tid * 8;
  const int l31 = lane & 31;
  const int kh = (lane >> 5) * 8;

  f32x16 acc = {};

  for (int t = 0; t < 16; ++t) {
    const int k0 = t * 64;
    __syncthreads();
#pragma unroll
    for (int q = 0; q < 2; ++q) {
      const size_t ga = (size_t)(r0 + q * 32 + srow) * 1024 + sc + k0;
      const size_t gb = (size_t)(c0 + q * 32 + srow) * 1024 + sc + k0;
      gload16(&s[0][q * 2048 + dst], Ah + ga);
      gload16(&s[1][q * 2048 + dst], Al + ga);
      gload16(&s[2][q * 2048 + dst], Bh + gb);
      gload16(&s[3][q * 2048 + dst], Bl + gb);
    }
    asm volatile("s_waitcnt vmcnt(0)" ::: "memory");
    __syncthreads();

    const int ar = wr * 32 + l31;
    const int br = wc * 32 + l31;
#pragma unroll
    for (int ks = 0; ks < 4; ++ks) {
      bf16x8 ah = *(const bf16x8*)&s[0][ar * 64 + ks * 16 + kh];
      bf16x8 al = *(const bf16x8*)&s[1][ar * 64 + ks * 16 + kh];
      bf16x8 bh = *(const bf16x8*)&s[2][br * 64 + ks * 16 + kh];
      bf16x8 bl = *(const bf16x8*)&s[3][br * 64 + ks * 16 + kh];
      acc = __builtin_amdgcn_mfma_f32_32x32x16_bf16(ah, bh, acc, 0, 0, 0);
      acc = __builtin_amdgcn_mfma_f32_32x32x16_bf16(ah, bl, acc, 0, 0, 0);
      acc = __builtin_amdgcn_mfma_f32_32x32x16_bf16(al, bh, acc, 0, 0, 0);
    }
  }

  const int oc = c0 + wc * 32 + l31;
  const int rb = (lane >> 5) << 2;
#pragma unroll
  for (int r = 0; r < 16; ++r) {
    const int gr = r0 + wr * 32 + (r & 3) + ((r >> 2) << 3) + rb;
    const size_t off = (size_t)gr * 1024 + oc;
    const float v = acc[r];
    const bf16 hb = __float2bfloat16(v);
    Yh[off] = hb;
    Yl[off] = __float2bfloat16(v - __bfloat162float(hb));
  }
}

// ---------------------------------------------------------------------------
// fused SINGLE-PASS big GEMM: Y[r][c] = sum_k xh[r][k] * Mcat_h[c][k]
//   c <  1024 -> O0[r][c]        (bottleneck = x Menc^T)
//   c >= 1024 -> O1[r][c-1024]   (out        = x Mtot^T)
// Pure bf16 x bf16 -> fp32 accum (precision margin: error ~0.02% of output
// max vs 2% threshold; chain stays 3-pass).
// 256x256 tile, BK=32, 8 waves, dbuf LDS (64KB), 2 phases/tile, early
// staging, raw s_barrier + setprio.
// Swizzle: XCD = pdisp&7 owns ROW-octant (A chunk L2-resident, read once);
// col-panels cycle fast (B = 4MB total, L2/L3-resident).
// ---------------------------------------------------------------------------
__global__ __launch_bounds__(512, 1) void gemmbig_kernel(
    const bf16* __restrict__ A, const bf16* __restrict__ Bh_,
    float* __restrict__ Y0, float* __restrict__ Y1) {
  __shared__ __align__(16) bf16 smem[2 * 2 * 8192];  // 64 KiB

  const int tid = threadIdx.x;
  const int lane = tid & 63;
  const int wave = tid >> 6;
  const int wr = wave >> 2;
  const int wc = wave & 3;

  // grid (64, 8) -> 512 blocks; XCD k owns row-octant k, cycles col panels.
  const int pdisp = blockIdx.x + (blockIdx.y << 6);
  const int xcd = pdisp & 7;
  const int chk = pdisp >> 3;          // 0..63
  const int row0 = (xcd * 8 + (chk >> 3)) * 256;
  const int col0 = (chk & 7) * 256;    // B row index into Mcat (0..1792)

  const int gsrc = (tid & 3) ^ ((tid >> 3) & 3);
  const int dst = tid * 8;
  const size_t abase = (size_t)(row0 + (tid >> 2)) * NFEAT + gsrc * 8;
  const size_t bbase = (size_t)(col0 + (tid >> 2)) * NFEAT + gsrc * 8;

  auto STAGE2 = [&](int nb, int arr, const bf16* __restrict__ src, size_t base, int k0) {
    bf16* d = smem + nb * 16384 + arr * 8192 + dst;
    gload16(d, src + base + k0);
    gload16(d + 4096, src + base + 131072 + k0);
  };

  const int l31 = lane & 31;
  const int hb = lane >> 5;
  int aoffB[4][2], boffB[2][2];
#pragma unroll
  for (int m = 0; m < 4; ++m) {
    const int r = wr * 128 + m * 32 + l31;
#pragma unroll
    for (int ks = 0; ks < 2; ++ks)
      aoffB[m][ks] = r * 64 + ((((ks << 1) | hb) ^ ((r >> 1) & 3)) << 4);
  }
#pragma unroll
  for (int n = 0; n < 2; ++n) {
    const int r = wc * 64 + n * 32 + l31;
#pragma unroll
    for (int ks = 0; ks < 2; ++ks)
      boffB[n][ks] = r * 64 + ((((ks << 1) | hb) ^ ((r >> 1) & 3)) << 4);
  }

  auto LD = [](const char* base, int off) { return *(const bf16x8*)(base + off); };

  f32x16 acc[4][2] = {};

  STAGE2(0, 0, A, abase, 0);
  STAGE2(0, 1, Bh_, bbase, 0);
  asm volatile("s_waitcnt vmcnt(0)" ::: "memory");
  __builtin_amdgcn_s_barrier();

  for (int t = 0; t < 32; ++t) {
    const int buf = t & 1;
    const int nb = buf ^ 1;
    const int k1 = (t + 1) * 32;
    const char* pA = (const char*)(smem + buf * 16384);
    const char* pBh = pA + 16384;
    const bool pf = (t < 31);

    bf16x8 ga[2][2], fbh[2][2];

    // ---- Phase 0: stage all for t+1; A m0/m1 + all B; MFMA ----
    if (pf) {
      STAGE2(nb, 0, A, abase, k1);
      STAGE2(nb, 1, Bh_, bbase, k1);
    }
#pragma unroll
    for (int mi = 0; mi < 2; ++mi)
#pragma unroll
      for (int ks = 0; ks < 2; ++ks)
        ga[mi][ks] = LD(pA, aoffB[mi][ks]);
#pragma unroll
    for (int n = 0; n < 2; ++n)
#pragma unroll
      for (int ks = 0; ks < 2; ++ks)
        fbh[n][ks] = LD(pBh, boffB[n][ks]);
    __builtin_amdgcn_s_barrier();
    __builtin_amdgcn_s_setprio(1);
#pragma unroll
    for (int ks = 0; ks < 2; ++ks)
#pragma unroll
      for (int mi = 0; mi < 2; ++mi)
#pragma unroll
        for (int n = 0; n < 2; ++n)
          acc[mi][n] = __builtin_amdgcn_mfma_f32_32x32x16_bf16(ga[mi][ks], fbh[n][ks], acc[mi][n], 0, 0, 0);
    __builtin_amdgcn_s_setprio(0);
    __builtin_amdgcn_s_barrier();

    // ---- Phase 1: A m2/m3; MFMA with cached B frags ----
#pragma unroll
    for (int mi = 0; mi < 2; ++mi)
#pragma unroll
      for (int ks = 0; ks < 2; ++ks)
        ga[mi][ks] = LD(pA, aoffB[2 + mi][ks]);
    __builtin_amdgcn_s_barrier();
    __builtin_amdgcn_s_setprio(1);
#pragma unroll
    for (int ks = 0; ks < 2; ++ks)
#pragma unroll
      for (int mi = 0; mi < 2; ++mi)
#pragma unroll
        for (int n = 0; n < 2; ++n)
          acc[2 + mi][n] = __builtin_amdgcn_mfma_f32_32x32x16_bf16(ga[mi][ks], fbh[n][ks], acc[2 + mi][n], 0, 0, 0);
    __builtin_amdgcn_s_setprio(0);
    if (pf) asm volatile("s_waitcnt vmcnt(0)" ::: "memory");
    __builtin_amdgcn_s_barrier();
  }

  // epilogue: 32x32 C/D: col = lane&31, row = (r&3)+8*(r>>2)+4*(lane>>5)
  float* Yb = (col0 < 1024) ? Y0 : (Y1 - 1024);
  const int ocol0 = col0 + wc * 64 + l31;
  const int rb = (lane >> 5) << 2;
#pragma unroll
  for (int m = 0; m < 4; ++m)
#pragma unroll
    for (int n = 0; n < 2; ++n)
#pragma unroll
      for (int r = 0; r < 16; ++r) {
        const int grow = row0 + wr * 128 + m * 32 + (r & 3) + ((r >> 2) << 3) + rb;
        const int gcol = ocol0 + n * 32;
        Yb[(size_t)grow * NFEAT + (size_t)gcol] = acc[m][n][r];
      }
}

// ---------------------------------------------------------------------------
// launch: build 8 L's -> fold to Menc, Mdec, Mtot = Mdec*Menc ->
// ONE fused single-pass big GEMM produces both outputs from x.
// ---------------------------------------------------------------------------
extern "C" void kernel_launch(void* const* d_in, const int* in_sizes, int n_in,
                              void* d_out, int out_size, void* d_ws, size_t ws_size,
                              hipStream_t stream) {
  (void)in_sizes; (void)n_in; (void)out_size; (void)ws_size;
  const float* x  = (const float*)d_in[0];
  const float* er = (const float*)d_in[1];
  const float* ed = (const float*)d_in[2];
  const float* dr = (const float*)d_in[3];
  const float* dd = (const float*)d_in[4];

  float* O0 = (float*)d_out;                       // bottleneck (fp32, 64 MB)
  float* O1 = O0 + (size_t)BATCH * NFEAT;          // out (fp32, 64 MB)

  const size_t LM = (size_t)1 << 20;  // elems per 1024x1024 matrix

  // d_ws: Lh (16MB) | Ll (16MB) | ab (32KB) | Qh (32MB)
  bf16* Lh = (bf16*)d_ws;
  bf16* Ll = Lh + 8 * LM;
  float* ab = (float*)(Ll + 8 * LM);
  bf16* Qh = (bf16*)(ab + 8 * 1024);

  // O0 region scratch (fully consumed before the big GEMM writes O0):
  // Tpref @0 (64KB); 16 chain slots @1MB (32MB).
  float* Tpref = O0;
  bf16* SB = (bf16*)((char*)O0 + (1 << 20));
  auto slot = [&](int s) { return SB + (size_t)s * LM; };
  bf16 *TheH = slot(0), *TheL = slot(1), *ThdH = slot(2), *ThdL = slot(3);
  bf16 *KaeH = slot(4), *KaeL = slot(5), *KadH = slot(6), *KadL = slot(7);
  bf16 *KbeH = slot(8), *KbeL = slot(9), *KbdH = slot(10), *KbdL = slot(11);
  bf16 *KceH = slot(12), *KceL = slot(13), *KcdH = slot(14), *KcdL = slot(15);

  // After the chain, all L slots are dead: Mcat (2048x1024 h+l) and Mdec
  // live in the Lh/Ll regions.
  bf16* McatH = Lh;              // rows 0-1023 = Menc, 1024-2047 = Mtot
  bf16* McatL = Lh + 2 * LM;
  bf16* MdH = Ll;
  bf16* MdL = Ll + LM;

  prep_kernel<<<8, 64, 0, stream>>>(er, ed, dr, dd, ab);
  prep2_kernel<<<8, 256, 0, stream>>>(er, ed, dr, dd, ab, Tpref);
  build_kernel<<<dim3(1024, 8), 256, 0, stream>>>(er, ed, dr, dd, ab, Tpref, Lh, Ll);
  splith_kernel<<<4096, 256, 0, stream>>>(x, Qh);

  const dim3 tg2(16, 16, 2);
  const dim3 tg1(16, 16, 1);
  // batched chains: enc (z=0) uses L1..L4, dec (z=1) uses L5..L8.
  transpose2_kernel<<<tg2, 256, 0, stream>>>(
      Lh + 0 * LM, Ll + 0 * LM, TheH, TheL,
      Lh + 4 * LM, Ll + 4 * LM, ThdH, ThdL);
  chaingemm2_kernel<<<tg2, 256, 0, stream>>>(
      TheH, TheL, Lh + 1 * LM, Ll + 1 * LM, KaeH, KaeL,
      ThdH, ThdL, Lh + 5 * LM, Ll + 5 * LM, KadH, KadL);
  chaingemm2_kernel<<<tg2, 256, 0, stream>>>(
      KaeH, KaeL, Lh + 2 * LM, Ll + 2 * LM, KbeH, KbeL,
      KadH, KadL, Lh + 6 * LM, Ll + 6 * LM, KbdH, KbdL);
  chaingemm2_kernel<<<tg2, 256, 0, stream>>>(
      KbeH, KbeL, Lh + 3 * LM, Ll + 3 * LM, KceH, KceL,
      KbdH, KbdL, Lh + 7 * LM, Ll + 7 * LM, KcdH, KcdL);
  // Kce = Menc^T, Kcd = Mdec^T.  Menc -> Mcat rows 0-1023; Mdec -> MdH/MdL.
  transpose2_kernel<<<tg2, 256, 0, stream>>>(
      KceH, KceL, McatH, McatL,
      KcdH, KcdL, MdH, MdL);
  // Mtot = Mdec * Menc = chaingemm(Mdec, Kce) -> Mcat rows 1024-2047.
  chaingemm2_kernel<<<tg1, 256, 0, stream>>>(
      MdH, MdL, KceH, KceL, McatH + LM, McatL + LM,
      MdH, MdL, KceH, KceL, McatH + LM, McatL + LM);

  // fused single-pass big GEMM: both outputs from x in one dispatch.
  gemmbig_kernel<<<dim3(64, 8), 512, 0, stream>>>(Qh, McatH, O0, O1);
}

// Round 11
// 279.707 us; speedup vs baseline: 3.2991x; 1.2309x over previous
//
#include <hip/hip_runtime.h>
#include <hip/hip_bf16.h>
#include <cstdint>
#include <cstddef>

#define H 512
#define NFEAT 1024
#define BATCH 16384
#define LM ((size_t)1 << 20)   // elems per 1024x1024 matrix

using bf16 = __hip_bfloat16;
using bf16x8 = __attribute__((ext_vector_type(8))) __bf16;
using f32x4 = __attribute__((ext_vector_type(4))) float;
using f32x16 = __attribute__((ext_vector_type(16))) float;

// ---------------------------------------------------------------------------
// async global -> LDS, 16 bytes per lane
// ---------------------------------------------------------------------------
__device__ __forceinline__ void gload16(void* lds, const void* g) {
  __builtin_amdgcn_global_load_lds(
      (__attribute__((address_space(1))) void*)g,
      (__attribute__((address_space(3))) void*)lds,
      16, 0, 0);
}

// ---------------------------------------------------------------------------
// prep: per matrix, compute a[], b[] for core = diag(d) + a*1^T + b*u^T
// Closed-form Cayley (rank-2 Woodbury), verified R0-R10.
// ---------------------------------------------------------------------------
__global__ void prep_kernel(const float* __restrict__ er, const float* __restrict__ ed,
                            const float* __restrict__ dr, const float* __restrict__ dd,
                            float* __restrict__ ab) {
  const int mat = blockIdx.x;          // 0..7
  const int lane = threadIdx.x;        // 0..63
  const float* u = (mat < 4) ? (er + mat * H) : (dr + (mat - 4) * H);
  const float* d = (mat < 4) ? (ed + mat * H) : (dd + (mat - 4) * H);

  double s = 0.0, q = 0.0;
  for (int k = 0; k < 8; ++k) {
    double v = (double)u[lane + 64 * k];
    s += v;
    q += v * v;
  }
  for (int off = 32; off; off >>= 1) {
    s += __shfl_down(s, off);
    q += __shfl_down(q, off);
  }
  s = __shfl(s, 0);
  q = __shfl(q, 0);

  const double det = 1.0 - s * s + (double)H * q;
  const double cuv = 2.0 * (1.0 + s) / det;
  const double cuu = -2.0 * (double)H / det;
  const double cvv = -2.0 * q / det;
  const double cvu = -2.0 * (1.0 - s) / det;

  float* a = ab + mat * 1024;
  float* b = a + H;
  for (int k = 0; k < 8; ++k) {
    int idx = lane + 64 * k;
    double ui = (double)u[idx], di = (double)d[idx];
    a[idx] = (float)(di * (cuv * ui + cvv));
    b[idx] = (float)(di * (cuu * ui + cvu));
  }
}

// ---------------------------------------------------------------------------
// prep2: stride-4-residue inclusive prefix tables over a, a_rev, d, d_rev.
// ---------------------------------------------------------------------------
__global__ __launch_bounds__(256) void prep2_kernel(
    const float* __restrict__ er, const float* __restrict__ ed,
    const float* __restrict__ dr, const float* __restrict__ dd,
    const float* __restrict__ ab, float* __restrict__ Tpref) {
  __shared__ float buf[4][512];
  __shared__ float tmp[4][512];
  const int mat = blockIdx.x;
  const float* d = (mat < 4) ? (ed + mat * H) : (dd + (mat - 4) * H);
  const float* a = ab + mat * 1024;
  const int t = threadIdx.x;
  for (int m = t; m < 512; m += 256) {
    buf[0][m] = a[m];
    buf[1][m] = a[511 - m];
    buf[2][m] = d[m];
    buf[3][m] = d[511 - m];
  }
  __syncthreads();
  for (int s = 4; s <= 256; s <<= 1) {
    for (int m = t; m < 512; m += 256)
#pragma unroll
      for (int q = 0; q < 4; ++q) tmp[q][m] = (m >= s) ? buf[q][m - s] : 0.f;
    __syncthreads();
    for (int m = t; m < 512; m += 256)
#pragma unroll
      for (int q = 0; q < 4; ++q) buf[q][m] += tmp[q][m];
    __syncthreads();
  }
  float* tp = Tpref + mat * 2048;
  for (int m = t; m < 512; m += 256) {
    tp[m] = buf[0][m];
    tp[512 + m] = buf[1][m];
    tp[1024 + m] = buf[2][m];
    tp[1536 + m] = buf[3][m];
  }
}

// ---------------------------------------------------------------------------
// build v3 (R2-validated): prefix tables + quad b*u loop.
// R11 change: L stored pair-interleaved (hi at mat*2LM, lo at +LM).
// ---------------------------------------------------------------------------
__global__ __launch_bounds__(256) void build_kernel(
    const float* __restrict__ er, const float* __restrict__ ed,
    const float* __restrict__ dr, const float* __restrict__ dd,
    const float* __restrict__ ab, const float* __restrict__ Tpref,
    bf16* __restrict__ Lbase) {
  __shared__ __align__(16) float arr4[4][520];
  __shared__ __align__(16) float4 up[132];
  __shared__ float pa[512], parev[512], pd[512], pdrev[512], sdl[512];

  const int i = blockIdx.x;
  const int mat = blockIdx.y;
  const float* u = (mat < 4) ? (er + mat * H) : (dr + (mat - 4) * H);
  const float* d = (mat < 4) ? (ed + mat * H) : (dd + (mat - 4) * H);
  const float* a = ab + mat * 1024;
  const float* b = a + H;
  const float* tp = Tpref + mat * 2048;
  const int t = threadIdx.x;

  for (int m = t; m < 520; m += 256) {
    arr4[0][m] = (m < 512) ? u[m] : 0.f;
    arr4[1][m] = (m >= 1 && m <= 512) ? b[m - 1] : 0.f;
    arr4[2][m] = (m >= 2 && m <= 513) ? u[513 - m] : 0.f;
    arr4[3][m] = (m >= 3 && m <= 514) ? b[514 - m] : 0.f;
  }
  for (int m = t; m < 512; m += 256) {
    pa[m] = tp[m];
    parev[m] = tp[512 + m];
    pd[m] = tp[1024 + m];
    pdrev[m] = tp[1536 + m];
    sdl[m] = d[m];
  }
  if (t < 132) {
    const int k4 = 4 * t;
    float4 v;
    int p0 = i - k4;
    v.x = (p0 >= 0 && p0 < 512) ? b[p0] : 0.f;
    int p1 = i - k4 - 1;
    v.y = (p1 >= 0 && p1 < 512) ? u[511 - p1] : 0.f;
    int p2 = i - k4 - 2;
    v.z = (p2 >= 0 && p2 < 512) ? b[511 - p2] : 0.f;
    int p3 = i - k4 - 3;
    v.w = (p3 >= 0 && p3 < 512) ? u[p3] : 0.f;
    up[t] = v;
  }
  __syncthreads();

  const float* upf = (const float*)up;
  const int j0 = t * 4;

  int lo_[4], hi_[4];
#pragma unroll
  for (int c = 0; c < 4; ++c) {
    const int jc = j0 + c;
    lo_[c] = max(0, max(i, jc) - 511);
    hi_[c] = min(512, min(i, jc));
  }
  const int CL = lo_[3];
  const int CH = hi_[0];

  float acc[4] = {0.f, 0.f, 0.f, 0.f};

#pragma unroll
  for (int c = 0; c < 4; ++c) {
    const int jc = j0 + c;
    const int lo = lo_[c], hi = hi_[c];
    if (lo > hi) continue;
    float v = 0.f;
    {
      int o1 = lo + ((0 - lo) & 3), o2 = hi - ((hi - 0) & 3);
      if (o1 <= o2) { int mx = i - o1, mn = i - o2; v += pa[mx] - (mn >= 4 ? pa[mn - 4] : 0.f); }
    }
    {
      int o1 = lo + ((1 - lo) & 3), o2 = hi - ((hi - 1) & 3);
      if (o1 <= o2) { int mx = jc - o1, mn = jc - o2; v += pa[mx] - (mn >= 4 ? pa[mn - 4] : 0.f); }
    }
    {
      int o1 = lo + ((2 - lo) & 3), o2 = hi - ((hi - 2) & 3);
      if (o1 <= o2) { int mx = i - o1, mn = i - o2; v += parev[mx] - (mn >= 4 ? parev[mn - 4] : 0.f); }
    }
    {
      int o1 = lo + ((3 - lo) & 3), o2 = hi - ((hi - 3) & 3);
      if (o1 <= o2) { int mx = jc - o1, mn = jc - o2; v += parev[mx] - (mn >= 4 ? parev[mn - 4] : 0.f); }
    }
    if (i == jc) {
      {
        int o1 = lo + ((0 - lo) & 3), o2 = hi - ((hi - 0) & 3);
        if (o1 <= o2) { int mx = i - o1, mn = i - o2; v += pd[mx] - (mn >= 4 ? pd[mn - 4] : 0.f); }
      }
      {
        int o1 = lo + ((2 - lo) & 3), o2 = hi - ((hi - 2) & 3);
        if (o1 <= o2) { int mx = i - o1, mn = i - o2; v += pdrev[mx] - (mn >= 4 ? pdrev[mn - 4] : 0.f); }
      }
    }
    const int m2 = i + jc - 511;
    if (m2 >= 0 && !(m2 & 1)) {
      const int os = m2 >> 1;
      if (os >= lo && os <= hi) {
        const int r = os & 3;
        if (r == 1) v += sdl[jc - os];
        else if (r == 3) v += sdl[511 - (jc - os)];
      }
    }
    acc[c] = v;
  }

  if (CL > CH) {
#pragma unroll
    for (int c = 0; c < 4; ++c) {
      const int jc = j0 + c;
      for (int o = lo_[c]; o <= hi_[c]; ++o) {
        const int r = o & 3;
        acc[c] += upf[o] * arr4[r][jc - o + r];
      }
    }
  } else {
#pragma unroll
    for (int c = 0; c < 4; ++c) {
      const int jc = j0 + c;
      const int he = min(hi_[c], CL - 1);
      for (int o = lo_[c]; o <= he; ++o) {
        const int r = o & 3;
        acc[c] += upf[o] * arr4[r][jc - o + r];
      }
      const int ls = max(lo_[c], CH + 1);
      for (int o = ls; o <= hi_[c]; ++o) {
        const int r = o & 3;
        acc[c] += upf[o] * arr4[r][jc - o + r];
      }
    }
    const int QL = (CL + 3) & ~3;
    for (int o = CL; o < QL && o <= CH; ++o) {
      const int r = o & 3;
      const float uvv = upf[o];
      const float4 wv = *(const float4*)&arr4[r][j0 - o + r];
      acc[0] += uvv * wv.x; acc[1] += uvv * wv.y;
      acc[2] += uvv * wv.z; acc[3] += uvv * wv.w;
    }
    int ob = QL;
    for (; ob + 3 <= CH; ob += 4) {
      const float4 uv = up[ob >> 2];
      const int x = j0 - ob;
      const float4 w0 = *(const float4*)&arr4[0][x];
      const float4 w1 = *(const float4*)&arr4[1][x];
      const float4 w2 = *(const float4*)&arr4[2][x];
      const float4 w3 = *(const float4*)&arr4[3][x];
      acc[0] += uv.x * w0.x + uv.y * w1.x + uv.z * w2.x + uv.w * w3.x;
      acc[1] += uv.x * w0.y + uv.y * w1.y + uv.z * w2.y + uv.w * w3.y;
      acc[2] += uv.x * w0.z + uv.y * w1.z + uv.z * w2.z + uv.w * w3.z;
      acc[3] += uv.x * w0.w + uv.y * w1.w + uv.z * w2.w + uv.w * w3.w;
    }
    for (int o = ob; o <= CH; ++o) {
      const int r = o & 3;
      const float uvv = upf[o];
      const float4 wv = *(const float4*)&arr4[r][j0 - o + r];
      acc[0] += uvv * wv.x; acc[1] += uvv * wv.y;
      acc[2] += uvv * wv.z; acc[3] += uvv * wv.w;
    }
  }

  // pair-interleaved: hi at mat*2LM, lo at mat*2LM + LM
  const size_t off = ((size_t)mat << 21) + ((size_t)i << 10) + (size_t)j0;
  union { bf16 v[4]; ushort4 s; } Hu, Lu;
#pragma unroll
  for (int c = 0; c < 4; ++c) {
    const bf16 hb = __float2bfloat16(acc[c]);
    Hu.v[c] = hb;
    Lu.v[c] = __float2bfloat16(acc[c] - __bfloat162float(hb));
  }
  *(ushort4*)(Lbase + off) = Hu.s;
  *(ushort4*)(Lbase + off + LM) = Lu.s;
}

// ---------------------------------------------------------------------------
// split fp32 -> hi bf16 only
// ---------------------------------------------------------------------------
__global__ void splith_kernel(const float* __restrict__ x, bf16* __restrict__ h) {
  const int n4 = BATCH * NFEAT / 4;
  int idx = blockIdx.x * blockDim.x + threadIdx.x;
  int stride = gridDim.x * blockDim.x;
  for (int i = idx; i < n4; i += stride) {
    float4 v = ((const float4*)x)[i];
    union { bf16 b[4]; short4 s; } Hu;
    Hu.b[0] = __float2bfloat16(v.x);
    Hu.b[1] = __float2bfloat16(v.y);
    Hu.b[2] = __float2bfloat16(v.z);
    Hu.b[3] = __float2bfloat16(v.w);
    ((short4*)h)[i] = Hu.s;
  }
}

// ---------------------------------------------------------------------------
// batched single-array transpose: D = S^T for one 1024x1024 bf16 array per z.
// ---------------------------------------------------------------------------
struct TPtrs { const bf16* s; bf16* d; };
struct T6 { TPtrs t[6]; };

__global__ __launch_bounds__(256) void transposeB_kernel(T6 p) {
  const bf16* S = p.t[blockIdx.z].s;
  bf16* D = p.t[blockIdx.z].d;
  __shared__ ushort tile[64][68];
  const int i0 = blockIdx.x * 64, j0 = blockIdx.y * 64;
  const int tid = threadIdx.x;
  const int rr = tid >> 4;
  const int cc = (tid & 15) * 4;
#pragma unroll
  for (int it = 0; it < 4; ++it) {
    const int row = it * 16 + rr;
    const size_t so = (size_t)(i0 + row) * 1024 + j0 + cc;
    ushort4 v = *(const ushort4*)((const ushort*)S + so);
    tile[row][cc] = v.x; tile[row][cc + 1] = v.y;
    tile[row][cc + 2] = v.z; tile[row][cc + 3] = v.w;
  }
  __syncthreads();
#pragma unroll
  for (int it = 0; it < 4; ++it) {
    const int row = it * 16 + rr;
    ushort4 o;
    o.x = tile[cc][row];     o.y = tile[cc + 1][row];
    o.z = tile[cc + 2][row]; o.w = tile[cc + 3][row];
    const size_t dofs = (size_t)(j0 + row) * 1024 + i0 + cc;
    *(ushort4*)((ushort*)D + dofs) = o;
  }
}

// ---------------------------------------------------------------------------
// batched 2-pass chain GEMM: Y = A * B^T per z.  A single-bf16; B pair
// (lo at b+LM).  acc += A*Bh + A*Bl (fp32).  Output split (Yh, Yl).
// 64x64 tile, 4 waves, BK=64, double-buffered LDS, raw s_barrier +
// counted stage (gemmbig-proven pattern), XOR granule swizzle
// (phys_g = g ^ (row&7), applied on stage source + frag read).
// ---------------------------------------------------------------------------
struct GPtrs { const bf16* a; const bf16* b; bf16* yh; bf16* yl; };
struct G4 { GPtrs g[4]; };

__global__ __launch_bounds__(256) void chaingemm4_kernel(G4 p) {
  GPtrs q = p.g[blockIdx.z];
  const bf16* A = q.a;
  const bf16* Bh = q.b;
  const bf16* Bl = q.b + LM;

  __shared__ __align__(16) bf16 smem[2 * 3 * 4096];  // 48 KiB

  const int tid = threadIdx.x;
  const int lane = tid & 63;
  const int wave = tid >> 6;
  const int wr = wave >> 1, wc = wave & 1;
  const int r0 = blockIdx.x * 64, c0 = blockIdx.y * 64;

  // staging: thread t -> row tid>>3 (and +32), source granule pre-swizzled
  const int srow = tid >> 3;                       // 0..31
  const int scol = (((tid & 7) ^ (srow & 7))) * 8; // elem col (inverse swizzle)
  const int dst = tid * 8;                         // linear dest elems
  const size_t ga0 = (size_t)(r0 + srow) * 1024 + scol;
  const size_t gb0 = (size_t)(c0 + srow) * 1024 + scol;

  auto STAGE = [&](int nb, int k0) {
    bf16* base = smem + nb * 12288;
    gload16(base + dst,        A + ga0 + k0);
    gload16(base + 2048 + dst, A + ga0 + 32 * 1024 + k0);
    gload16(base + 4096 + dst,        Bh + gb0 + k0);
    gload16(base + 4096 + 2048 + dst, Bh + gb0 + 32 * 1024 + k0);
    gload16(base + 8192 + dst,        Bl + gb0 + k0);
    gload16(base + 8192 + 2048 + dst, Bl + gb0 + 32 * 1024 + k0);
  };

  const int l31 = lane & 31;
  const int klg = lane >> 5;  // k-half selector
  const int ar = wr * 32 + l31;
  const int br = wc * 32 + l31;
  int aoff[4], boff[4];
#pragma unroll
  for (int ks = 0; ks < 4; ++ks) {
    const int lgA = (ks << 1) | klg;               // logical granule 0..7
    aoff[ks] = ar * 64 + ((lgA ^ (ar & 7)) << 3);  // elem offset
    boff[ks] = br * 64 + ((lgA ^ (br & 7)) << 3);
  }

  f32x16 acc = {};

  STAGE(0, 0);
  asm volatile("s_waitcnt vmcnt(0)" ::: "memory");
  __builtin_amdgcn_s_barrier();

  for (int t = 0; t < 16; ++t) {
    const int buf = t & 1;
    const int nb = buf ^ 1;
    const bool pf = (t < 15);
    if (pf) STAGE(nb, (t + 1) * 64);

    const bf16* pA = smem + buf * 12288;
    const bf16* pBh = pA + 4096;
    const bf16* pBl = pA + 8192;
#pragma unroll
    for (int ks = 0; ks < 4; ++ks) {
      bf16x8 ah = *(const bf16x8*)(pA + aoff[ks]);
      bf16x8 bh = *(const bf16x8*)(pBh + boff[ks]);
      bf16x8 bl = *(const bf16x8*)(pBl + boff[ks]);
      acc = __builtin_amdgcn_mfma_f32_32x32x16_bf16(ah, bh, acc, 0, 0, 0);
      acc = __builtin_amdgcn_mfma_f32_32x32x16_bf16(ah, bl, acc, 0, 0, 0);
    }
    if (pf) asm volatile("s_waitcnt vmcnt(0)" ::: "memory");
    __builtin_amdgcn_s_barrier();
  }

  // epilogue: 32x32 C/D: col = lane&31, row = (r&3)+8*(r>>2)+4*(lane>>5)
  const int oc = c0 + wc * 32 + l31;
  const int rb = (lane >> 5) << 2;
#pragma unroll
  for (int r = 0; r < 16; ++r) {
    const int gr = r0 + wr * 32 + (r & 3) + ((r >> 2) << 3) + rb;
    const size_t off = (size_t)gr * 1024 + oc;
    const float v = acc[r];
    const bf16 hb = __float2bfloat16(v);
    q.yh[off] = hb;
    q.yl[off] = __float2bfloat16(v - __bfloat162float(hb));
  }
}

// ---------------------------------------------------------------------------
// fused SINGLE-PASS big GEMM (unchanged from R10, validated):
//   Y[r][c] = sum_k xh[r][k] * Mcat_h[c][k];  c<1024 -> O0, else O1.
// ---------------------------------------------------------------------------
__global__ __launch_bounds__(512, 1) void gemmbig_kernel(
    const bf16* __restrict__ A, const bf16* __restrict__ Bh_,
    float* __restrict__ Y0, float* __restrict__ Y1) {
  __shared__ __align__(16) bf16 smem[2 * 2 * 8192];  // 64 KiB

  const int tid = threadIdx.x;
  const int lane = tid & 63;
  const int wave = tid >> 6;
  const int wr = wave >> 2;
  const int wc = wave & 3;

  const int pdisp = blockIdx.x + (blockIdx.y << 6);
  const int xcd = pdisp & 7;
  const int chk = pdisp >> 3;
  const int row0 = (xcd * 8 + (chk >> 3)) * 256;
  const int col0 = (chk & 7) * 256;

  const int gsrc = (tid & 3) ^ ((tid >> 3) & 3);
  const int dst = tid * 8;
  const size_t abase = (size_t)(row0 + (tid >> 2)) * NFEAT + gsrc * 8;
  const size_t bbase = (size_t)(col0 + (tid >> 2)) * NFEAT + gsrc * 8;

  auto STAGE2 = [&](int nb, int arr, const bf16* __restrict__ src, size_t base, int k0) {
    bf16* d = smem + nb * 16384 + arr * 8192 + dst;
    gload16(d, src + base + k0);
    gload16(d + 4096, src + base + 131072 + k0);
  };

  const int l31 = lane & 31;
  const int hb = lane >> 5;
  int aoffB[4][2], boffB[2][2];
#pragma unroll
  for (int m = 0; m < 4; ++m) {
    const int r = wr * 128 + m * 32 + l31;
#pragma unroll
    for (int ks = 0; ks < 2; ++ks)
      aoffB[m][ks] = r * 64 + ((((ks << 1) | hb) ^ ((r >> 1) & 3)) << 4);
  }
#pragma unroll
  for (int n = 0; n < 2; ++n) {
    const int r = wc * 64 + n * 32 + l31;
#pragma unroll
    for (int ks = 0; ks < 2; ++ks)
      boffB[n][ks] = r * 64 + ((((ks << 1) | hb) ^ ((r >> 1) & 3)) << 4);
  }

  auto LD = [](const char* base, int off) { return *(const bf16x8*)(base + off); };

  f32x16 acc[4][2] = {};

  STAGE2(0, 0, A, abase, 0);
  STAGE2(0, 1, Bh_, bbase, 0);
  asm volatile("s_waitcnt vmcnt(0)" ::: "memory");
  __builtin_amdgcn_s_barrier();

  for (int t = 0; t < 32; ++t) {
    const int buf = t & 1;
    const int nb = buf ^ 1;
    const int k1 = (t + 1) * 32;
    const char* pA = (const char*)(smem + buf * 16384);
    const char* pBh = pA + 16384;
    const bool pf = (t < 31);

    bf16x8 ga[2][2], fbh[2][2];

    if (pf) {
      STAGE2(nb, 0, A, abase, k1);
      STAGE2(nb, 1, Bh_, bbase, k1);
    }
#pragma unroll
    for (int mi = 0; mi < 2; ++mi)
#pragma unroll
      for (int ks = 0; ks < 2; ++ks)
        ga[mi][ks] = LD(pA, aoffB[mi][ks]);
#pragma unroll
    for (int n = 0; n < 2; ++n)
#pragma unroll
      for (int ks = 0; ks < 2; ++ks)
        fbh[n][ks] = LD(pBh, boffB[n][ks]);
    __builtin_amdgcn_s_barrier();
    __builtin_amdgcn_s_setprio(1);
#pragma unroll
    for (int ks = 0; ks < 2; ++ks)
#pragma unroll
      for (int mi = 0; mi < 2; ++mi)
#pragma unroll
        for (int n = 0; n < 2; ++n)
          acc[mi][n] = __builtin_amdgcn_mfma_f32_32x32x16_bf16(ga[mi][ks], fbh[n][ks], acc[mi][n], 0, 0, 0);
    __builtin_amdgcn_s_setprio(0);
    __builtin_amdgcn_s_barrier();

#pragma unroll
    for (int mi = 0; mi < 2; ++mi)
#pragma unroll
      for (int ks = 0; ks < 2; ++ks)
        ga[mi][ks] = LD(pA, aoffB[2 + mi][ks]);
    __builtin_amdgcn_s_barrier();
    __builtin_amdgcn_s_setprio(1);
#pragma unroll
    for (int ks = 0; ks < 2; ++ks)
#pragma unroll
      for (int mi = 0; mi < 2; ++mi)
#pragma unroll
        for (int n = 0; n < 2; ++n)
          acc[2 + mi][n] = __builtin_amdgcn_mfma_f32_32x32x16_bf16(ga[mi][ks], fbh[n][ks], acc[2 + mi][n], 0, 0, 0);
    __builtin_amdgcn_s_setprio(0);
    if (pf) asm volatile("s_waitcnt vmcnt(0)" ::: "memory");
    __builtin_amdgcn_s_barrier();
  }

  float* Yb = (col0 < 1024) ? Y0 : (Y1 - 1024);
  const int ocol0 = col0 + wc * 64 + l31;
  const int rb = (lane >> 5) << 2;
#pragma unroll
  for (int m = 0; m < 4; ++m)
#pragma unroll
    for (int n = 0; n < 2; ++n)
#pragma unroll
      for (int r = 0; r < 16; ++r) {
        const int grow = row0 + wr * 128 + m * 32 + (r & 3) + ((r >> 2) << 3) + rb;
        const int gcol = ocol0 + n * 32;
        Yb[(size_t)grow * NFEAT + (size_t)gcol] = acc[m][n][r];
      }
}

// ---------------------------------------------------------------------------
// launch: build 8 L's (pair-interleaved) -> tree-fold:
//   level1 (z=4): Q1e=T1e*L2^T, Q2te=L4*T2e^T, Q1d=T1d*L6^T, Q2td=L8*T2d^T
//   level2 (z=2): Kce=Q1e*Q2te^T (=Menc^T), Kcd=Q1d*Q2td^T (=Mdec^T)
//   transpose(z=2): Menc->Mcat[0:1024), Mdec->MdecH
//   level3 (z=1): Mtot=Mdec*Kce^T -> Mcat[1024:2048)
// then ONE fused single-pass big GEMM.
// ---------------------------------------------------------------------------
extern "C" void kernel_launch(void* const* d_in, const int* in_sizes, int n_in,
                              void* d_out, int out_size, void* d_ws, size_t ws_size,
                              hipStream_t stream) {
  (void)in_sizes; (void)n_in; (void)out_size; (void)ws_size;
  const float* x  = (const float*)d_in[0];
  const float* er = (const float*)d_in[1];
  const float* ed = (const float*)d_in[2];
  const float* dr = (const float*)d_in[3];
  const float* dd = (const float*)d_in[4];

  float* O0 = (float*)d_out;                       // bottleneck (fp32, 64 MB)
  float* O1 = O0 + (size_t)BATCH * NFEAT;          // out (fp32, 64 MB)

  // d_ws: L pairs [16 LM] (32MB) | ab (32KB) | Qh (32MB)
  bf16* Lb = (bf16*)d_ws;                          // L mat m: hi at m*2LM, lo +LM
  float* ab = (float*)(Lb + 16 * LM);
  bf16* Qh = (bf16*)(ab + 8 * 1024);

  // O0 scratch: Tpref @0 (64KB); 16 chain slots @1MB.
  float* Tpref = O0;
  bf16* SB = (bf16*)((char*)O0 + (1 << 20));
  auto slot = [&](int s) { return SB + (size_t)s * LM; };

  prep_kernel<<<8, 64, 0, stream>>>(er, ed, dr, dd, ab);
  prep2_kernel<<<8, 256, 0, stream>>>(er, ed, dr, dd, ab, Tpref);
  build_kernel<<<dim3(1024, 8), 256, 0, stream>>>(er, ed, dr, dd, ab, Tpref, Lb);
  splith_kernel<<<4096, 256, 0, stream>>>(x, Qh);

  // ---- initial transposes (z=6): T1e=L1^T(hi), T2e=L3^T(pair),
  //      T1d=L5^T(hi), T2d=L7^T(pair) ----
  {
    T6 p;
    p.t[0] = {Lb + 0 * LM,  slot(0)};   // L1h -> s0  (T1e hi)
    p.t[1] = {Lb + 4 * LM,  slot(2)};   // L3h -> s2  (T2e hi)
    p.t[2] = {Lb + 5 * LM,  slot(3)};   // L3l -> s3  (T2e lo)
    p.t[3] = {Lb + 8 * LM,  slot(4)};   // L5h -> s4  (T1d hi)
    p.t[4] = {Lb + 12 * LM, slot(6)};   // L7h -> s6  (T2d hi)
    p.t[5] = {Lb + 13 * LM, slot(7)};   // L7l -> s7  (T2d lo)
    transposeB_kernel<<<dim3(16, 16, 6), 256, 0, stream>>>(p);
  }
  // ---- level 1 (z=4) ----
  {
    G4 p;
    p.g[0] = {slot(0),      Lb + 2 * LM,  slot(8),  slot(9)};   // Q1e = T1e * L2^T
    p.g[1] = {Lb + 6 * LM,  slot(2),      slot(10), slot(11)};  // Q2te = L4 * T2e^T
    p.g[2] = {slot(4),      Lb + 10 * LM, slot(12), slot(13)};  // Q1d = T1d * L6^T
    p.g[3] = {Lb + 14 * LM, slot(6),      slot(14), slot(15)};  // Q2td = L8 * T2d^T
    chaingemm4_kernel<<<dim3(16, 16, 4), 256, 0, stream>>>(p);
  }
  // ---- level 2 (z=2): Kce = Menc^T -> s0/s1; Kcd = Mdec^T -> s2/s3 ----
  {
    G4 p;
    p.g[0] = {slot(8),  slot(10), slot(0), slot(1)};
    p.g[1] = {slot(12), slot(14), slot(2), slot(3)};
    p.g[2] = p.g[0];
    p.g[3] = p.g[1];
    chaingemm4_kernel<<<dim3(16, 16, 2), 256, 0, stream>>>(p);
  }
  // ---- transpose (z=2): Menc -> Mcat rows 0-1023 (Lb+0), Mdec -> Lb+2LM ----
  {
    T6 p;
    p.t[0] = {slot(0), Lb + 0 * LM};
    p.t[1] = {slot(2), Lb + 2 * LM};
    p.t[2] = p.t[0]; p.t[3] = p.t[0]; p.t[4] = p.t[0]; p.t[5] = p.t[0];
    transposeB_kernel<<<dim3(16, 16, 2), 256, 0, stream>>>(p);
  }
  // ---- level 3 (z=1): Mtot = Mdec * Kce^T -> Mcat rows 1024-2047 ----
  {
    G4 p;
    p.g[0] = {Lb + 2 * LM, slot(0), Lb + 1 * LM, slot(4)};  // yl -> junk s4
    p.g[1] = p.g[0]; p.g[2] = p.g[0]; p.g[3] = p.g[0];
    chaingemm4_kernel<<<dim3(16, 16, 1), 256, 0, stream>>>(p);
  }

  // fused single-pass big GEMM: both outputs from x in one dispatch.
  gemmbig_kernel<<<dim3(64, 8), 512, 0, stream>>>(Qh, Lb, O0, O1);
}

// Round 12
// 259.350 us; speedup vs baseline: 3.5581x; 1.0785x over previous
//
#include <hip/hip_runtime.h>
#include <hip/hip_bf16.h>
#include <cstdint>
#include <cstddef>

#define H 512
#define NFEAT 1024
#define BATCH 16384
#define LM ((size_t)1 << 20)   // elems per 1024x1024 matrix
#define KOP 576                // padded K for the build GEMM (513 used)

using bf16 = __hip_bfloat16;
using bf16x8 = __attribute__((ext_vector_type(8))) __bf16;
using f32x4 = __attribute__((ext_vector_type(4))) float;
using f32x16 = __attribute__((ext_vector_type(16))) float;

// ---------------------------------------------------------------------------
// async global -> LDS, 16 bytes per lane
// ---------------------------------------------------------------------------
__device__ __forceinline__ void gload16(void* lds, const void* g) {
  __builtin_amdgcn_global_load_lds(
      (__attribute__((address_space(1))) void*)g,
      (__attribute__((address_space(3))) void*)lds,
      16, 0, 0);
}

// ---------------------------------------------------------------------------
// prep: per matrix, compute a[], b[] for core = diag(d) + a*1^T + b*u^T
// Closed-form Cayley (rank-2 Woodbury), verified R0-R11.
// ---------------------------------------------------------------------------
__global__ void prep_kernel(const float* __restrict__ er, const float* __restrict__ ed,
                            const float* __restrict__ dr, const float* __restrict__ dd,
                            float* __restrict__ ab) {
  const int mat = blockIdx.x;          // 0..7
  const int lane = threadIdx.x;        // 0..63
  const float* u = (mat < 4) ? (er + mat * H) : (dr + (mat - 4) * H);
  const float* d = (mat < 4) ? (ed + mat * H) : (dd + (mat - 4) * H);

  double s = 0.0, q = 0.0;
  for (int k = 0; k < 8; ++k) {
    double v = (double)u[lane + 64 * k];
    s += v;
    q += v * v;
  }
  for (int off = 32; off; off >>= 1) {
    s += __shfl_down(s, off);
    q += __shfl_down(q, off);
  }
  s = __shfl(s, 0);
  q = __shfl(q, 0);

  const double det = 1.0 - s * s + (double)H * q;
  const double cuv = 2.0 * (1.0 + s) / det;
  const double cuu = -2.0 * (double)H / det;
  const double cvv = -2.0 * q / det;
  const double cvu = -2.0 * (1.0 - s) / det;

  float* a = ab + mat * 1024;
  float* b = a + H;
  for (int k = 0; k < 8; ++k) {
    int idx = lane + 64 * k;
    double ui = (double)u[idx], di = (double)d[idx];
    a[idx] = (float)(di * (cuv * ui + cvv));
    b[idx] = (float)(di * (cuu * ui + cvu));
  }
}

// ---------------------------------------------------------------------------
// prep2: stride-4-residue inclusive prefix tables over a, a_rev, d, d_rev.
// ---------------------------------------------------------------------------
__global__ __launch_bounds__(256) void prep2_kernel(
    const float* __restrict__ er, const float* __restrict__ ed,
    const float* __restrict__ dr, const float* __restrict__ dd,
    const float* __restrict__ ab, float* __restrict__ Tpref) {
  __shared__ float buf[4][512];
  __shared__ float tmp[4][512];
  const int mat = blockIdx.x;
  const float* d = (mat < 4) ? (ed + mat * H) : (dd + (mat - 4) * H);
  const float* a = ab + mat * 1024;
  const int t = threadIdx.x;
  for (int m = t; m < 512; m += 256) {
    buf[0][m] = a[m];
    buf[1][m] = a[511 - m];
    buf[2][m] = d[m];
    buf[3][m] = d[511 - m];
  }
  __syncthreads();
  for (int s = 4; s <= 256; s <<= 1) {
    for (int m = t; m < 512; m += 256)
#pragma unroll
      for (int q = 0; q < 4; ++q) tmp[q][m] = (m >= s) ? buf[q][m - s] : 0.f;
    __syncthreads();
    for (int m = t; m < 512; m += 256)
#pragma unroll
      for (int q = 0; q < 4; ++q) buf[q][m] += tmp[q][m];
    __syncthreads();
  }
  float* tp = Tpref + mat * 2048;
  for (int m = t; m < 512; m += 256) {
    tp[m] = buf[0][m];
    tp[512 + m] = buf[1][m];
    tp[1024 + m] = buf[2][m];
    tp[1536 + m] = buf[3][m];
  }
}

// ---------------------------------------------------------------------------
// genops: build the K=513 (padded KOP=576) operand matrices for the
// sea-GEMM  L_sea = Aop @ Bop^T.  Column blocks by o-residue:
//   k in [0,128]:   o=4k      A=b~[x-o]       B=u~[x-o]
//   k in [129,256]: o=4(k-129)+1  A=u~[511-x+o]  B=b~[x-o]
//   k in [257,384]: o=4(k-257)+2  A=b~[511-x+o]  B=u~[511-x+o]
//   k in [385,512]: o=4(k-385)+3  A=u~[x-o]      B=b~[511-x+o]
// (zero outside [0,512); zero-pad handles the p,q validity window.)
// hi/lo bf16 split for the 3-pass GEMM.
// ---------------------------------------------------------------------------
__global__ __launch_bounds__(256) void genops_kernel(
    const float* __restrict__ er, const float* __restrict__ dr,
    const float* __restrict__ ab,
    bf16* __restrict__ Ah, bf16* __restrict__ Al,
    bf16* __restrict__ Bh, bf16* __restrict__ Bl) {
  const int x = blockIdx.x;            // 0..1023
  const int mat = blockIdx.y;          // 0..7
  const float* u = (mat < 4) ? (er + mat * H) : (dr + (mat - 4) * H);
  const float* b = ab + mat * 1024 + H;
  const int t = threadIdx.x;
  const size_t base = ((size_t)mat * 1024 + x) * KOP;
  for (int k = t; k < KOP; k += 256) {
    float av = 0.f, bv = 0.f;
    if (k <= 128) {
      const int o = 4 * k;
      const int ia = x - o;
      av = (ia >= 0 && ia < 512) ? b[ia] : 0.f;
      bv = (ia >= 0 && ia < 512) ? u[ia] : 0.f;
    } else if (k <= 256) {
      const int o = 4 * (k - 129) + 1;
      const int ia = 511 - x + o;
      const int ib = x - o;
      av = (ia >= 0 && ia < 512) ? u[ia] : 0.f;
      bv = (ib >= 0 && ib < 512) ? b[ib] : 0.f;
    } else if (k <= 384) {
      const int o = 4 * (k - 257) + 2;
      const int ia = 511 - x + o;
      av = (ia >= 0 && ia < 512) ? b[ia] : 0.f;
      bv = (ia >= 0 && ia < 512) ? u[ia] : 0.f;
    } else if (k <= 512) {
      const int o = 4 * (k - 385) + 3;
      const int ia = x - o;
      const int ib = 511 - x + o;
      av = (ia >= 0 && ia < 512) ? u[ia] : 0.f;
      bv = (ib >= 0 && ib < 512) ? b[ib] : 0.f;
    }
    const bf16 ah = __float2bfloat16(av);
    Ah[base + k] = ah;
    Al[base + k] = __float2bfloat16(av - __bfloat162float(ah));
    const bf16 bh = __float2bfloat16(bv);
    Bh[base + k] = bh;
    Bl[base + k] = __float2bfloat16(bv - __bfloat162float(bh));
  }
}

// ---------------------------------------------------------------------------
// buildgemm: L[mat] = Aop @ Bop^T (3-pass split-bf16, fp32 accum) with the
// a-part / diagonal / anti-diagonal terms added in the epilogue via the
// R2-validated prefix-table lookups.  128x128 tile, BK=64, 4 waves,
// 32x32x16 MFMA, XOR-swizzled LDS (R4-validated frame).  grid (8,8,8).
// Output: pair-interleaved split (hi at mat*2LM, lo +LM).
// ---------------------------------------------------------------------------
__global__ __launch_bounds__(256) void buildgemm_kernel(
    const bf16* __restrict__ Ah, const bf16* __restrict__ Al,
    const bf16* __restrict__ Bh, const bf16* __restrict__ Bl,
    const float* __restrict__ ed, const float* __restrict__ dd,
    const float* __restrict__ Tpref, bf16* __restrict__ Lbase) {
  __shared__ __align__(16) bf16 smem[4 * 8192];  // 4 arrays x [128][64]
  __shared__ float pa[512], parev[512], pd[512], pdrev[512], sdl[512];
  bf16* sAh = smem;
  bf16* sAl = smem + 8192;
  bf16* sBh = smem + 16384;
  bf16* sBl = smem + 24576;

  const int tid = threadIdx.x;
  const int lane = tid & 63;
  const int wave = tid >> 6;
  const int wr = wave >> 1;
  const int wc = wave & 1;
  const int mat = blockIdx.z;
  const int row0 = blockIdx.x * 128;
  const int col0 = blockIdx.y * 128;

  // stage epilogue tables
  {
    const float* tp = Tpref + mat * 2048;
    const float* d = (mat < 4) ? (ed + mat * H) : (dd + (mat - 4) * H);
    for (int m = tid; m < 512; m += 256) {
      pa[m] = tp[m];
      parev[m] = tp[512 + m];
      pd[m] = tp[1024 + m];
      pdrev[m] = tp[1536 + m];
      sdl[m] = d[m];
    }
  }

  const size_t OPS = (size_t)mat * 1024 * KOP;
  const int srow = tid >> 3;  // 0..31
  const int sce = (((tid * 16) ^ (((tid >> 3) & 7) << 4)) & 127) >> 1;
  const size_t abase = OPS + (size_t)(row0 + srow) * KOP + sce;
  const size_t bbase = OPS + (size_t)(col0 + srow) * KOP + sce;
  const int dst0 = tid * 8;

  f32x16 acc[2][2] = {};

  for (int kt = 0; kt < 9; ++kt) {
    const int k0 = kt * 64;
#pragma unroll
    for (int q = 0; q < 4; ++q) {
      const size_t ga = abase + (size_t)(32 * q) * KOP + k0;
      const size_t gb = bbase + (size_t)(32 * q) * KOP + k0;
      const int dq = q * 2048 + dst0;
      gload16(sAh + dq, Ah + ga);
      gload16(sAl + dq, Al + ga);
      gload16(sBh + dq, Bh + gb);
      gload16(sBl + dq, Bl + gb);
    }
    __syncthreads();

    const int l31 = lane & 31;
    const int kh16 = (lane >> 5) * 16;
#pragma unroll
    for (int ks = 0; ks < 4; ++ks) {
      bf16x8 fah[2], fal[2], fbh[2], fbl[2];
#pragma unroll
      for (int m = 0; m < 2; ++m) {
        const int arow = wr * 64 + m * 32 + l31;
        const int abk = (arow * 128 + ks * 32 + kh16) ^ ((arow & 7) << 4);
        fah[m] = *(const bf16x8*)((const char*)sAh + abk);
        fal[m] = *(const bf16x8*)((const char*)sAl + abk);
        const int brow = wc * 64 + m * 32 + l31;
        const int bbk = (brow * 128 + ks * 32 + kh16) ^ ((brow & 7) << 4);
        fbh[m] = *(const bf16x8*)((const char*)sBh + bbk);
        fbl[m] = *(const bf16x8*)((const char*)sBl + bbk);
      }
#pragma unroll
      for (int m = 0; m < 2; ++m)
#pragma unroll
        for (int n = 0; n < 2; ++n) {
          acc[m][n] = __builtin_amdgcn_mfma_f32_32x32x16_bf16(fah[m], fbh[n], acc[m][n], 0, 0, 0);
          acc[m][n] = __builtin_amdgcn_mfma_f32_32x32x16_bf16(fah[m], fbl[n], acc[m][n], 0, 0, 0);
          acc[m][n] = __builtin_amdgcn_mfma_f32_32x32x16_bf16(fal[m], fbh[n], acc[m][n], 0, 0, 0);
        }
    }
    __syncthreads();
  }

  // ---- fused epilogue: add a-part / diagonal / anti-diagonal (R2 logic) ----
  auto apart = [&](int i, int j) -> float {
    const int lo = max(0, max(i, j) - 511);
    const int hi = min(512, min(i, j));
    if (lo > hi) return 0.f;
    float v = 0.f;
    {
      int o1 = lo + ((0 - lo) & 3), o2 = hi - (hi & 3);
      if (o1 <= o2) { int mx = i - o1, mn = i - o2; v += pa[mx] - (mn >= 4 ? pa[mn - 4] : 0.f); }
    }
    {
      int o1 = lo + ((1 - lo) & 3), o2 = hi - ((hi - 1) & 3);
      if (o1 <= o2) { int mx = j - o1, mn = j - o2; v += pa[mx] - (mn >= 4 ? pa[mn - 4] : 0.f); }
    }
    {
      int o1 = lo + ((2 - lo) & 3), o2 = hi - ((hi - 2) & 3);
      if (o1 <= o2) { int mx = i - o1, mn = i - o2; v += parev[mx] - (mn >= 4 ? parev[mn - 4] : 0.f); }
    }
    {
      int o1 = lo + ((3 - lo) & 3), o2 = hi - ((hi - 3) & 3);
      if (o1 <= o2) { int mx = j - o1, mn = j - o2; v += parev[mx] - (mn >= 4 ? parev[mn - 4] : 0.f); }
    }
    if (i == j) {
      {
        int o1 = lo + ((0 - lo) & 3), o2 = hi - (hi & 3);
        if (o1 <= o2) { int mx = i - o1, mn = i - o2; v += pd[mx] - (mn >= 4 ? pd[mn - 4] : 0.f); }
      }
      {
        int o1 = lo + ((2 - lo) & 3), o2 = hi - ((hi - 2) & 3);
        if (o1 <= o2) { int mx = i - o1, mn = i - o2; v += pdrev[mx] - (mn >= 4 ? pdrev[mn - 4] : 0.f); }
      }
    }
    const int m2 = i + j - 511;
    if (m2 >= 0 && !(m2 & 1)) {
      const int os = m2 >> 1;
      if (os >= lo && os <= hi) {
        const int r = os & 3;
        if (r == 1) v += sdl[j - os];
        else if (r == 3) v += sdl[511 - (j - os)];
      }
    }
    return v;
  };

  const int ocol0 = col0 + wc * 64 + (lane & 31);
  const int rb = (lane >> 5) << 2;
#pragma unroll
  for (int m = 0; m < 2; ++m)
#pragma unroll
    for (int n = 0; n < 2; ++n)
#pragma unroll
      for (int r = 0; r < 16; ++r) {
        const int grow = row0 + wr * 64 + m * 32 + (r & 3) + ((r >> 2) << 3) + rb;
        const int gcol = ocol0 + n * 32;
        const float v = acc[m][n][r] + apart(grow, gcol);
        const size_t off = ((size_t)mat << 21) + ((size_t)grow << 10) + (size_t)gcol;
        const bf16 hb = __float2bfloat16(v);
        Lbase[off] = hb;
        Lbase[off + LM] = __float2bfloat16(v - __bfloat162float(hb));
      }
}

// ---------------------------------------------------------------------------
// split fp32 -> hi bf16 only
// ---------------------------------------------------------------------------
__global__ void splith_kernel(const float* __restrict__ x, bf16* __restrict__ h) {
  const int n4 = BATCH * NFEAT / 4;
  int idx = blockIdx.x * blockDim.x + threadIdx.x;
  int stride = gridDim.x * blockDim.x;
  for (int i = idx; i < n4; i += stride) {
    float4 v = ((const float4*)x)[i];
    union { bf16 b[4]; short4 s; } Hu;
    Hu.b[0] = __float2bfloat16(v.x);
    Hu.b[1] = __float2bfloat16(v.y);
    Hu.b[2] = __float2bfloat16(v.z);
    Hu.b[3] = __float2bfloat16(v.w);
    ((short4*)h)[i] = Hu.s;
  }
}

// ---------------------------------------------------------------------------
// batched single-array transpose: D = S^T for one 1024x1024 bf16 array per z.
// ---------------------------------------------------------------------------
struct TPtrs { const bf16* s; bf16* d; };
struct T6 { TPtrs t[6]; };

__global__ __launch_bounds__(256) void transposeB_kernel(T6 p) {
  const bf16* S = p.t[blockIdx.z].s;
  bf16* D = p.t[blockIdx.z].d;
  __shared__ ushort tile[64][68];
  const int i0 = blockIdx.x * 64, j0 = blockIdx.y * 64;
  const int tid = threadIdx.x;
  const int rr = tid >> 4;
  const int cc = (tid & 15) * 4;
#pragma unroll
  for (int it = 0; it < 4; ++it) {
    const int row = it * 16 + rr;
    const size_t so = (size_t)(i0 + row) * 1024 + j0 + cc;
    ushort4 v = *(const ushort4*)((const ushort*)S + so);
    tile[row][cc] = v.x; tile[row][cc + 1] = v.y;
    tile[row][cc + 2] = v.z; tile[row][cc + 3] = v.w;
  }
  __syncthreads();
#pragma unroll
  for (int it = 0; it < 4; ++it) {
    const int row = it * 16 + rr;
    ushort4 o;
    o.x = tile[cc][row];     o.y = tile[cc + 1][row];
    o.z = tile[cc + 2][row]; o.w = tile[cc + 3][row];
    const size_t dofs = (size_t)(j0 + row) * 1024 + i0 + cc;
    *(ushort4*)((ushort*)D + dofs) = o;
  }
}

// ---------------------------------------------------------------------------
// batched 2-pass chain GEMM (R11-validated): Y = A * B^T per z.
// A single-bf16; B pair (lo at b+LM).  Output split (Yh, Yl).
// ---------------------------------------------------------------------------
struct GPtrs { const bf16* a; const bf16* b; bf16* yh; bf16* yl; };
struct G4 { GPtrs g[4]; };

__global__ __launch_bounds__(256) void chaingemm4_kernel(G4 p) {
  GPtrs q = p.g[blockIdx.z];
  const bf16* A = q.a;
  const bf16* Bh = q.b;
  const bf16* Bl = q.b + LM;

  __shared__ __align__(16) bf16 smem[2 * 3 * 4096];  // 48 KiB

  const int tid = threadIdx.x;
  const int lane = tid & 63;
  const int wave = tid >> 6;
  const int wr = wave >> 1, wc = wave & 1;
  const int r0 = blockIdx.x * 64, c0 = blockIdx.y * 64;

  const int srow = tid >> 3;
  const int scol = (((tid & 7) ^ (srow & 7))) * 8;
  const int dst = tid * 8;
  const size_t ga0 = (size_t)(r0 + srow) * 1024 + scol;
  const size_t gb0 = (size_t)(c0 + srow) * 1024 + scol;

  auto STAGE = [&](int nb, int k0) {
    bf16* base = smem + nb * 12288;
    gload16(base + dst,        A + ga0 + k0);
    gload16(base + 2048 + dst, A + ga0 + 32 * 1024 + k0);
    gload16(base + 4096 + dst,        Bh + gb0 + k0);
    gload16(base + 4096 + 2048 + dst, Bh + gb0 + 32 * 1024 + k0);
    gload16(base + 8192 + dst,        Bl + gb0 + k0);
    gload16(base + 8192 + 2048 + dst, Bl + gb0 + 32 * 1024 + k0);
  };

  const int l31 = lane & 31;
  const int klg = lane >> 5;
  const int ar = wr * 32 + l31;
  const int br = wc * 32 + l31;
  int aoff[4], boff[4];
#pragma unroll
  for (int ks = 0; ks < 4; ++ks) {
    const int lgA = (ks << 1) | klg;
    aoff[ks] = ar * 64 + ((lgA ^ (ar & 7)) << 3);
    boff[ks] = br * 64 + ((lgA ^ (br & 7)) << 3);
  }

  f32x16 acc = {};

  STAGE(0, 0);
  asm volatile("s_waitcnt vmcnt(0)" ::: "memory");
  __builtin_amdgcn_s_barrier();

  for (int t = 0; t < 16; ++t) {
    const int buf = t & 1;
    const int nb = buf ^ 1;
    const bool pf = (t < 15);
    if (pf) STAGE(nb, (t + 1) * 64);

    const bf16* pA = smem + buf * 12288;
    const bf16* pBh = pA + 4096;
    const bf16* pBl = pA + 8192;
#pragma unroll
    for (int ks = 0; ks < 4; ++ks) {
      bf16x8 ah = *(const bf16x8*)(pA + aoff[ks]);
      bf16x8 bh = *(const bf16x8*)(pBh + boff[ks]);
      bf16x8 bl = *(const bf16x8*)(pBl + boff[ks]);
      acc = __builtin_amdgcn_mfma_f32_32x32x16_bf16(ah, bh, acc, 0, 0, 0);
      acc = __builtin_amdgcn_mfma_f32_32x32x16_bf16(ah, bl, acc, 0, 0, 0);
    }
    if (pf) asm volatile("s_waitcnt vmcnt(0)" ::: "memory");
    __builtin_amdgcn_s_barrier();
  }

  const int oc = c0 + wc * 32 + l31;
  const int rb = (lane >> 5) << 2;
#pragma unroll
  for (int r = 0; r < 16; ++r) {
    const int gr = r0 + wr * 32 + (r & 3) + ((r >> 2) << 3) + rb;
    const size_t off = (size_t)gr * 1024 + oc;
    const float v = acc[r];
    const bf16 hb = __float2bfloat16(v);
    q.yh[off] = hb;
    q.yl[off] = __float2bfloat16(v - __bfloat162float(hb));
  }
}

// ---------------------------------------------------------------------------
// fused SINGLE-PASS big GEMM (R10-validated):
//   Y[r][c] = sum_k xh[r][k] * Mcat_h[c][k];  c<1024 -> O0, else O1.
// ---------------------------------------------------------------------------
__global__ __launch_bounds__(512, 1) void gemmbig_kernel(
    const bf16* __restrict__ A, const bf16* __restrict__ Bh_,
    float* __restrict__ Y0, float* __restrict__ Y1) {
  __shared__ __align__(16) bf16 smem[2 * 2 * 8192];  // 64 KiB

  const int tid = threadIdx.x;
  const int lane = tid & 63;
  const int wave = tid >> 6;
  const int wr = wave >> 2;
  const int wc = wave & 3;

  const int pdisp = blockIdx.x + (blockIdx.y << 6);
  const int xcd = pdisp & 7;
  const int chk = pdisp >> 3;
  const int row0 = (xcd * 8 + (chk >> 3)) * 256;
  const int col0 = (chk & 7) * 256;

  const int gsrc = (tid & 3) ^ ((tid >> 3) & 3);
  const int dst = tid * 8;
  const size_t abase = (size_t)(row0 + (tid >> 2)) * NFEAT + gsrc * 8;
  const size_t bbase = (size_t)(col0 + (tid >> 2)) * NFEAT + gsrc * 8;

  auto STAGE2 = [&](int nb, int arr, const bf16* __restrict__ src, size_t base, int k0) {
    bf16* d = smem + nb * 16384 + arr * 8192 + dst;
    gload16(d, src + base + k0);
    gload16(d + 4096, src + base + 131072 + k0);
  };

  const int l31 = lane & 31;
  const int hb = lane >> 5;
  int aoffB[4][2], boffB[2][2];
#pragma unroll
  for (int m = 0; m < 4; ++m) {
    const int r = wr * 128 + m * 32 + l31;
#pragma unroll
    for (int ks = 0; ks < 2; ++ks)
      aoffB[m][ks] = r * 64 + ((((ks << 1) | hb) ^ ((r >> 1) & 3)) << 4);
  }
#pragma unroll
  for (int n = 0; n < 2; ++n) {
    const int r = wc * 64 + n * 32 + l31;
#pragma unroll
    for (int ks = 0; ks < 2; ++ks)
      boffB[n][ks] = r * 64 + ((((ks << 1) | hb) ^ ((r >> 1) & 3)) << 4);
  }

  auto LD = [](const char* base, int off) { return *(const bf16x8*)(base + off); };

  f32x16 acc[4][2] = {};

  STAGE2(0, 0, A, abase, 0);
  STAGE2(0, 1, Bh_, bbase, 0);
  asm volatile("s_waitcnt vmcnt(0)" ::: "memory");
  __builtin_amdgcn_s_barrier();

  for (int t = 0; t < 32; ++t) {
    const int buf = t & 1;
    const int nb = buf ^ 1;
    const int k1 = (t + 1) * 32;
    const char* pA = (const char*)(smem + buf * 16384);
    const char* pBh = pA + 16384;
    const bool pf = (t < 31);

    bf16x8 ga[2][2], fbh[2][2];

    if (pf) {
      STAGE2(nb, 0, A, abase, k1);
      STAGE2(nb, 1, Bh_, bbase, k1);
    }
#pragma unroll
    for (int mi = 0; mi < 2; ++mi)
#pragma unroll
      for (int ks = 0; ks < 2; ++ks)
        ga[mi][ks] = LD(pA, aoffB[mi][ks]);
#pragma unroll
    for (int n = 0; n < 2; ++n)
#pragma unroll
      for (int ks = 0; ks < 2; ++ks)
        fbh[n][ks] = LD(pBh, boffB[n][ks]);
    __builtin_amdgcn_s_barrier();
    __builtin_amdgcn_s_setprio(1);
#pragma unroll
    for (int ks = 0; ks < 2; ++ks)
#pragma unroll
      for (int mi = 0; mi < 2; ++mi)
#pragma unroll
        for (int n = 0; n < 2; ++n)
          acc[mi][n] = __builtin_amdgcn_mfma_f32_32x32x16_bf16(ga[mi][ks], fbh[n][ks], acc[mi][n], 0, 0, 0);
    __builtin_amdgcn_s_setprio(0);
    __builtin_amdgcn_s_barrier();

#pragma unroll
    for (int mi = 0; mi < 2; ++mi)
#pragma unroll
      for (int ks = 0; ks < 2; ++ks)
        ga[mi][ks] = LD(pA, aoffB[2 + mi][ks]);
    __builtin_amdgcn_s_barrier();
    __builtin_amdgcn_s_setprio(1);
#pragma unroll
    for (int ks = 0; ks < 2; ++ks)
#pragma unroll
      for (int mi = 0; mi < 2; ++mi)
#pragma unroll
        for (int n = 0; n < 2; ++n)
          acc[2 + mi][n] = __builtin_amdgcn_mfma_f32_32x32x16_bf16(ga[mi][ks], fbh[n][ks], acc[2 + mi][n], 0, 0, 0);
    __builtin_amdgcn_s_setprio(0);
    if (pf) asm volatile("s_waitcnt vmcnt(0)" ::: "memory");
    __builtin_amdgcn_s_barrier();
  }

  float* Yb = (col0 < 1024) ? Y0 : (Y1 - 1024);
  const int ocol0 = col0 + wc * 64 + l31;
  const int rb = (lane >> 5) << 2;
#pragma unroll
  for (int m = 0; m < 4; ++m)
#pragma unroll
    for (int n = 0; n < 2; ++n)
#pragma unroll
      for (int r = 0; r < 16; ++r) {
        const int grow = row0 + wr * 128 + m * 32 + (r & 3) + ((r >> 2) << 3) + rb;
        const int gcol = ocol0 + n * 32;
        Yb[(size_t)grow * NFEAT + (size_t)gcol] = acc[m][n][r];
      }
}

// ---------------------------------------------------------------------------
// launch
// ---------------------------------------------------------------------------
extern "C" void kernel_launch(void* const* d_in, const int* in_sizes, int n_in,
                              void* d_out, int out_size, void* d_ws, size_t ws_size,
                              hipStream_t stream) {
  (void)in_sizes; (void)n_in; (void)out_size; (void)ws_size;
  const float* x  = (const float*)d_in[0];
  const float* er = (const float*)d_in[1];
  const float* ed = (const float*)d_in[2];
  const float* dr = (const float*)d_in[3];
  const float* dd = (const float*)d_in[4];

  float* O0 = (float*)d_out;                       // bottleneck (fp32, 64 MB)
  float* O1 = O0 + (size_t)BATCH * NFEAT;          // out (fp32, 64 MB)

  // d_ws: L pairs [16 LM] (32MB) | ab (32KB) | Qh (32MB)
  bf16* Lb = (bf16*)d_ws;
  float* ab = (float*)(Lb + 16 * LM);
  bf16* Qh = (bf16*)(ab + 8 * 1024);

  // O0 scratch: Tpref @0 (64KB); 16 chain slots @1MB.
  float* Tpref = O0;
  bf16* SB = (bf16*)((char*)O0 + (1 << 20));
  auto slot = [&](int s) { return SB + (size_t)s * LM; };

  // O1 scratch (dead until gemmbig): sea-GEMM operands, 4 x 9.44MB.
  const size_t OPN = (size_t)8 * 1024 * KOP;
  bf16* Aoph = (bf16*)O1;
  bf16* Aopl = Aoph + OPN;
  bf16* Boph = Aopl + OPN;
  bf16* Bopl = Boph + OPN;

  prep_kernel<<<8, 64, 0, stream>>>(er, ed, dr, dd, ab);
  prep2_kernel<<<8, 256, 0, stream>>>(er, ed, dr, dd, ab, Tpref);
  genops_kernel<<<dim3(1024, 8), 256, 0, stream>>>(er, dr, ab, Aoph, Aopl, Boph, Bopl);
  buildgemm_kernel<<<dim3(8, 8, 8), 256, 0, stream>>>(Aoph, Aopl, Boph, Bopl,
                                                      ed, dd, Tpref, Lb);
  splith_kernel<<<4096, 256, 0, stream>>>(x, Qh);

  // ---- tree fold (R11-validated) ----
  {
    T6 p;
    p.t[0] = {Lb + 0 * LM,  slot(0)};   // L1h -> s0  (T1e hi)
    p.t[1] = {Lb + 4 * LM,  slot(2)};   // L3h -> s2  (T2e hi)
    p.t[2] = {Lb + 5 * LM,  slot(3)};   // L3l -> s3  (T2e lo)
    p.t[3] = {Lb + 8 * LM,  slot(4)};   // L5h -> s4  (T1d hi)
    p.t[4] = {Lb + 12 * LM, slot(6)};   // L7h -> s6  (T2d hi)
    p.t[5] = {Lb + 13 * LM, slot(7)};   // L7l -> s7  (T2d lo)
    transposeB_kernel<<<dim3(16, 16, 6), 256, 0, stream>>>(p);
  }
  {
    G4 p;
    p.g[0] = {slot(0),      Lb + 2 * LM,  slot(8),  slot(9)};   // Q1e = T1e * L2^T
    p.g[1] = {Lb + 6 * LM,  slot(2),      slot(10), slot(11)};  // Q2te = L4 * T2e^T
    p.g[2] = {slot(4),      Lb + 10 * LM, slot(12), slot(13)};  // Q1d = T1d * L6^T
    p.g[3] = {Lb + 14 * LM, slot(6),      slot(14), slot(15)};  // Q2td = L8 * T2d^T
    chaingemm4_kernel<<<dim3(16, 16, 4), 256, 0, stream>>>(p);
  }
  {
    G4 p;
    p.g[0] = {slot(8),  slot(10), slot(0), slot(1)};   // Kce = Menc^T
    p.g[1] = {slot(12), slot(14), slot(2), slot(3)};   // Kcd = Mdec^T
    p.g[2] = p.g[0];
    p.g[3] = p.g[1];
    chaingemm4_kernel<<<dim3(16, 16, 2), 256, 0, stream>>>(p);
  }
  {
    T6 p;
    p.t[0] = {slot(0), Lb + 0 * LM};    // Menc -> Mcat rows 0-1023
    p.t[1] = {slot(2), Lb + 2 * LM};    // Mdec
    p.t[2] = p.t[0]; p.t[3] = p.t[0]; p.t[4] = p.t[0]; p.t[5] = p.t[0];
    transposeB_kernel<<<dim3(16, 16, 2), 256, 0, stream>>>(p);
  }
  {
    G4 p;
    p.g[0] = {Lb + 2 * LM, slot(0), Lb + 1 * LM, slot(4)};  // Mtot -> Mcat rows 1024+
    p.g[1] = p.g[0]; p.g[2] = p.g[0]; p.g[3] = p.g[0];
    chaingemm4_kernel<<<dim3(16, 16, 1), 256, 0, stream>>>(p);
  }

  // fused single-pass big GEMM: both outputs from x in one dispatch.
  gemmbig_kernel<<<dim3(64, 8), 512, 0, stream>>>(Qh, Lb, O0, O1);
}

// Round 13
// 258.256 us; speedup vs baseline: 3.5731x; 1.0042x over previous
//
#include <hip/hip_runtime.h>
#include <hip/hip_bf16.h>
#include <cstdint>
#include <cstddef>

#define H 512
#define NFEAT 1024
#define BATCH 16384
#define LM ((size_t)1 << 20)   // elems per 1024x1024 matrix
#define KOP 576                // padded K for the build GEMM (513 used)

using bf16 = __hip_bfloat16;
using bf16x8 = __attribute__((ext_vector_type(8))) __bf16;
using f32x4 = __attribute__((ext_vector_type(4))) float;
using f32x16 = __attribute__((ext_vector_type(16))) float;

// ---------------------------------------------------------------------------
// async global -> LDS, 16 bytes per lane
// ---------------------------------------------------------------------------
__device__ __forceinline__ void gload16(void* lds, const void* g) {
  __builtin_amdgcn_global_load_lds(
      (__attribute__((address_space(1))) void*)g,
      (__attribute__((address_space(3))) void*)lds,
      16, 0, 0);
}

// ---------------------------------------------------------------------------
// prep: per matrix, compute a[], b[] for core = diag(d) + a*1^T + b*u^T
// Closed-form Cayley (rank-2 Woodbury), verified R0-R12.
// ---------------------------------------------------------------------------
__global__ void prep_kernel(const float* __restrict__ er, const float* __restrict__ ed,
                            const float* __restrict__ dr, const float* __restrict__ dd,
                            float* __restrict__ ab) {
  const int mat = blockIdx.x;          // 0..7
  const int lane = threadIdx.x;        // 0..63
  const float* u = (mat < 4) ? (er + mat * H) : (dr + (mat - 4) * H);
  const float* d = (mat < 4) ? (ed + mat * H) : (dd + (mat - 4) * H);

  double s = 0.0, q = 0.0;
  for (int k = 0; k < 8; ++k) {
    double v = (double)u[lane + 64 * k];
    s += v;
    q += v * v;
  }
  for (int off = 32; off; off >>= 1) {
    s += __shfl_down(s, off);
    q += __shfl_down(q, off);
  }
  s = __shfl(s, 0);
  q = __shfl(q, 0);

  const double det = 1.0 - s * s + (double)H * q;
  const double cuv = 2.0 * (1.0 + s) / det;
  const double cuu = -2.0 * (double)H / det;
  const double cvv = -2.0 * q / det;
  const double cvu = -2.0 * (1.0 - s) / det;

  float* a = ab + mat * 1024;
  float* b = a + H;
  for (int k = 0; k < 8; ++k) {
    int idx = lane + 64 * k;
    double ui = (double)u[idx], di = (double)d[idx];
    a[idx] = (float)(di * (cuv * ui + cvv));
    b[idx] = (float)(di * (cuu * ui + cvu));
  }
}

// ---------------------------------------------------------------------------
// prep2: stride-4-residue inclusive prefix tables over a, a_rev, d, d_rev.
// ---------------------------------------------------------------------------
__global__ __launch_bounds__(256) void prep2_kernel(
    const float* __restrict__ er, const float* __restrict__ ed,
    const float* __restrict__ dr, const float* __restrict__ dd,
    const float* __restrict__ ab, float* __restrict__ Tpref) {
  __shared__ float buf[4][512];
  __shared__ float tmp[4][512];
  const int mat = blockIdx.x;
  const float* d = (mat < 4) ? (ed + mat * H) : (dd + (mat - 4) * H);
  const float* a = ab + mat * 1024;
  const int t = threadIdx.x;
  for (int m = t; m < 512; m += 256) {
    buf[0][m] = a[m];
    buf[1][m] = a[511 - m];
    buf[2][m] = d[m];
    buf[3][m] = d[511 - m];
  }
  __syncthreads();
  for (int s = 4; s <= 256; s <<= 1) {
    for (int m = t; m < 512; m += 256)
#pragma unroll
      for (int q = 0; q < 4; ++q) tmp[q][m] = (m >= s) ? buf[q][m - s] : 0.f;
    __syncthreads();
    for (int m = t; m < 512; m += 256)
#pragma unroll
      for (int q = 0; q < 4; ++q) buf[q][m] += tmp[q][m];
    __syncthreads();
  }
  float* tp = Tpref + mat * 2048;
  for (int m = t; m < 512; m += 256) {
    tp[m] = buf[0][m];
    tp[512 + m] = buf[1][m];
    tp[1024 + m] = buf[2][m];
    tp[1536 + m] = buf[3][m];
  }
}

// ---------------------------------------------------------------------------
// genops: build the K=513 (padded KOP=576) operand matrices for the
// sea-GEMM  L_sea = Aop @ Bop^T.  (R12-validated.)
// ---------------------------------------------------------------------------
__global__ __launch_bounds__(256) void genops_kernel(
    const float* __restrict__ er, const float* __restrict__ dr,
    const float* __restrict__ ab,
    bf16* __restrict__ Ah, bf16* __restrict__ Al,
    bf16* __restrict__ Bh, bf16* __restrict__ Bl) {
  const int x = blockIdx.x;            // 0..1023
  const int mat = blockIdx.y;          // 0..7
  const float* u = (mat < 4) ? (er + mat * H) : (dr + (mat - 4) * H);
  const float* b = ab + mat * 1024 + H;
  const int t = threadIdx.x;
  const size_t base = ((size_t)mat * 1024 + x) * KOP;
  for (int k = t; k < KOP; k += 256) {
    float av = 0.f, bv = 0.f;
    if (k <= 128) {
      const int o = 4 * k;
      const int ia = x - o;
      av = (ia >= 0 && ia < 512) ? b[ia] : 0.f;
      bv = (ia >= 0 && ia < 512) ? u[ia] : 0.f;
    } else if (k <= 256) {
      const int o = 4 * (k - 129) + 1;
      const int ia = 511 - x + o;
      const int ib = x - o;
      av = (ia >= 0 && ia < 512) ? u[ia] : 0.f;
      bv = (ib >= 0 && ib < 512) ? b[ib] : 0.f;
    } else if (k <= 384) {
      const int o = 4 * (k - 257) + 2;
      const int ia = 511 - x + o;
      av = (ia >= 0 && ia < 512) ? b[ia] : 0.f;
      bv = (ia >= 0 && ia < 512) ? u[ia] : 0.f;
    } else if (k <= 512) {
      const int o = 4 * (k - 385) + 3;
      const int ia = x - o;
      const int ib = 511 - x + o;
      av = (ia >= 0 && ia < 512) ? u[ia] : 0.f;
      bv = (ib >= 0 && ib < 512) ? b[ib] : 0.f;
    }
    const bf16 ah = __float2bfloat16(av);
    Ah[base + k] = ah;
    Al[base + k] = __float2bfloat16(av - __bfloat162float(ah));
    const bf16 bh = __float2bfloat16(bv);
    Bh[base + k] = bh;
    Bl[base + k] = __float2bfloat16(bv - __bfloat162float(bh));
  }
}

// ---------------------------------------------------------------------------
// buildgemm (R12-validated): L[mat] = Aop @ Bop^T (3-pass split-bf16) with
// a-part / diagonal terms fused in the epilogue.  128x128 tile, BK=64.
// ---------------------------------------------------------------------------
__global__ __launch_bounds__(256) void buildgemm_kernel(
    const bf16* __restrict__ Ah, const bf16* __restrict__ Al,
    const bf16* __restrict__ Bh, const bf16* __restrict__ Bl,
    const float* __restrict__ ed, const float* __restrict__ dd,
    const float* __restrict__ Tpref, bf16* __restrict__ Lbase) {
  __shared__ __align__(16) bf16 smem[4 * 8192];
  __shared__ float pa[512], parev[512], pd[512], pdrev[512], sdl[512];
  bf16* sAh = smem;
  bf16* sAl = smem + 8192;
  bf16* sBh = smem + 16384;
  bf16* sBl = smem + 24576;

  const int tid = threadIdx.x;
  const int lane = tid & 63;
  const int wave = tid >> 6;
  const int wr = wave >> 1;
  const int wc = wave & 1;
  const int mat = blockIdx.z;
  const int row0 = blockIdx.x * 128;
  const int col0 = blockIdx.y * 128;

  {
    const float* tp = Tpref + mat * 2048;
    const float* d = (mat < 4) ? (ed + mat * H) : (dd + (mat - 4) * H);
    for (int m = tid; m < 512; m += 256) {
      pa[m] = tp[m];
      parev[m] = tp[512 + m];
      pd[m] = tp[1024 + m];
      pdrev[m] = tp[1536 + m];
      sdl[m] = d[m];
    }
  }

  const size_t OPS = (size_t)mat * 1024 * KOP;
  const int srow = tid >> 3;
  const int sce = (((tid * 16) ^ (((tid >> 3) & 7) << 4)) & 127) >> 1;
  const size_t abase = OPS + (size_t)(row0 + srow) * KOP + sce;
  const size_t bbase = OPS + (size_t)(col0 + srow) * KOP + sce;
  const int dst0 = tid * 8;

  f32x16 acc[2][2] = {};

  for (int kt = 0; kt < 9; ++kt) {
    const int k0 = kt * 64;
#pragma unroll
    for (int q = 0; q < 4; ++q) {
      const size_t ga = abase + (size_t)(32 * q) * KOP + k0;
      const size_t gb = bbase + (size_t)(32 * q) * KOP + k0;
      const int dq = q * 2048 + dst0;
      gload16(sAh + dq, Ah + ga);
      gload16(sAl + dq, Al + ga);
      gload16(sBh + dq, Bh + gb);
      gload16(sBl + dq, Bl + gb);
    }
    __syncthreads();

    const int l31 = lane & 31;
    const int kh16 = (lane >> 5) * 16;
#pragma unroll
    for (int ks = 0; ks < 4; ++ks) {
      bf16x8 fah[2], fal[2], fbh[2], fbl[2];
#pragma unroll
      for (int m = 0; m < 2; ++m) {
        const int arow = wr * 64 + m * 32 + l31;
        const int abk = (arow * 128 + ks * 32 + kh16) ^ ((arow & 7) << 4);
        fah[m] = *(const bf16x8*)((const char*)sAh + abk);
        fal[m] = *(const bf16x8*)((const char*)sAl + abk);
        const int brow = wc * 64 + m * 32 + l31;
        const int bbk = (brow * 128 + ks * 32 + kh16) ^ ((brow & 7) << 4);
        fbh[m] = *(const bf16x8*)((const char*)sBh + bbk);
        fbl[m] = *(const bf16x8*)((const char*)sBl + bbk);
      }
#pragma unroll
      for (int m = 0; m < 2; ++m)
#pragma unroll
        for (int n = 0; n < 2; ++n) {
          acc[m][n] = __builtin_amdgcn_mfma_f32_32x32x16_bf16(fah[m], fbh[n], acc[m][n], 0, 0, 0);
          acc[m][n] = __builtin_amdgcn_mfma_f32_32x32x16_bf16(fah[m], fbl[n], acc[m][n], 0, 0, 0);
          acc[m][n] = __builtin_amdgcn_mfma_f32_32x32x16_bf16(fal[m], fbh[n], acc[m][n], 0, 0, 0);
        }
    }
    __syncthreads();
  }

  auto apart = [&](int i, int j) -> float {
    const int lo = max(0, max(i, j) - 511);
    const int hi = min(512, min(i, j));
    if (lo > hi) return 0.f;
    float v = 0.f;
    {
      int o1 = lo + ((0 - lo) & 3), o2 = hi - (hi & 3);
      if (o1 <= o2) { int mx = i - o1, mn = i - o2; v += pa[mx] - (mn >= 4 ? pa[mn - 4] : 0.f); }
    }
    {
      int o1 = lo + ((1 - lo) & 3), o2 = hi - ((hi - 1) & 3);
      if (o1 <= o2) { int mx = j - o1, mn = j - o2; v += pa[mx] - (mn >= 4 ? pa[mn - 4] : 0.f); }
    }
    {
      int o1 = lo + ((2 - lo) & 3), o2 = hi - ((hi - 2) & 3);
      if (o1 <= o2) { int mx = i - o1, mn = i - o2; v += parev[mx] - (mn >= 4 ? parev[mn - 4] : 0.f); }
    }
    {
      int o1 = lo + ((3 - lo) & 3), o2 = hi - ((hi - 3) & 3);
      if (o1 <= o2) { int mx = j - o1, mn = j - o2; v += parev[mx] - (mn >= 4 ? parev[mn - 4] : 0.f); }
    }
    if (i == j) {
      {
        int o1 = lo + ((0 - lo) & 3), o2 = hi - (hi & 3);
        if (o1 <= o2) { int mx = i - o1, mn = i - o2; v += pd[mx] - (mn >= 4 ? pd[mn - 4] : 0.f); }
      }
      {
        int o1 = lo + ((2 - lo) & 3), o2 = hi - ((hi - 2) & 3);
        if (o1 <= o2) { int mx = i - o1, mn = i - o2; v += pdrev[mx] - (mn >= 4 ? pdrev[mn - 4] : 0.f); }
      }
    }
    const int m2 = i + j - 511;
    if (m2 >= 0 && !(m2 & 1)) {
      const int os = m2 >> 1;
      if (os >= lo && os <= hi) {
        const int r = os & 3;
        if (r == 1) v += sdl[j - os];
        else if (r == 3) v += sdl[511 - (j - os)];
      }
    }
    return v;
  };

  const int ocol0 = col0 + wc * 64 + (lane & 31);
  const int rb = (lane >> 5) << 2;
#pragma unroll
  for (int m = 0; m < 2; ++m)
#pragma unroll
    for (int n = 0; n < 2; ++n)
#pragma unroll
      for (int r = 0; r < 16; ++r) {
        const int grow = row0 + wr * 64 + m * 32 + (r & 3) + ((r >> 2) << 3) + rb;
        const int gcol = ocol0 + n * 32;
        const float v = acc[m][n][r] + apart(grow, gcol);
        const size_t off = ((size_t)mat << 21) + ((size_t)grow << 10) + (size_t)gcol;
        const bf16 hb = __float2bfloat16(v);
        Lbase[off] = hb;
        Lbase[off + LM] = __float2bfloat16(v - __bfloat162float(hb));
      }
}

// ---------------------------------------------------------------------------
// split fp32 -> hi bf16 only
// ---------------------------------------------------------------------------
__global__ void splith_kernel(const float* __restrict__ x, bf16* __restrict__ h) {
  const int n4 = BATCH * NFEAT / 4;
  int idx = blockIdx.x * blockDim.x + threadIdx.x;
  int stride = gridDim.x * blockDim.x;
  for (int i = idx; i < n4; i += stride) {
    float4 v = ((const float4*)x)[i];
    union { bf16 b[4]; short4 s; } Hu;
    Hu.b[0] = __float2bfloat16(v.x);
    Hu.b[1] = __float2bfloat16(v.y);
    Hu.b[2] = __float2bfloat16(v.z);
    Hu.b[3] = __float2bfloat16(v.w);
    ((short4*)h)[i] = Hu.s;
  }
}

// ---------------------------------------------------------------------------
// batched single-array transpose: D = S^T for one 1024x1024 bf16 array per z.
// ---------------------------------------------------------------------------
struct TPtrs { const bf16* s; bf16* d; };
struct T6 { TPtrs t[6]; };

__global__ __launch_bounds__(256) void transposeB_kernel(T6 p) {
  const bf16* S = p.t[blockIdx.z].s;
  bf16* D = p.t[blockIdx.z].d;
  __shared__ ushort tile[64][68];
  const int i0 = blockIdx.x * 64, j0 = blockIdx.y * 64;
  const int tid = threadIdx.x;
  const int rr = tid >> 4;
  const int cc = (tid & 15) * 4;
#pragma unroll
  for (int it = 0; it < 4; ++it) {
    const int row = it * 16 + rr;
    const size_t so = (size_t)(i0 + row) * 1024 + j0 + cc;
    ushort4 v = *(const ushort4*)((const ushort*)S + so);
    tile[row][cc] = v.x; tile[row][cc + 1] = v.y;
    tile[row][cc + 2] = v.z; tile[row][cc + 3] = v.w;
  }
  __syncthreads();
#pragma unroll
  for (int it = 0; it < 4; ++it) {
    const int row = it * 16 + rr;
    ushort4 o;
    o.x = tile[cc][row];     o.y = tile[cc + 1][row];
    o.z = tile[cc + 2][row]; o.w = tile[cc + 3][row];
    const size_t dofs = (size_t)(j0 + row) * 1024 + i0 + cc;
    *(ushort4*)((ushort*)D + dofs) = o;
  }
}

// ---------------------------------------------------------------------------
// batched 2-pass chain GEMM (R11-validated): Y = A * B^T per z.
// ---------------------------------------------------------------------------
struct GPtrs { const bf16* a; const bf16* b; bf16* yh; bf16* yl; };
struct G4 { GPtrs g[4]; };

__global__ __launch_bounds__(256) void chaingemm4_kernel(G4 p) {
  GPtrs q = p.g[blockIdx.z];
  const bf16* A = q.a;
  const bf16* Bh = q.b;
  const bf16* Bl = q.b + LM;

  __shared__ __align__(16) bf16 smem[2 * 3 * 4096];  // 48 KiB

  const int tid = threadIdx.x;
  const int lane = tid & 63;
  const int wave = tid >> 6;
  const int wr = wave >> 1, wc = wave & 1;
  const int r0 = blockIdx.x * 64, c0 = blockIdx.y * 64;

  const int srow = tid >> 3;
  const int scol = (((tid & 7) ^ (srow & 7))) * 8;
  const int dst = tid * 8;
  const size_t ga0 = (size_t)(r0 + srow) * 1024 + scol;
  const size_t gb0 = (size_t)(c0 + srow) * 1024 + scol;

  auto STAGE = [&](int nb, int k0) {
    bf16* base = smem + nb * 12288;
    gload16(base + dst,        A + ga0 + k0);
    gload16(base + 2048 + dst, A + ga0 + 32 * 1024 + k0);
    gload16(base + 4096 + dst,        Bh + gb0 + k0);
    gload16(base + 4096 + 2048 + dst, Bh + gb0 + 32 * 1024 + k0);
    gload16(base + 8192 + dst,        Bl + gb0 + k0);
    gload16(base + 8192 + 2048 + dst, Bl + gb0 + 32 * 1024 + k0);
  };

  const int l31 = lane & 31;
  const int klg = lane >> 5;
  const int ar = wr * 32 + l31;
  const int br = wc * 32 + l31;
  int aoff[4], boff[4];
#pragma unroll
  for (int ks = 0; ks < 4; ++ks) {
    const int lgA = (ks << 1) | klg;
    aoff[ks] = ar * 64 + ((lgA ^ (ar & 7)) << 3);
    boff[ks] = br * 64 + ((lgA ^ (br & 7)) << 3);
  }

  f32x16 acc = {};

  STAGE(0, 0);
  asm volatile("s_waitcnt vmcnt(0)" ::: "memory");
  __builtin_amdgcn_s_barrier();

  for (int t = 0; t < 16; ++t) {
    const int buf = t & 1;
    const int nb = buf ^ 1;
    const bool pf = (t < 15);
    if (pf) STAGE(nb, (t + 1) * 64);

    const bf16* pA = smem + buf * 12288;
    const bf16* pBh = pA + 4096;
    const bf16* pBl = pA + 8192;
#pragma unroll
    for (int ks = 0; ks < 4; ++ks) {
      bf16x8 ah = *(const bf16x8*)(pA + aoff[ks]);
      bf16x8 bh = *(const bf16x8*)(pBh + boff[ks]);
      bf16x8 bl = *(const bf16x8*)(pBl + boff[ks]);
      acc = __builtin_amdgcn_mfma_f32_32x32x16_bf16(ah, bh, acc, 0, 0, 0);
      acc = __builtin_amdgcn_mfma_f32_32x32x16_bf16(ah, bl, acc, 0, 0, 0);
    }
    if (pf) asm volatile("s_waitcnt vmcnt(0)" ::: "memory");
    __builtin_amdgcn_s_barrier();
  }

  const int oc = c0 + wc * 32 + l31;
  const int rb = (lane >> 5) << 2;
#pragma unroll
  for (int r = 0; r < 16; ++r) {
    const int gr = r0 + wr * 32 + (r & 3) + ((r >> 2) << 3) + rb;
    const size_t off = (size_t)gr * 1024 + oc;
    const float v = acc[r];
    const bf16 hb = __float2bfloat16(v);
    q.yh[off] = hb;
    q.yl[off] = __float2bfloat16(v - __bfloat162float(hb));
  }
}

// ---------------------------------------------------------------------------
// fused SINGLE-PASS big GEMM v2: triple-buffered LDS, ONE barrier per K-tile,
// counted vmcnt(4) (never 0 until tail).  Stage target slot (t+2)%3 is never
// a slot any wave can be reading (barrier bounds drift to <1 tile).
//   Y[r][c] = sum_k xh[r][k] * Mcat_h[c][k];  c<1024 -> O0, else O1.
// Swizzle: XCD = pdisp&7 owns ROW-octant (A L2-resident, read once).
// ---------------------------------------------------------------------------
__global__ __launch_bounds__(512, 1) void gemmbig_kernel(
    const bf16* __restrict__ A, const bf16* __restrict__ Bh_,
    float* __restrict__ Y0, float* __restrict__ Y1) {
  __shared__ __align__(16) bf16 smem[3 * 2 * 8192];  // 96 KiB: 3 bufs x (A|B)

  const int tid = threadIdx.x;
  const int lane = tid & 63;
  const int wave = tid >> 6;
  const int wr = wave >> 2;
  const int wc = wave & 3;

  const int pdisp = blockIdx.x + (blockIdx.y << 6);
  const int xcd = pdisp & 7;
  const int chk = pdisp >> 3;
  const int row0 = (xcd * 8 + (chk >> 3)) * 256;
  const int col0 = (chk & 7) * 256;

  const int gsrc = (tid & 3) ^ ((tid >> 3) & 3);
  const int dst = tid * 8;
  const size_t abase = (size_t)(row0 + (tid >> 2)) * NFEAT + gsrc * 8;
  const size_t bbase = (size_t)(col0 + (tid >> 2)) * NFEAT + gsrc * 8;

  // stage one K-tile (A + B) into buffer bufp: 4 gload16/thread
  auto STAGE = [&](bf16* bufp, int k0) {
    gload16(bufp + dst, A + abase + k0);
    gload16(bufp + 4096 + dst, A + abase + 131072 + k0);
    gload16(bufp + 8192 + dst, Bh_ + bbase + k0);
    gload16(bufp + 12288 + dst, Bh_ + bbase + 131072 + k0);
  };

  const int l31 = lane & 31;
  const int hb = lane >> 5;
  int aoffB[4][2], boffB[2][2];
#pragma unroll
  for (int m = 0; m < 4; ++m) {
    const int r = wr * 128 + m * 32 + l31;
#pragma unroll
    for (int ks = 0; ks < 2; ++ks)
      aoffB[m][ks] = r * 64 + ((((ks << 1) | hb) ^ ((r >> 1) & 3)) << 4);
  }
#pragma unroll
  for (int n = 0; n < 2; ++n) {
    const int r = wc * 64 + n * 32 + l31;
#pragma unroll
    for (int ks = 0; ks < 2; ++ks)
      boffB[n][ks] = r * 64 + ((((ks << 1) | hb) ^ ((r >> 1) & 3)) << 4);
  }

  auto LD = [](const char* base, int off) { return *(const bf16x8*)(base + off); };

  f32x16 acc[4][2] = {};

  bf16* b0 = smem;              // tile t
  bf16* b1 = smem + 16384;      // tile t+1
  bf16* b2 = smem + 32768;      // tile t+2 (staging target)

  // prologue: tiles 0 and 1 (8 loads); wait for tile 0 (leave tile 1's 4)
  STAGE(b0, 0);
  STAGE(b1, 32);
  asm volatile("s_waitcnt vmcnt(4)" ::: "memory");
  __builtin_amdgcn_s_barrier();

  for (int t = 0; t < 32; ++t) {
    if (t < 30) STAGE(b2, (t + 2) * 32);

    const char* pA = (const char*)b0;
    const char* pBh = pA + 16384;

    bf16x8 ga[2][2], fbh[2][2];
#pragma unroll
    for (int n = 0; n < 2; ++n)
#pragma unroll
      for (int ks = 0; ks < 2; ++ks)
        fbh[n][ks] = LD(pBh, boffB[n][ks]);
#pragma unroll
    for (int mi = 0; mi < 2; ++mi)
#pragma unroll
      for (int ks = 0; ks < 2; ++ks)
        ga[mi][ks] = LD(pA, aoffB[mi][ks]);

    __builtin_amdgcn_s_setprio(1);
#pragma unroll
    for (int ks = 0; ks < 2; ++ks)
#pragma unroll
      for (int mi = 0; mi < 2; ++mi)
#pragma unroll
        for (int n = 0; n < 2; ++n)
          acc[mi][n] = __builtin_amdgcn_mfma_f32_32x32x16_bf16(ga[mi][ks], fbh[n][ks], acc[mi][n], 0, 0, 0);
    __builtin_amdgcn_s_setprio(0);

#pragma unroll
    for (int mi = 0; mi < 2; ++mi)
#pragma unroll
      for (int ks = 0; ks < 2; ++ks)
        ga[mi][ks] = LD(pA, aoffB[2 + mi][ks]);

    __builtin_amdgcn_s_setprio(1);
#pragma unroll
    for (int ks = 0; ks < 2; ++ks)
#pragma unroll
      for (int mi = 0; mi < 2; ++mi)
#pragma unroll
        for (int n = 0; n < 2; ++n)
          acc[2 + mi][n] = __builtin_amdgcn_mfma_f32_32x32x16_bf16(ga[mi][ks], fbh[n][ks], acc[2 + mi][n], 0, 0, 0);
    __builtin_amdgcn_s_setprio(0);

    // tile t+1 must be resident before flip; its loads are older than the
    // 4 just issued for tile t+2 -> counted wait, no drain.
    if (t < 30) {
      asm volatile("s_waitcnt vmcnt(4)" ::: "memory");
    } else {
      asm volatile("s_waitcnt vmcnt(0)" ::: "memory");
    }
    __builtin_amdgcn_s_barrier();

    bf16* tmp = b0; b0 = b1; b1 = b2; b2 = tmp;
  }

  float* Yb = (col0 < 1024) ? Y0 : (Y1 - 1024);
  const int ocol0 = col0 + wc * 64 + l31;
  const int rb = (lane >> 5) << 2;
#pragma unroll
  for (int m = 0; m < 4; ++m)
#pragma unroll
    for (int n = 0; n < 2; ++n)
#pragma unroll
      for (int r = 0; r < 16; ++r) {
        const int grow = row0 + wr * 128 + m * 32 + (r & 3) + ((r >> 2) << 3) + rb;
        const int gcol = ocol0 + n * 32;
        Yb[(size_t)grow * NFEAT + (size_t)gcol] = acc[m][n][r];
      }
}

// ---------------------------------------------------------------------------
// launch
// ---------------------------------------------------------------------------
extern "C" void kernel_launch(void* const* d_in, const int* in_sizes, int n_in,
                              void* d_out, int out_size, void* d_ws, size_t ws_size,
                              hipStream_t stream) {
  (void)in_sizes; (void)n_in; (void)out_size; (void)ws_size;
  const float* x  = (const float*)d_in[0];
  const float* er = (const float*)d_in[1];
  const float* ed = (const float*)d_in[2];
  const float* dr = (const float*)d_in[3];
  const float* dd = (const float*)d_in[4];

  float* O0 = (float*)d_out;                       // bottleneck (fp32, 64 MB)
  float* O1 = O0 + (size_t)BATCH * NFEAT;          // out (fp32, 64 MB)

  // d_ws: L pairs [16 LM] (32MB) | ab (32KB) | Qh (32MB)
  bf16* Lb = (bf16*)d_ws;
  float* ab = (float*)(Lb + 16 * LM);
  bf16* Qh = (bf16*)(ab + 8 * 1024);

  // O0 scratch: Tpref @0 (64KB); 16 chain slots @1MB.
  float* Tpref = O0;
  bf16* SB = (bf16*)((char*)O0 + (1 << 20));
  auto slot = [&](int s) { return SB + (size_t)s * LM; };

  // O1 scratch (dead until gemmbig): sea-GEMM operands, 4 x 9.44MB.
  const size_t OPN = (size_t)8 * 1024 * KOP;
  bf16* Aoph = (bf16*)O1;
  bf16* Aopl = Aoph + OPN;
  bf16* Boph = Aopl + OPN;
  bf16* Bopl = Boph + OPN;

  prep_kernel<<<8, 64, 0, stream>>>(er, ed, dr, dd, ab);
  prep2_kernel<<<8, 256, 0, stream>>>(er, ed, dr, dd, ab, Tpref);
  genops_kernel<<<dim3(1024, 8), 256, 0, stream>>>(er, dr, ab, Aoph, Aopl, Boph, Bopl);
  buildgemm_kernel<<<dim3(8, 8, 8), 256, 0, stream>>>(Aoph, Aopl, Boph, Bopl,
                                                      ed, dd, Tpref, Lb);
  splith_kernel<<<4096, 256, 0, stream>>>(x, Qh);

  // ---- tree fold (R11-validated) ----
  {
    T6 p;
    p.t[0] = {Lb + 0 * LM,  slot(0)};   // L1h -> s0  (T1e hi)
    p.t[1] = {Lb + 4 * LM,  slot(2)};   // L3h -> s2  (T2e hi)
    p.t[2] = {Lb + 5 * LM,  slot(3)};   // L3l -> s3  (T2e lo)
    p.t[3] = {Lb + 8 * LM,  slot(4)};   // L5h -> s4  (T1d hi)
    p.t[4] = {Lb + 12 * LM, slot(6)};   // L7h -> s6  (T2d hi)
    p.t[5] = {Lb + 13 * LM, slot(7)};   // L7l -> s7  (T2d lo)
    transposeB_kernel<<<dim3(16, 16, 6), 256, 0, stream>>>(p);
  }
  {
    G4 p;
    p.g[0] = {slot(0),      Lb + 2 * LM,  slot(8),  slot(9)};   // Q1e = T1e * L2^T
    p.g[1] = {Lb + 6 * LM,  slot(2),      slot(10), slot(11)};  // Q2te = L4 * T2e^T
    p.g[2] = {slot(4),      Lb + 10 * LM, slot(12), slot(13)};  // Q1d = T1d * L6^T
    p.g[3] = {Lb + 14 * LM, slot(6),      slot(14), slot(15)};  // Q2td = L8 * T2d^T
    chaingemm4_kernel<<<dim3(16, 16, 4), 256, 0, stream>>>(p);
  }
  {
    G4 p;
    p.g[0] = {slot(8),  slot(10), slot(0), slot(1)};   // Kce = Menc^T
    p.g[1] = {slot(12), slot(14), slot(2), slot(3)};   // Kcd = Mdec^T
    p.g[2] = p.g[0];
    p.g[3] = p.g[1];
    chaingemm4_kernel<<<dim3(16, 16, 2), 256, 0, stream>>>(p);
  }
  {
    T6 p;
    p.t[0] = {slot(0), Lb + 0 * LM};    // Menc -> Mcat rows 0-1023
    p.t[1] = {slot(2), Lb + 2 * LM};    // Mdec
    p.t[2] = p.t[0]; p.t[3] = p.t[0]; p.t[4] = p.t[0]; p.t[5] = p.t[0];
    transposeB_kernel<<<dim3(16, 16, 2), 256, 0, stream>>>(p);
  }
  {
    G4 p;
    p.g[0] = {Lb + 2 * LM, slot(0), Lb + 1 * LM, slot(4)};  // Mtot -> Mcat rows 1024+
    p.g[1] = p.g[0]; p.g[2] = p.g[0]; p.g[3] = p.g[0];
    chaingemm4_kernel<<<dim3(16, 16, 1), 256, 0, stream>>>(p);
  }

  // fused single-pass big GEMM: both outputs from x in one dispatch.
  gemmbig_kernel<<<dim3(64, 8), 512, 0, stream>>>(Qh, Lb, O0, O1);
}

// Round 14
// 257.198 us; speedup vs baseline: 3.5878x; 1.0041x over previous
//
#include <hip/hip_runtime.h>
#include <hip/hip_bf16.h>
#include <cstdint>
#include <cstddef>

#define H 512
#define NFEAT 1024
#define BATCH 16384
#define LM ((size_t)1 << 20)   // elems per 1024x1024 matrix
#define KOP 576                // padded K for the build GEMM (513 used)

using bf16 = __hip_bfloat16;
using bf16x8 = __attribute__((ext_vector_type(8))) __bf16;
using f32x4 = __attribute__((ext_vector_type(4))) float;
using f32x16 = __attribute__((ext_vector_type(16))) float;

// ---------------------------------------------------------------------------
// async global -> LDS, 16 bytes per lane
// ---------------------------------------------------------------------------
__device__ __forceinline__ void gload16(void* lds, const void* g) {
  __builtin_amdgcn_global_load_lds(
      (__attribute__((address_space(1))) void*)g,
      (__attribute__((address_space(3))) void*)lds,
      16, 0, 0);
}

// ---------------------------------------------------------------------------
// prep: per matrix, compute a[], b[] for core = diag(d) + a*1^T + b*u^T
// Closed-form Cayley (rank-2 Woodbury), verified R0-R13.
// ---------------------------------------------------------------------------
__global__ void prep_kernel(const float* __restrict__ er, const float* __restrict__ ed,
                            const float* __restrict__ dr, const float* __restrict__ dd,
                            float* __restrict__ ab) {
  const int mat = blockIdx.x;          // 0..7
  const int lane = threadIdx.x;        // 0..63
  const float* u = (mat < 4) ? (er + mat * H) : (dr + (mat - 4) * H);
  const float* d = (mat < 4) ? (ed + mat * H) : (dd + (mat - 4) * H);

  double s = 0.0, q = 0.0;
  for (int k = 0; k < 8; ++k) {
    double v = (double)u[lane + 64 * k];
    s += v;
    q += v * v;
  }
  for (int off = 32; off; off >>= 1) {
    s += __shfl_down(s, off);
    q += __shfl_down(q, off);
  }
  s = __shfl(s, 0);
  q = __shfl(q, 0);

  const double det = 1.0 - s * s + (double)H * q;
  const double cuv = 2.0 * (1.0 + s) / det;
  const double cuu = -2.0 * (double)H / det;
  const double cvv = -2.0 * q / det;
  const double cvu = -2.0 * (1.0 - s) / det;

  float* a = ab + mat * 1024;
  float* b = a + H;
  for (int k = 0; k < 8; ++k) {
    int idx = lane + 64 * k;
    double ui = (double)u[idx], di = (double)d[idx];
    a[idx] = (float)(di * (cuv * ui + cvv));
    b[idx] = (float)(di * (cuu * ui + cvu));
  }
}

// ---------------------------------------------------------------------------
// prep2: stride-4-residue inclusive prefix tables over a, a_rev, d, d_rev.
// ---------------------------------------------------------------------------
__global__ __launch_bounds__(256) void prep2_kernel(
    const float* __restrict__ er, const float* __restrict__ ed,
    const float* __restrict__ dr, const float* __restrict__ dd,
    const float* __restrict__ ab, float* __restrict__ Tpref) {
  __shared__ float buf[4][512];
  __shared__ float tmp[4][512];
  const int mat = blockIdx.x;
  const float* d = (mat < 4) ? (ed + mat * H) : (dd + (mat - 4) * H);
  const float* a = ab + mat * 1024;
  const int t = threadIdx.x;
  for (int m = t; m < 512; m += 256) {
    buf[0][m] = a[m];
    buf[1][m] = a[511 - m];
    buf[2][m] = d[m];
    buf[3][m] = d[511 - m];
  }
  __syncthreads();
  for (int s = 4; s <= 256; s <<= 1) {
    for (int m = t; m < 512; m += 256)
#pragma unroll
      for (int q = 0; q < 4; ++q) tmp[q][m] = (m >= s) ? buf[q][m - s] : 0.f;
    __syncthreads();
    for (int m = t; m < 512; m += 256)
#pragma unroll
      for (int q = 0; q < 4; ++q) buf[q][m] += tmp[q][m];
    __syncthreads();
  }
  float* tp = Tpref + mat * 2048;
  for (int m = t; m < 512; m += 256) {
    tp[m] = buf[0][m];
    tp[512 + m] = buf[1][m];
    tp[1024 + m] = buf[2][m];
    tp[1536 + m] = buf[3][m];
  }
}

// ---------------------------------------------------------------------------
// genops (R12-validated): K=513 (padded KOP=576) operands for the sea-GEMM.
// ---------------------------------------------------------------------------
__global__ __launch_bounds__(256) void genops_kernel(
    const float* __restrict__ er, const float* __restrict__ dr,
    const float* __restrict__ ab,
    bf16* __restrict__ Ah, bf16* __restrict__ Al,
    bf16* __restrict__ Bh, bf16* __restrict__ Bl) {
  const int x = blockIdx.x;            // 0..1023
  const int mat = blockIdx.y;          // 0..7
  const float* u = (mat < 4) ? (er + mat * H) : (dr + (mat - 4) * H);
  const float* b = ab + mat * 1024 + H;
  const int t = threadIdx.x;
  const size_t base = ((size_t)mat * 1024 + x) * KOP;
  for (int k = t; k < KOP; k += 256) {
    float av = 0.f, bv = 0.f;
    if (k <= 128) {
      const int o = 4 * k;
      const int ia = x - o;
      av = (ia >= 0 && ia < 512) ? b[ia] : 0.f;
      bv = (ia >= 0 && ia < 512) ? u[ia] : 0.f;
    } else if (k <= 256) {
      const int o = 4 * (k - 129) + 1;
      const int ia = 511 - x + o;
      const int ib = x - o;
      av = (ia >= 0 && ia < 512) ? u[ia] : 0.f;
      bv = (ib >= 0 && ib < 512) ? b[ib] : 0.f;
    } else if (k <= 384) {
      const int o = 4 * (k - 257) + 2;
      const int ia = 511 - x + o;
      av = (ia >= 0 && ia < 512) ? b[ia] : 0.f;
      bv = (ia >= 0 && ia < 512) ? u[ia] : 0.f;
    } else if (k <= 512) {
      const int o = 4 * (k - 385) + 3;
      const int ia = x - o;
      const int ib = 511 - x + o;
      av = (ia >= 0 && ia < 512) ? u[ia] : 0.f;
      bv = (ib >= 0 && ib < 512) ? b[ib] : 0.f;
    }
    const bf16 ah = __float2bfloat16(av);
    Ah[base + k] = ah;
    Al[base + k] = __float2bfloat16(av - __bfloat162float(ah));
    const bf16 bh = __float2bfloat16(bv);
    Bh[base + k] = bh;
    Bl[base + k] = __float2bfloat16(bv - __bfloat162float(bh));
  }
}

// ---------------------------------------------------------------------------
// buildgemm (R12-validated): L[mat] = Aop @ Bop^T (3-pass split-bf16) with
// a-part / diagonal terms fused in the epilogue.  128x128 tile, BK=64.
// ---------------------------------------------------------------------------
__global__ __launch_bounds__(256) void buildgemm_kernel(
    const bf16* __restrict__ Ah, const bf16* __restrict__ Al,
    const bf16* __restrict__ Bh, const bf16* __restrict__ Bl,
    const float* __restrict__ ed, const float* __restrict__ dd,
    const float* __restrict__ Tpref, bf16* __restrict__ Lbase) {
  __shared__ __align__(16) bf16 smem[4 * 8192];
  __shared__ float pa[512], parev[512], pd[512], pdrev[512], sdl[512];
  bf16* sAh = smem;
  bf16* sAl = smem + 8192;
  bf16* sBh = smem + 16384;
  bf16* sBl = smem + 24576;

  const int tid = threadIdx.x;
  const int lane = tid & 63;
  const int wave = tid >> 6;
  const int wr = wave >> 1;
  const int wc = wave & 1;
  const int mat = blockIdx.z;
  const int row0 = blockIdx.x * 128;
  const int col0 = blockIdx.y * 128;

  {
    const float* tp = Tpref + mat * 2048;
    const float* d = (mat < 4) ? (ed + mat * H) : (dd + (mat - 4) * H);
    for (int m = tid; m < 512; m += 256) {
      pa[m] = tp[m];
      parev[m] = tp[512 + m];
      pd[m] = tp[1024 + m];
      pdrev[m] = tp[1536 + m];
      sdl[m] = d[m];
    }
  }

  const size_t OPS = (size_t)mat * 1024 * KOP;
  const int srow = tid >> 3;
  const int sce = (((tid * 16) ^ (((tid >> 3) & 7) << 4)) & 127) >> 1;
  const size_t abase = OPS + (size_t)(row0 + srow) * KOP + sce;
  const size_t bbase = OPS + (size_t)(col0 + srow) * KOP + sce;
  const int dst0 = tid * 8;

  f32x16 acc[2][2] = {};

  for (int kt = 0; kt < 9; ++kt) {
    const int k0 = kt * 64;
#pragma unroll
    for (int q = 0; q < 4; ++q) {
      const size_t ga = abase + (size_t)(32 * q) * KOP + k0;
      const size_t gb = bbase + (size_t)(32 * q) * KOP + k0;
      const int dq = q * 2048 + dst0;
      gload16(sAh + dq, Ah + ga);
      gload16(sAl + dq, Al + ga);
      gload16(sBh + dq, Bh + gb);
      gload16(sBl + dq, Bl + gb);
    }
    __syncthreads();

    const int l31 = lane & 31;
    const int kh16 = (lane >> 5) * 16;
#pragma unroll
    for (int ks = 0; ks < 4; ++ks) {
      bf16x8 fah[2], fal[2], fbh[2], fbl[2];
#pragma unroll
      for (int m = 0; m < 2; ++m) {
        const int arow = wr * 64 + m * 32 + l31;
        const int abk = (arow * 128 + ks * 32 + kh16) ^ ((arow & 7) << 4);
        fah[m] = *(const bf16x8*)((const char*)sAh + abk);
        fal[m] = *(const bf16x8*)((const char*)sAl + abk);
        const int brow = wc * 64 + m * 32 + l31;
        const int bbk = (brow * 128 + ks * 32 + kh16) ^ ((brow & 7) << 4);
        fbh[m] = *(const bf16x8*)((const char*)sBh + bbk);
        fbl[m] = *(const bf16x8*)((const char*)sBl + bbk);
      }
#pragma unroll
      for (int m = 0; m < 2; ++m)
#pragma unroll
        for (int n = 0; n < 2; ++n) {
          acc[m][n] = __builtin_amdgcn_mfma_f32_32x32x16_bf16(fah[m], fbh[n], acc[m][n], 0, 0, 0);
          acc[m][n] = __builtin_amdgcn_mfma_f32_32x32x16_bf16(fah[m], fbl[n], acc[m][n], 0, 0, 0);
          acc[m][n] = __builtin_amdgcn_mfma_f32_32x32x16_bf16(fal[m], fbh[n], acc[m][n], 0, 0, 0);
        }
    }
    __syncthreads();
  }

  auto apart = [&](int i, int j) -> float {
    const int lo = max(0, max(i, j) - 511);
    const int hi = min(512, min(i, j));
    if (lo > hi) return 0.f;
    float v = 0.f;
    {
      int o1 = lo + ((0 - lo) & 3), o2 = hi - (hi & 3);
      if (o1 <= o2) { int mx = i - o1, mn = i - o2; v += pa[mx] - (mn >= 4 ? pa[mn - 4] : 0.f); }
    }
    {
      int o1 = lo + ((1 - lo) & 3), o2 = hi - ((hi - 1) & 3);
      if (o1 <= o2) { int mx = j - o1, mn = j - o2; v += pa[mx] - (mn >= 4 ? pa[mn - 4] : 0.f); }
    }
    {
      int o1 = lo + ((2 - lo) & 3), o2 = hi - ((hi - 2) & 3);
      if (o1 <= o2) { int mx = i - o1, mn = i - o2; v += parev[mx] - (mn >= 4 ? parev[mn - 4] : 0.f); }
    }
    {
      int o1 = lo + ((3 - lo) & 3), o2 = hi - ((hi - 3) & 3);
      if (o1 <= o2) { int mx = j - o1, mn = j - o2; v += parev[mx] - (mn >= 4 ? parev[mn - 4] : 0.f); }
    }
    if (i == j) {
      {
        int o1 = lo + ((0 - lo) & 3), o2 = hi - (hi & 3);
        if (o1 <= o2) { int mx = i - o1, mn = i - o2; v += pd[mx] - (mn >= 4 ? pd[mn - 4] : 0.f); }
      }
      {
        int o1 = lo + ((2 - lo) & 3), o2 = hi - ((hi - 2) & 3);
        if (o1 <= o2) { int mx = i - o1, mn = i - o2; v += pdrev[mx] - (mn >= 4 ? pdrev[mn - 4] : 0.f); }
      }
    }
    const int m2 = i + j - 511;
    if (m2 >= 0 && !(m2 & 1)) {
      const int os = m2 >> 1;
      if (os >= lo && os <= hi) {
        const int r = os & 3;
        if (r == 1) v += sdl[j - os];
        else if (r == 3) v += sdl[511 - (j - os)];
      }
    }
    return v;
  };

  const int ocol0 = col0 + wc * 64 + (lane & 31);
  const int rb = (lane >> 5) << 2;
#pragma unroll
  for (int m = 0; m < 2; ++m)
#pragma unroll
    for (int n = 0; n < 2; ++n)
#pragma unroll
      for (int r = 0; r < 16; ++r) {
        const int grow = row0 + wr * 64 + m * 32 + (r & 3) + ((r >> 2) << 3) + rb;
        const int gcol = ocol0 + n * 32;
        const float v = acc[m][n][r] + apart(grow, gcol);
        const size_t off = ((size_t)mat << 21) + ((size_t)grow << 10) + (size_t)gcol;
        const bf16 hb = __float2bfloat16(v);
        Lbase[off] = hb;
        Lbase[off + LM] = __float2bfloat16(v - __bfloat162float(hb));
      }
}

// ---------------------------------------------------------------------------
// split fp32 -> hi bf16 only
// ---------------------------------------------------------------------------
__global__ void splith_kernel(const float* __restrict__ x, bf16* __restrict__ h) {
  const int n4 = BATCH * NFEAT / 4;
  int idx = blockIdx.x * blockDim.x + threadIdx.x;
  int stride = gridDim.x * blockDim.x;
  for (int i = idx; i < n4; i += stride) {
    float4 v = ((const float4*)x)[i];
    union { bf16 b[4]; short4 s; } Hu;
    Hu.b[0] = __float2bfloat16(v.x);
    Hu.b[1] = __float2bfloat16(v.y);
    Hu.b[2] = __float2bfloat16(v.z);
    Hu.b[3] = __float2bfloat16(v.w);
    ((short4*)h)[i] = Hu.s;
  }
}

// ---------------------------------------------------------------------------
// batched single-array transpose: D = S^T for one 1024x1024 bf16 array per z.
// ---------------------------------------------------------------------------
struct TPtrs { const bf16* s; bf16* d; };
struct T6 { TPtrs t[6]; };

__global__ __launch_bounds__(256) void transposeB_kernel(T6 p) {
  const bf16* S = p.t[blockIdx.z].s;
  bf16* D = p.t[blockIdx.z].d;
  __shared__ ushort tile[64][68];
  const int i0 = blockIdx.x * 64, j0 = blockIdx.y * 64;
  const int tid = threadIdx.x;
  const int rr = tid >> 4;
  const int cc = (tid & 15) * 4;
#pragma unroll
  for (int it = 0; it < 4; ++it) {
    const int row = it * 16 + rr;
    const size_t so = (size_t)(i0 + row) * 1024 + j0 + cc;
    ushort4 v = *(const ushort4*)((const ushort*)S + so);
    tile[row][cc] = v.x; tile[row][cc + 1] = v.y;
    tile[row][cc + 2] = v.z; tile[row][cc + 3] = v.w;
  }
  __syncthreads();
#pragma unroll
  for (int it = 0; it < 4; ++it) {
    const int row = it * 16 + rr;
    ushort4 o;
    o.x = tile[cc][row];     o.y = tile[cc + 1][row];
    o.z = tile[cc + 2][row]; o.w = tile[cc + 3][row];
    const size_t dofs = (size_t)(j0 + row) * 1024 + i0 + cc;
    *(ushort4*)((ushort*)D + dofs) = o;
  }
}

// ---------------------------------------------------------------------------
// batched 2-pass chain GEMM (R11-validated): Y = A * B^T per z.
// ---------------------------------------------------------------------------
struct GPtrs { const bf16* a; const bf16* b; bf16* yh; bf16* yl; };
struct G4 { GPtrs g[4]; };

__global__ __launch_bounds__(256) void chaingemm4_kernel(G4 p) {
  GPtrs q = p.g[blockIdx.z];
  const bf16* A = q.a;
  const bf16* Bh = q.b;
  const bf16* Bl = q.b + LM;

  __shared__ __align__(16) bf16 smem[2 * 3 * 4096];  // 48 KiB

  const int tid = threadIdx.x;
  const int lane = tid & 63;
  const int wave = tid >> 6;
  const int wr = wave >> 1, wc = wave & 1;
  const int r0 = blockIdx.x * 64, c0 = blockIdx.y * 64;

  const int srow = tid >> 3;
  const int scol = (((tid & 7) ^ (srow & 7))) * 8;
  const int dst = tid * 8;
  const size_t ga0 = (size_t)(r0 + srow) * 1024 + scol;
  const size_t gb0 = (size_t)(c0 + srow) * 1024 + scol;

  auto STAGE = [&](int nb, int k0) {
    bf16* base = smem + nb * 12288;
    gload16(base + dst,        A + ga0 + k0);
    gload16(base + 2048 + dst, A + ga0 + 32 * 1024 + k0);
    gload16(base + 4096 + dst,        Bh + gb0 + k0);
    gload16(base + 4096 + 2048 + dst, Bh + gb0 + 32 * 1024 + k0);
    gload16(base + 8192 + dst,        Bl + gb0 + k0);
    gload16(base + 8192 + 2048 + dst, Bl + gb0 + 32 * 1024 + k0);
  };

  const int l31 = lane & 31;
  const int klg = lane >> 5;
  const int ar = wr * 32 + l31;
  const int br = wc * 32 + l31;
  int aoff[4], boff[4];
#pragma unroll
  for (int ks = 0; ks < 4; ++ks) {
    const int lgA = (ks << 1) | klg;
    aoff[ks] = ar * 64 + ((lgA ^ (ar & 7)) << 3);
    boff[ks] = br * 64 + ((lgA ^ (br & 7)) << 3);
  }

  f32x16 acc = {};

  STAGE(0, 0);
  asm volatile("s_waitcnt vmcnt(0)" ::: "memory");
  __builtin_amdgcn_s_barrier();

  for (int t = 0; t < 16; ++t) {
    const int buf = t & 1;
    const int nb = buf ^ 1;
    const bool pf = (t < 15);
    if (pf) STAGE(nb, (t + 1) * 64);

    const bf16* pA = smem + buf * 12288;
    const bf16* pBh = pA + 4096;
    const bf16* pBl = pA + 8192;
#pragma unroll
    for (int ks = 0; ks < 4; ++ks) {
      bf16x8 ah = *(const bf16x8*)(pA + aoff[ks]);
      bf16x8 bh = *(const bf16x8*)(pBh + boff[ks]);
      bf16x8 bl = *(const bf16x8*)(pBl + boff[ks]);
      acc = __builtin_amdgcn_mfma_f32_32x32x16_bf16(ah, bh, acc, 0, 0, 0);
      acc = __builtin_amdgcn_mfma_f32_32x32x16_bf16(ah, bl, acc, 0, 0, 0);
    }
    if (pf) asm volatile("s_waitcnt vmcnt(0)" ::: "memory");
    __builtin_amdgcn_s_barrier();
  }

  const int oc = c0 + wc * 32 + l31;
  const int rb = (lane >> 5) << 2;
#pragma unroll
  for (int r = 0; r < 16; ++r) {
    const int gr = r0 + wr * 32 + (r & 3) + ((r >> 2) << 3) + rb;
    const size_t off = (size_t)gr * 1024 + oc;
    const float v = acc[r];
    const bf16 hb = __float2bfloat16(v);
    q.yh[off] = hb;
    q.yl[off] = __float2bfloat16(v - __bfloat162float(hb));
  }
}

// ---------------------------------------------------------------------------
// fused SINGLE-PASS big GEMM v3 — fine-phase (m201-style) schedule:
//   Y[r][c] = sum_k xh[r][k] * Mcat_h[c][k];  c<1024 -> O0, else O1.
// 256x256 tile, 8 waves (2Mx4N, wave 128x64), mfma_f32_16x16x32_bf16,
// acc[8][4] f32x4.  BK=32, RING of 4 LDS buffers (4 x (A[256][32]+B[256][32])
// = 128 KiB); stage tile T+3 into buf (T+3)&3 during tile T (buffer distance
// 3 => write-after-read safe behind >=4 barriers).
// 2 phases per K-tile, each: {4-8 ds_read_b128 ; 1 stage (2 gload16) ;
// s_barrier ; setprio(1) ; 16 MFMA ; setprio(0) ; [counted vmcnt] ; s_barrier}.
// Bank swizzle for 64-B rows: cb ^= ((r>>1)&3)<<4 (all 8 slots, 2-way free),
// applied on stage SOURCE + frag read (rule #21).
// ---------------------------------------------------------------------------
__global__ __launch_bounds__(512, 1) void gemmbig_kernel(
    const bf16* __restrict__ A, const bf16* __restrict__ Bh_,
    float* __restrict__ Y0, float* __restrict__ Y1) {
  __shared__ __align__(16) bf16 smem[4 * 16384];  // 128 KiB: 4 ring bufs

  const int tid = threadIdx.x;
  const int lane = tid & 63;
  const int wave = tid >> 6;
  const int wr = wave >> 2;      // 0..1 : 128-row half of M
  const int wc = wave & 3;       // 0..3 : 64-col quarter of N

  // XCD row-octant swizzle (R10-validated: A L2-resident, FETCH 49MB)
  const int pdisp = blockIdx.x + (blockIdx.y << 6);
  const int xcd = pdisp & 7;
  const int chk = pdisp >> 3;
  const int row0 = (xcd * 8 + (chk >> 3)) * 256;
  const int col0 = (chk & 7) * 256;

  // staging: A-tile [256][32] = 16KB: 2 gload16/thread.  dest linear
  // (tid*16B, +8KB); source col pre-swizzled: ((tid&3) ^ ((tid>>3)&3))*8
  const int sr = tid >> 2;                          // phys row 0..127
  const int sc = ((tid & 3) ^ ((tid >> 3) & 3)) * 8;  // src col elem
  const size_t abase0 = (size_t)(row0 + sr) * NFEAT + sc;
  const size_t abase1 = (size_t)(row0 + sr + 128) * NFEAT + sc;
  const size_t bbase0 = (size_t)(col0 + sr) * NFEAT + sc;
  const size_t bbase1 = (size_t)(col0 + sr + 128) * NFEAT + sc;
  const int dst = tid * 8;

  auto STAGE_A = [&](int buf, int k0) {
    bf16* base = smem + buf * 16384;
    gload16(base + dst, A + abase0 + k0);
    gload16(base + 4096 + dst, A + abase1 + k0);
  };
  auto STAGE_B = [&](int buf, int k0) {
    bf16* base = smem + buf * 16384 + 8192;
    gload16(base + dst, Bh_ + bbase0 + k0);
    gload16(base + 4096 + dst, Bh_ + bbase1 + k0);
  };

  // frag-read byte offsets (within buffer): row r, addr = r*64 + (kg*16 ^ swz)
  const int l15 = lane & 15;
  const int kg16 = (lane >> 4) * 16;                 // k-group byte
  const int swz = ((l15 >> 1) & 3) << 4;
  const int kcol = kg16 ^ swz;
  int aoff[8], boff[4];
#pragma unroll
  for (int fr = 0; fr < 8; ++fr)
    aoff[fr] = (wr * 128 + fr * 16 + l15) * 64 + kcol;
#pragma unroll
  for (int fc = 0; fc < 4; ++fc)
    boff[fc] = (wc * 64 + fc * 16 + l15) * 64 + kcol + 16384;  // B at +8192 elems

  auto LD = [&](int buf, int off) {
    return *(const bf16x8*)((const char*)(smem + buf * 16384) + off);
  };

  f32x4 acc[8][4] = {};

  // prologue: stage tiles 0,1,2 into bufs 0,1,2; wait tile 0 (leave 8 loads)
  STAGE_A(0, 0); STAGE_B(0, 0);
  STAGE_A(1, 32); STAGE_B(1, 32);
  STAGE_A(2, 64); STAGE_B(2, 64);
  asm volatile("s_waitcnt vmcnt(8)" ::: "memory");
  __builtin_amdgcn_s_barrier();

  for (int T = 0; T < 32; ++T) {
    const int buf = T & 3;
    const int kpre = (T + 3) * 32;
    const bool pf = (T < 29);

    bf16x8 fa[4], fb[4];

    // ---- phase 1: A fr0-3 + all B reads; stage A(T+3); 16 MFMA ----
    if (pf) STAGE_A((T + 3) & 3, kpre);
#pragma unroll
    for (int fc = 0; fc < 4; ++fc) fb[fc] = LD(buf, boff[fc]);
#pragma unroll
    for (int fr = 0; fr < 4; ++fr) fa[fr] = LD(buf, aoff[fr]);
    __builtin_amdgcn_s_barrier();
    __builtin_amdgcn_s_setprio(1);
#pragma unroll
    for (int fr = 0; fr < 4; ++fr)
#pragma unroll
      for (int fc = 0; fc < 4; ++fc)
        acc[fr][fc] = __builtin_amdgcn_mfma_f32_16x16x32_bf16(fa[fr], fb[fc], acc[fr][fc], 0, 0, 0);
    __builtin_amdgcn_s_setprio(0);
    __builtin_amdgcn_s_barrier();

    // ---- phase 2: A fr4-7 reads; stage B(T+3); 16 MFMA; counted vmcnt ----
    if (pf) STAGE_B((T + 3) & 3, kpre);
#pragma unroll
    for (int fr = 0; fr < 4; ++fr) fa[fr] = LD(buf, aoff[4 + fr]);
    __builtin_amdgcn_s_barrier();
    __builtin_amdgcn_s_setprio(1);
#pragma unroll
    for (int fr = 0; fr < 4; ++fr)
#pragma unroll
      for (int fc = 0; fc < 4; ++fc)
        acc[4 + fr][fc] = __builtin_amdgcn_mfma_f32_16x16x32_bf16(fa[fr], fb[fc], acc[4 + fr][fc], 0, 0, 0);
    __builtin_amdgcn_s_setprio(0);
    // ensure tile T+1 resident: all stages older than the 2 newest tiles.
    if (T <= 28) {
      asm volatile("s_waitcnt vmcnt(8)" ::: "memory");
    } else if (T == 29) {
      asm volatile("s_waitcnt vmcnt(4)" ::: "memory");
    } else if (T == 30) {
      asm volatile("s_waitcnt vmcnt(0)" ::: "memory");
    }
    __builtin_amdgcn_s_barrier();
  }

  // epilogue: 16x16 C/D layout: col = lane&15, row = (lane>>4)*4 + reg
  float* Yb = (col0 < 1024) ? Y0 : (Y1 - 1024);
  const int orow = row0 + wr * 128 + (lane >> 4) * 4;
  const int ocol = col0 + wc * 64 + l15;
#pragma unroll
  for (int fr = 0; fr < 8; ++fr)
#pragma unroll
    for (int fc = 0; fc < 4; ++fc)
#pragma unroll
      for (int r = 0; r < 4; ++r) {
        const int grow = orow + fr * 16 + r;
        const int gcol = ocol + fc * 16;
        Yb[(size_t)grow * NFEAT + (size_t)gcol] = acc[fr][fc][r];
      }
}

// ---------------------------------------------------------------------------
// launch
// ---------------------------------------------------------------------------
extern "C" void kernel_launch(void* const* d_in, const int* in_sizes, int n_in,
                              void* d_out, int out_size, void* d_ws, size_t ws_size,
                              hipStream_t stream) {
  (void)in_sizes; (void)n_in; (void)out_size; (void)ws_size;
  const float* x  = (const float*)d_in[0];
  const float* er = (const float*)d_in[1];
  const float* ed = (const float*)d_in[2];
  const float* dr = (const float*)d_in[3];
  const float* dd = (const float*)d_in[4];

  float* O0 = (float*)d_out;                       // bottleneck (fp32, 64 MB)
  float* O1 = O0 + (size_t)BATCH * NFEAT;          // out (fp32, 64 MB)

  // d_ws: L pairs [16 LM] (32MB) | ab (32KB) | Qh (32MB)
  bf16* Lb = (bf16*)d_ws;
  float* ab = (float*)(Lb + 16 * LM);
  bf16* Qh = (bf16*)(ab + 8 * 1024);

  // O0 scratch: Tpref @0 (64KB); 16 chain slots @1MB.
  float* Tpref = O0;
  bf16* SB = (bf16*)((char*)O0 + (1 << 20));
  auto slot = [&](int s) { return SB + (size_t)s * LM; };

  // O1 scratch (dead until gemmbig): sea-GEMM operands, 4 x 9.44MB.
  const size_t OPN = (size_t)8 * 1024 * KOP;
  bf16* Aoph = (bf16*)O1;
  bf16* Aopl = Aoph + OPN;
  bf16* Boph = Aopl + OPN;
  bf16* Bopl = Boph + OPN;

  prep_kernel<<<8, 64, 0, stream>>>(er, ed, dr, dd, ab);
  prep2_kernel<<<8, 256, 0, stream>>>(er, ed, dr, dd, ab, Tpref);
  genops_kernel<<<dim3(1024, 8), 256, 0, stream>>>(er, dr, ab, Aoph, Aopl, Boph, Bopl);
  buildgemm_kernel<<<dim3(8, 8, 8), 256, 0, stream>>>(Aoph, Aopl, Boph, Bopl,
                                                      ed, dd, Tpref, Lb);
  splith_kernel<<<4096, 256, 0, stream>>>(x, Qh);

  // ---- tree fold (R11-validated) ----
  {
    T6 p;
    p.t[0] = {Lb + 0 * LM,  slot(0)};   // L1h -> s0  (T1e hi)
    p.t[1] = {Lb + 4 * LM,  slot(2)};   // L3h -> s2  (T2e hi)
    p.t[2] = {Lb + 5 * LM,  slot(3)};   // L3l -> s3  (T2e lo)
    p.t[3] = {Lb + 8 * LM,  slot(4)};   // L5h -> s4  (T1d hi)
    p.t[4] = {Lb + 12 * LM, slot(6)};   // L7h -> s6  (T2d hi)
    p.t[5] = {Lb + 13 * LM, slot(7)};   // L7l -> s7  (T2d lo)
    transposeB_kernel<<<dim3(16, 16, 6), 256, 0, stream>>>(p);
  }
  {
    G4 p;
    p.g[0] = {slot(0),      Lb + 2 * LM,  slot(8),  slot(9)};   // Q1e = T1e * L2^T
    p.g[1] = {Lb + 6 * LM,  slot(2),      slot(10), slot(11)};  // Q2te = L4 * T2e^T
    p.g[2] = {slot(4),      Lb + 10 * LM, slot(12), slot(13)};  // Q1d = T1d * L6^T
    p.g[3] = {Lb + 14 * LM, slot(6),      slot(14), slot(15)};  // Q2td = L8 * T2d^T
    chaingemm4_kernel<<<dim3(16, 16, 4), 256, 0, stream>>>(p);
  }
  {
    G4 p;
    p.g[0] = {slot(8),  slot(10), slot(0), slot(1)};   // Kce = Menc^T
    p.g[1] = {slot(12), slot(14), slot(2), slot(3)};   // Kcd = Mdec^T
    p.g[2] = p.g[0];
    p.g[3] = p.g[1];
    chaingemm4_kernel<<<dim3(16, 16, 2), 256, 0, stream>>>(p);
  }
  {
    T6 p;
    p.t[0] = {slot(0), Lb + 0 * LM};    // Menc -> Mcat rows 0-1023
    p.t[1] = {slot(2), Lb + 2 * LM};    // Mdec
    p.t[2] = p.t[0]; p.t[3] = p.t[0]; p.t[4] = p.t[0]; p.t[5] = p.t[0];
    transposeB_kernel<<<dim3(16, 16, 2), 256, 0, stream>>>(p);
  }
  {
    G4 p;
    p.g[0] = {Lb + 2 * LM, slot(0), Lb + 1 * LM, slot(4)};  // Mtot -> Mcat rows 1024+
    p.g[1] = p.g[0]; p.g[2] = p.g[0]; p.g[3] = p.g[0];
    chaingemm4_kernel<<<dim3(16, 16, 1), 256, 0, stream>>>(p);
  }

  // fused single-pass big GEMM: both outputs from x in one dispatch.
  gemmbig_kernel<<<dim3(64, 8), 512, 0, stream>>>(Qh, Lb, O0, O1);
}

// Round 15
// 253.125 us; speedup vs baseline: 3.6455x; 1.0161x over previous
//
#include <hip/hip_runtime.h>
#include <hip/hip_bf16.h>
#include <cstdint>
#include <cstddef>

#define H 512
#define NFEAT 1024
#define BATCH 16384
#define LM ((size_t)1 << 20)   // elems per 1024x1024 matrix
#define KOP 576                // padded K for the build GEMM (513 used)

using bf16 = __hip_bfloat16;
using bf16x8 = __attribute__((ext_vector_type(8))) __bf16;
using f32x4 = __attribute__((ext_vector_type(4))) float;
using f32x16 = __attribute__((ext_vector_type(16))) float;

// ---------------------------------------------------------------------------
// async global -> LDS, 16 bytes per lane
// ---------------------------------------------------------------------------
__device__ __forceinline__ void gload16(void* lds, const void* g) {
  __builtin_amdgcn_global_load_lds(
      (__attribute__((address_space(1))) void*)g,
      (__attribute__((address_space(3))) void*)lds,
      16, 0, 0);
}

// ---------------------------------------------------------------------------
// prep: per matrix, compute a[], b[] for core = diag(d) + a*1^T + b*u^T
// Closed-form Cayley (rank-2 Woodbury), verified R0-R14.
// ---------------------------------------------------------------------------
__global__ void prep_kernel(const float* __restrict__ er, const float* __restrict__ ed,
                            const float* __restrict__ dr, const float* __restrict__ dd,
                            float* __restrict__ ab) {
  const int mat = blockIdx.x;          // 0..7
  const int lane = threadIdx.x;        // 0..63
  const float* u = (mat < 4) ? (er + mat * H) : (dr + (mat - 4) * H);
  const float* d = (mat < 4) ? (ed + mat * H) : (dd + (mat - 4) * H);

  double s = 0.0, q = 0.0;
  for (int k = 0; k < 8; ++k) {
    double v = (double)u[lane + 64 * k];
    s += v;
    q += v * v;
  }
  for (int off = 32; off; off >>= 1) {
    s += __shfl_down(s, off);
    q += __shfl_down(q, off);
  }
  s = __shfl(s, 0);
  q = __shfl(q, 0);

  const double det = 1.0 - s * s + (double)H * q;
  const double cuv = 2.0 * (1.0 + s) / det;
  const double cuu = -2.0 * (double)H / det;
  const double cvv = -2.0 * q / det;
  const double cvu = -2.0 * (1.0 - s) / det;

  float* a = ab + mat * 1024;
  float* b = a + H;
  for (int k = 0; k < 8; ++k) {
    int idx = lane + 64 * k;
    double ui = (double)u[idx], di = (double)d[idx];
    a[idx] = (float)(di * (cuv * ui + cvv));
    b[idx] = (float)(di * (cuu * ui + cvu));
  }
}

// ---------------------------------------------------------------------------
// prep2: stride-4-residue inclusive prefix tables over a, a_rev, d, d_rev.
// ---------------------------------------------------------------------------
__global__ __launch_bounds__(256) void prep2_kernel(
    const float* __restrict__ er, const float* __restrict__ ed,
    const float* __restrict__ dr, const float* __restrict__ dd,
    const float* __restrict__ ab, float* __restrict__ Tpref) {
  __shared__ float buf[4][512];
  __shared__ float tmp[4][512];
  const int mat = blockIdx.x;
  const float* d = (mat < 4) ? (ed + mat * H) : (dd + (mat - 4) * H);
  const float* a = ab + mat * 1024;
  const int t = threadIdx.x;
  for (int m = t; m < 512; m += 256) {
    buf[0][m] = a[m];
    buf[1][m] = a[511 - m];
    buf[2][m] = d[m];
    buf[3][m] = d[511 - m];
  }
  __syncthreads();
  for (int s = 4; s <= 256; s <<= 1) {
    for (int m = t; m < 512; m += 256)
#pragma unroll
      for (int q = 0; q < 4; ++q) tmp[q][m] = (m >= s) ? buf[q][m - s] : 0.f;
    __syncthreads();
    for (int m = t; m < 512; m += 256)
#pragma unroll
      for (int q = 0; q < 4; ++q) buf[q][m] += tmp[q][m];
    __syncthreads();
  }
  float* tp = Tpref + mat * 2048;
  for (int m = t; m < 512; m += 256) {
    tp[m] = buf[0][m];
    tp[512 + m] = buf[1][m];
    tp[1024 + m] = buf[2][m];
    tp[1536 + m] = buf[3][m];
  }
}

// ---------------------------------------------------------------------------
// genops (R12-validated): K=513 (padded KOP=576) operands for the sea-GEMM.
// ---------------------------------------------------------------------------
__global__ __launch_bounds__(256) void genops_kernel(
    const float* __restrict__ er, const float* __restrict__ dr,
    const float* __restrict__ ab,
    bf16* __restrict__ Ah, bf16* __restrict__ Al,
    bf16* __restrict__ Bh, bf16* __restrict__ Bl) {
  const int x = blockIdx.x;            // 0..1023
  const int mat = blockIdx.y;          // 0..7
  const float* u = (mat < 4) ? (er + mat * H) : (dr + (mat - 4) * H);
  const float* b = ab + mat * 1024 + H;
  const int t = threadIdx.x;
  const size_t base = ((size_t)mat * 1024 + x) * KOP;
  for (int k = t; k < KOP; k += 256) {
    float av = 0.f, bv = 0.f;
    if (k <= 128) {
      const int o = 4 * k;
      const int ia = x - o;
      av = (ia >= 0 && ia < 512) ? b[ia] : 0.f;
      bv = (ia >= 0 && ia < 512) ? u[ia] : 0.f;
    } else if (k <= 256) {
      const int o = 4 * (k - 129) + 1;
      const int ia = 511 - x + o;
      const int ib = x - o;
      av = (ia >= 0 && ia < 512) ? u[ia] : 0.f;
      bv = (ib >= 0 && ib < 512) ? b[ib] : 0.f;
    } else if (k <= 384) {
      const int o = 4 * (k - 257) + 2;
      const int ia = 511 - x + o;
      av = (ia >= 0 && ia < 512) ? b[ia] : 0.f;
      bv = (ia >= 0 && ia < 512) ? u[ia] : 0.f;
    } else if (k <= 512) {
      const int o = 4 * (k - 385) + 3;
      const int ia = x - o;
      const int ib = 511 - x + o;
      av = (ia >= 0 && ia < 512) ? u[ia] : 0.f;
      bv = (ib >= 0 && ib < 512) ? b[ib] : 0.f;
    }
    const bf16 ah = __float2bfloat16(av);
    Ah[base + k] = ah;
    Al[base + k] = __float2bfloat16(av - __bfloat162float(ah));
    const bf16 bh = __float2bfloat16(bv);
    Bh[base + k] = bh;
    Bl[base + k] = __float2bfloat16(bv - __bfloat162float(bh));
  }
}

// ---------------------------------------------------------------------------
// buildgemm (R12-validated): L[mat] = Aop @ Bop^T (3-pass split-bf16) with
// a-part / diagonal terms fused in the epilogue.  128x128 tile, BK=64.
// ---------------------------------------------------------------------------
__global__ __launch_bounds__(256) void buildgemm_kernel(
    const bf16* __restrict__ Ah, const bf16* __restrict__ Al,
    const bf16* __restrict__ Bh, const bf16* __restrict__ Bl,
    const float* __restrict__ ed, const float* __restrict__ dd,
    const float* __restrict__ Tpref, bf16* __restrict__ Lbase) {
  __shared__ __align__(16) bf16 smem[4 * 8192];
  __shared__ float pa[512], parev[512], pd[512], pdrev[512], sdl[512];
  bf16* sAh = smem;
  bf16* sAl = smem + 8192;
  bf16* sBh = smem + 16384;
  bf16* sBl = smem + 24576;

  const int tid = threadIdx.x;
  const int lane = tid & 63;
  const int wave = tid >> 6;
  const int wr = wave >> 1;
  const int wc = wave & 1;
  const int mat = blockIdx.z;
  const int row0 = blockIdx.x * 128;
  const int col0 = blockIdx.y * 128;

  {
    const float* tp = Tpref + mat * 2048;
    const float* d = (mat < 4) ? (ed + mat * H) : (dd + (mat - 4) * H);
    for (int m = tid; m < 512; m += 256) {
      pa[m] = tp[m];
      parev[m] = tp[512 + m];
      pd[m] = tp[1024 + m];
      pdrev[m] = tp[1536 + m];
      sdl[m] = d[m];
    }
  }

  const size_t OPS = (size_t)mat * 1024 * KOP;
  const int srow = tid >> 3;
  const int sce = (((tid * 16) ^ (((tid >> 3) & 7) << 4)) & 127) >> 1;
  const size_t abase = OPS + (size_t)(row0 + srow) * KOP + sce;
  const size_t bbase = OPS + (size_t)(col0 + srow) * KOP + sce;
  const int dst0 = tid * 8;

  f32x16 acc[2][2] = {};

  for (int kt = 0; kt < 9; ++kt) {
    const int k0 = kt * 64;
#pragma unroll
    for (int q = 0; q < 4; ++q) {
      const size_t ga = abase + (size_t)(32 * q) * KOP + k0;
      const size_t gb = bbase + (size_t)(32 * q) * KOP + k0;
      const int dq = q * 2048 + dst0;
      gload16(sAh + dq, Ah + ga);
      gload16(sAl + dq, Al + ga);
      gload16(sBh + dq, Bh + gb);
      gload16(sBl + dq, Bl + gb);
    }
    __syncthreads();

    const int l31 = lane & 31;
    const int kh16 = (lane >> 5) * 16;
#pragma unroll
    for (int ks = 0; ks < 4; ++ks) {
      bf16x8 fah[2], fal[2], fbh[2], fbl[2];
#pragma unroll
      for (int m = 0; m < 2; ++m) {
        const int arow = wr * 64 + m * 32 + l31;
        const int abk = (arow * 128 + ks * 32 + kh16) ^ ((arow & 7) << 4);
        fah[m] = *(const bf16x8*)((const char*)sAh + abk);
        fal[m] = *(const bf16x8*)((const char*)sAl + abk);
        const int brow = wc * 64 + m * 32 + l31;
        const int bbk = (brow * 128 + ks * 32 + kh16) ^ ((brow & 7) << 4);
        fbh[m] = *(const bf16x8*)((const char*)sBh + bbk);
        fbl[m] = *(const bf16x8*)((const char*)sBl + bbk);
      }
#pragma unroll
      for (int m = 0; m < 2; ++m)
#pragma unroll
        for (int n = 0; n < 2; ++n) {
          acc[m][n] = __builtin_amdgcn_mfma_f32_32x32x16_bf16(fah[m], fbh[n], acc[m][n], 0, 0, 0);
          acc[m][n] = __builtin_amdgcn_mfma_f32_32x32x16_bf16(fah[m], fbl[n], acc[m][n], 0, 0, 0);
          acc[m][n] = __builtin_amdgcn_mfma_f32_32x32x16_bf16(fal[m], fbh[n], acc[m][n], 0, 0, 0);
        }
    }
    __syncthreads();
  }

  auto apart = [&](int i, int j) -> float {
    const int lo = max(0, max(i, j) - 511);
    const int hi = min(512, min(i, j));
    if (lo > hi) return 0.f;
    float v = 0.f;
    {
      int o1 = lo + ((0 - lo) & 3), o2 = hi - (hi & 3);
      if (o1 <= o2) { int mx = i - o1, mn = i - o2; v += pa[mx] - (mn >= 4 ? pa[mn - 4] : 0.f); }
    }
    {
      int o1 = lo + ((1 - lo) & 3), o2 = hi - ((hi - 1) & 3);
      if (o1 <= o2) { int mx = j - o1, mn = j - o2; v += pa[mx] - (mn >= 4 ? pa[mn - 4] : 0.f); }
    }
    {
      int o1 = lo + ((2 - lo) & 3), o2 = hi - ((hi - 2) & 3);
      if (o1 <= o2) { int mx = i - o1, mn = i - o2; v += parev[mx] - (mn >= 4 ? parev[mn - 4] : 0.f); }
    }
    {
      int o1 = lo + ((3 - lo) & 3), o2 = hi - ((hi - 3) & 3);
      if (o1 <= o2) { int mx = j - o1, mn = j - o2; v += parev[mx] - (mn >= 4 ? parev[mn - 4] : 0.f); }
    }
    if (i == j) {
      {
        int o1 = lo + ((0 - lo) & 3), o2 = hi - (hi & 3);
        if (o1 <= o2) { int mx = i - o1, mn = i - o2; v += pd[mx] - (mn >= 4 ? pd[mn - 4] : 0.f); }
      }
      {
        int o1 = lo + ((2 - lo) & 3), o2 = hi - ((hi - 2) & 3);
        if (o1 <= o2) { int mx = i - o1, mn = i - o2; v += pdrev[mx] - (mn >= 4 ? pdrev[mn - 4] : 0.f); }
      }
    }
    const int m2 = i + j - 511;
    if (m2 >= 0 && !(m2 & 1)) {
      const int os = m2 >> 1;
      if (os >= lo && os <= hi) {
        const int r = os & 3;
        if (r == 1) v += sdl[j - os];
        else if (r == 3) v += sdl[511 - (j - os)];
      }
    }
    return v;
  };

  const int ocol0 = col0 + wc * 64 + (lane & 31);
  const int rb = (lane >> 5) << 2;
#pragma unroll
  for (int m = 0; m < 2; ++m)
#pragma unroll
    for (int n = 0; n < 2; ++n)
#pragma unroll
      for (int r = 0; r < 16; ++r) {
        const int grow = row0 + wr * 64 + m * 32 + (r & 3) + ((r >> 2) << 3) + rb;
        const int gcol = ocol0 + n * 32;
        const float v = acc[m][n][r] + apart(grow, gcol);
        const size_t off = ((size_t)mat << 21) + ((size_t)grow << 10) + (size_t)gcol;
        const bf16 hb = __float2bfloat16(v);
        Lbase[off] = hb;
        Lbase[off + LM] = __float2bfloat16(v - __bfloat162float(hb));
      }
}

// ---------------------------------------------------------------------------
// split fp32 -> hi bf16 only
// ---------------------------------------------------------------------------
__global__ void splith_kernel(const float* __restrict__ x, bf16* __restrict__ h) {
  const int n4 = BATCH * NFEAT / 4;
  int idx = blockIdx.x * blockDim.x + threadIdx.x;
  int stride = gridDim.x * blockDim.x;
  for (int i = idx; i < n4; i += stride) {
    float4 v = ((const float4*)x)[i];
    union { bf16 b[4]; short4 s; } Hu;
    Hu.b[0] = __float2bfloat16(v.x);
    Hu.b[1] = __float2bfloat16(v.y);
    Hu.b[2] = __float2bfloat16(v.z);
    Hu.b[3] = __float2bfloat16(v.w);
    ((short4*)h)[i] = Hu.s;
  }
}

// ---------------------------------------------------------------------------
// batched single-array transpose: D = S^T for one 1024x1024 bf16 array per z.
// ---------------------------------------------------------------------------
struct TPtrs { const bf16* s; bf16* d; };
struct T6 { TPtrs t[6]; };

__global__ __launch_bounds__(256) void transposeB_kernel(T6 p) {
  const bf16* S = p.t[blockIdx.z].s;
  bf16* D = p.t[blockIdx.z].d;
  __shared__ ushort tile[64][68];
  const int i0 = blockIdx.x * 64, j0 = blockIdx.y * 64;
  const int tid = threadIdx.x;
  const int rr = tid >> 4;
  const int cc = (tid & 15) * 4;
#pragma unroll
  for (int it = 0; it < 4; ++it) {
    const int row = it * 16 + rr;
    const size_t so = (size_t)(i0 + row) * 1024 + j0 + cc;
    ushort4 v = *(const ushort4*)((const ushort*)S + so);
    tile[row][cc] = v.x; tile[row][cc + 1] = v.y;
    tile[row][cc + 2] = v.z; tile[row][cc + 3] = v.w;
  }
  __syncthreads();
#pragma unroll
  for (int it = 0; it < 4; ++it) {
    const int row = it * 16 + rr;
    ushort4 o;
    o.x = tile[cc][row];     o.y = tile[cc + 1][row];
    o.z = tile[cc + 2][row]; o.w = tile[cc + 3][row];
    const size_t dofs = (size_t)(j0 + row) * 1024 + i0 + cc;
    *(ushort4*)((ushort*)D + dofs) = o;
  }
}

// ---------------------------------------------------------------------------
// batched 2-pass chain GEMM (R11-validated): Y = A * B^T per z.
// ---------------------------------------------------------------------------
struct GPtrs { const bf16* a; const bf16* b; bf16* yh; bf16* yl; };
struct G4 { GPtrs g[4]; };

__global__ __launch_bounds__(256) void chaingemm4_kernel(G4 p) {
  GPtrs q = p.g[blockIdx.z];
  const bf16* A = q.a;
  const bf16* Bh = q.b;
  const bf16* Bl = q.b + LM;

  __shared__ __align__(16) bf16 smem[2 * 3 * 4096];  // 48 KiB

  const int tid = threadIdx.x;
  const int lane = tid & 63;
  const int wave = tid >> 6;
  const int wr = wave >> 1, wc = wave & 1;
  const int r0 = blockIdx.x * 64, c0 = blockIdx.y * 64;

  const int srow = tid >> 3;
  const int scol = (((tid & 7) ^ (srow & 7))) * 8;
  const int dst = tid * 8;
  const size_t ga0 = (size_t)(r0 + srow) * 1024 + scol;
  const size_t gb0 = (size_t)(c0 + srow) * 1024 + scol;

  auto STAGE = [&](int nb, int k0) {
    bf16* base = smem + nb * 12288;
    gload16(base + dst,        A + ga0 + k0);
    gload16(base + 2048 + dst, A + ga0 + 32 * 1024 + k0);
    gload16(base + 4096 + dst,        Bh + gb0 + k0);
    gload16(base + 4096 + 2048 + dst, Bh + gb0 + 32 * 1024 + k0);
    gload16(base + 8192 + dst,        Bl + gb0 + k0);
    gload16(base + 8192 + 2048 + dst, Bl + gb0 + 32 * 1024 + k0);
  };

  const int l31 = lane & 31;
  const int klg = lane >> 5;
  const int ar = wr * 32 + l31;
  const int br = wc * 32 + l31;
  int aoff[4], boff[4];
#pragma unroll
  for (int ks = 0; ks < 4; ++ks) {
    const int lgA = (ks << 1) | klg;
    aoff[ks] = ar * 64 + ((lgA ^ (ar & 7)) << 3);
    boff[ks] = br * 64 + ((lgA ^ (br & 7)) << 3);
  }

  f32x16 acc = {};

  STAGE(0, 0);
  asm volatile("s_waitcnt vmcnt(0)" ::: "memory");
  __builtin_amdgcn_s_barrier();

  for (int t = 0; t < 16; ++t) {
    const int buf = t & 1;
    const int nb = buf ^ 1;
    const bool pf = (t < 15);
    if (pf) STAGE(nb, (t + 1) * 64);

    const bf16* pA = smem + buf * 12288;
    const bf16* pBh = pA + 4096;
    const bf16* pBl = pA + 8192;
#pragma unroll
    for (int ks = 0; ks < 4; ++ks) {
      bf16x8 ah = *(const bf16x8*)(pA + aoff[ks]);
      bf16x8 bh = *(const bf16x8*)(pBh + boff[ks]);
      bf16x8 bl = *(const bf16x8*)(pBl + boff[ks]);
      acc = __builtin_amdgcn_mfma_f32_32x32x16_bf16(ah, bh, acc, 0, 0, 0);
      acc = __builtin_amdgcn_mfma_f32_32x32x16_bf16(ah, bl, acc, 0, 0, 0);
    }
    if (pf) asm volatile("s_waitcnt vmcnt(0)" ::: "memory");
    __builtin_amdgcn_s_barrier();
  }

  const int oc = c0 + wc * 32 + l31;
  const int rb = (lane >> 5) << 2;
#pragma unroll
  for (int r = 0; r < 16; ++r) {
    const int gr = r0 + wr * 32 + (r & 3) + ((r >> 2) << 3) + rb;
    const size_t off = (size_t)gr * 1024 + oc;
    const float v = acc[r];
    const bf16 hb = __float2bfloat16(v);
    q.yh[off] = hb;
    q.yl[off] = __float2bfloat16(v - __bfloat162float(hb));
  }
}

// ---------------------------------------------------------------------------
// fused SINGLE-PASS big GEMM v4 — 2 blocks/CU for independent barrier domains:
//   Y[r][c] = sum_k xh[r][k] * Mcat_h[c][k];  c<1024 -> O0, else O1.
// 256 threads (4 waves, 2Mx2N, wave 64x128), tile 128x256, BK=32,
// mfma_f32_16x16x32_bf16, acc[4][8] f32x4 (128 regs).
// Ring-3 LDS (3 x (A[128][32] + B[256][32]) = 72 KiB) -> 2 blocks/CU:
// two independent barrier groups per CU so one block's MFMA overlaps the
// other's stage/LDS phase (m114 mechanism).  Stage tile T+2 during T
// (write target's reads finished before the previous barrier); counted
// vmcnt(6) per tile, one barrier per tile (R13-validated safety logic).
// Swizzle: R14's zero-conflict pattern verbatim (source-col XOR + read XOR).
// XCD swizzle: xcd owns 2048-row A-chunk (4 MB, L2-resident).
// ---------------------------------------------------------------------------
__global__ __launch_bounds__(256, 2) void gemmbig_kernel(
    const bf16* __restrict__ A, const bf16* __restrict__ Bh_,
    float* __restrict__ Y0, float* __restrict__ Y1) {
  __shared__ __align__(16) bf16 smem[3 * 12288];  // 72 KiB

  const int tid = threadIdx.x;
  const int lane = tid & 63;
  const int wave = tid >> 6;     // 0..3
  const int wr = wave >> 1;      // 0..1 : 64-row half
  const int wc = wave & 1;       // 0..1 : 128-col half

  // grid 1024 linear; xcd owns rows [xcd*2048, +2048), cycles 8 col panels
  const int pdisp = blockIdx.x;
  const int xcd = pdisp & 7;
  const int chk = pdisp >> 3;          // 0..127
  const int row0 = (xcd * 16 + (chk >> 3)) * 128;
  const int col0 = (chk & 7) * 256;    // row index into Mcat

  // staging: dest linear tid*16B (+4KB per round); source col pre-swizzled
  const int sr = tid >> 2;                            // 0..63
  const int sc = ((tid & 3) ^ ((tid >> 3) & 3)) * 8;  // src col elem
  const size_t abase0 = (size_t)(row0 + sr) * NFEAT + sc;
  const size_t abase1 = abase0 + (size_t)64 * NFEAT;
  const size_t bbase = (size_t)(col0 + sr) * NFEAT + sc;
  const int dst = tid * 8;

  auto STAGE_A = [&](int buf, int k0) {   // A[128][32] = 8KB: 2 loads
    bf16* base = smem + buf * 12288;
    gload16(base + dst, A + abase0 + k0);
    gload16(base + 2048 + dst, A + abase1 + k0);
  };
  auto STAGE_B = [&](int buf, int k0) {   // B[256][32] = 16KB: 4 loads
    bf16* base = smem + buf * 12288 + 4096;
#pragma unroll
    for (int q = 0; q < 4; ++q)
      gload16(base + q * 2048 + dst, Bh_ + bbase + (size_t)(64 * q) * NFEAT + k0);
  };

  // frag-read byte offsets: row r -> r*64 + (kg*16 ^ ((l15>>1)&3)<<4)
  const int l15 = lane & 15;
  const int kcol = ((lane >> 4) * 16) ^ (((l15 >> 1) & 3) << 4);
  int aoff[4], boff[8];
#pragma unroll
  for (int fr = 0; fr < 4; ++fr)
    aoff[fr] = (wr * 64 + fr * 16 + l15) * 64 + kcol;
#pragma unroll
  for (int fc = 0; fc < 8; ++fc)
    boff[fc] = 8192 + (wc * 128 + fc * 16 + l15) * 64 + kcol;  // B at +4096 elems

  auto LD = [&](int buf, int off) {
    return *(const bf16x8*)((const char*)(smem + buf * 12288) + off);
  };

  f32x4 acc[4][8] = {};

  // prologue: stage tiles 0,1; wait tile 0 (leave tile 1's 6 loads)
  STAGE_A(0, 0); STAGE_B(0, 0);
  STAGE_A(1, 32); STAGE_B(1, 32);
  asm volatile("s_waitcnt vmcnt(6)" ::: "memory");
  __builtin_amdgcn_s_barrier();

  for (int T = 0; T < 32; ++T) {
    const int buf = T % 3;
    if (T < 30) {
      const int nb = (T + 2) % 3;
      STAGE_A(nb, (T + 2) * 32);
      STAGE_B(nb, (T + 2) * 32);
    }

    bf16x8 fa[4], fb[4];
#pragma unroll
    for (int fr = 0; fr < 4; ++fr) fa[fr] = LD(buf, aoff[fr]);
#pragma unroll
    for (int fc = 0; fc < 4; ++fc) fb[fc] = LD(buf, boff[fc]);
    __builtin_amdgcn_s_setprio(1);
#pragma unroll
    for (int fr = 0; fr < 4; ++fr)
#pragma unroll
      for (int fc = 0; fc < 4; ++fc)
        acc[fr][fc] = __builtin_amdgcn_mfma_f32_16x16x32_bf16(fa[fr], fb[fc], acc[fr][fc], 0, 0, 0);
    __builtin_amdgcn_s_setprio(0);
#pragma unroll
    for (int fc = 0; fc < 4; ++fc) fb[fc] = LD(buf, boff[4 + fc]);
    __builtin_amdgcn_s_setprio(1);
#pragma unroll
    for (int fr = 0; fr < 4; ++fr)
#pragma unroll
      for (int fc = 0; fc < 4; ++fc)
        acc[fr][4 + fc] = __builtin_amdgcn_mfma_f32_16x16x32_bf16(fa[fr], fb[fc], acc[fr][4 + fc], 0, 0, 0);
    __builtin_amdgcn_s_setprio(0);

    // tile T+1 resident: all but the 6 newest (tile T+2) loads complete
    if (T <= 29) {
      asm volatile("s_waitcnt vmcnt(6)" ::: "memory");
    } else if (T == 30) {
      asm volatile("s_waitcnt vmcnt(0)" ::: "memory");
    }
    __builtin_amdgcn_s_barrier();
  }

  // epilogue: 16x16 C/D layout: col = lane&15, row = (lane>>4)*4 + reg
  float* Yb = (col0 < 1024) ? Y0 : (Y1 - 1024);
  const int orow = row0 + wr * 64 + (lane >> 4) * 4;
  const int ocol = col0 + wc * 128 + l15;
#pragma unroll
  for (int fr = 0; fr < 4; ++fr)
#pragma unroll
    for (int fc = 0; fc < 8; ++fc)
#pragma unroll
      for (int r = 0; r < 4; ++r) {
        const int grow = orow + fr * 16 + r;
        const int gcol = ocol + fc * 16;
        Yb[(size_t)grow * NFEAT + (size_t)gcol] = acc[fr][fc][r];
      }
}

// ---------------------------------------------------------------------------
// launch
// ---------------------------------------------------------------------------
extern "C" void kernel_launch(void* const* d_in, const int* in_sizes, int n_in,
                              void* d_out, int out_size, void* d_ws, size_t ws_size,
                              hipStream_t stream) {
  (void)in_sizes; (void)n_in; (void)out_size; (void)ws_size;
  const float* x  = (const float*)d_in[0];
  const float* er = (const float*)d_in[1];
  const float* ed = (const float*)d_in[2];
  const float* dr = (const float*)d_in[3];
  const float* dd = (const float*)d_in[4];

  float* O0 = (float*)d_out;                       // bottleneck (fp32, 64 MB)
  float* O1 = O0 + (size_t)BATCH * NFEAT;          // out (fp32, 64 MB)

  // d_ws: L pairs [16 LM] (32MB) | ab (32KB) | Qh (32MB)
  bf16* Lb = (bf16*)d_ws;
  float* ab = (float*)(Lb + 16 * LM);
  bf16* Qh = (bf16*)(ab + 8 * 1024);

  // O0 scratch: Tpref @0 (64KB); 16 chain slots @1MB.
  float* Tpref = O0;
  bf16* SB = (bf16*)((char*)O0 + (1 << 20));
  auto slot = [&](int s) { return SB + (size_t)s * LM; };

  // O1 scratch (dead until gemmbig): sea-GEMM operands, 4 x 9.44MB.
  const size_t OPN = (size_t)8 * 1024 * KOP;
  bf16* Aoph = (bf16*)O1;
  bf16* Aopl = Aoph + OPN;
  bf16* Boph = Aopl + OPN;
  bf16* Bopl = Boph + OPN;

  prep_kernel<<<8, 64, 0, stream>>>(er, ed, dr, dd, ab);
  prep2_kernel<<<8, 256, 0, stream>>>(er, ed, dr, dd, ab, Tpref);
  genops_kernel<<<dim3(1024, 8), 256, 0, stream>>>(er, dr, ab, Aoph, Aopl, Boph, Bopl);
  buildgemm_kernel<<<dim3(8, 8, 8), 256, 0, stream>>>(Aoph, Aopl, Boph, Bopl,
                                                      ed, dd, Tpref, Lb);
  splith_kernel<<<4096, 256, 0, stream>>>(x, Qh);

  // ---- tree fold (R11-validated) ----
  {
    T6 p;
    p.t[0] = {Lb + 0 * LM,  slot(0)};   // L1h -> s0  (T1e hi)
    p.t[1] = {Lb + 4 * LM,  slot(2)};   // L3h -> s2  (T2e hi)
    p.t[2] = {Lb + 5 * LM,  slot(3)};   // L3l -> s3  (T2e lo)
    p.t[3] = {Lb + 8 * LM,  slot(4)};   // L5h -> s4  (T1d hi)
    p.t[4] = {Lb + 12 * LM, slot(6)};   // L7h -> s6  (T2d hi)
    p.t[5] = {Lb + 13 * LM, slot(7)};   // L7l -> s7  (T2d lo)
    transposeB_kernel<<<dim3(16, 16, 6), 256, 0, stream>>>(p);
  }
  {
    G4 p;
    p.g[0] = {slot(0),      Lb + 2 * LM,  slot(8),  slot(9)};   // Q1e = T1e * L2^T
    p.g[1] = {Lb + 6 * LM,  slot(2),      slot(10), slot(11)};  // Q2te = L4 * T2e^T
    p.g[2] = {slot(4),      Lb + 10 * LM, slot(12), slot(13)};  // Q1d = T1d * L6^T
    p.g[3] = {Lb + 14 * LM, slot(6),      slot(14), slot(15)};  // Q2td = L8 * T2d^T
    chaingemm4_kernel<<<dim3(16, 16, 4), 256, 0, stream>>>(p);
  }
  {
    G4 p;
    p.g[0] = {slot(8),  slot(10), slot(0), slot(1)};   // Kce = Menc^T
    p.g[1] = {slot(12), slot(14), slot(2), slot(3)};   // Kcd = Mdec^T
    p.g[2] = p.g[0];
    p.g[3] = p.g[1];
    chaingemm4_kernel<<<dim3(16, 16, 2), 256, 0, stream>>>(p);
  }
  {
    T6 p;
    p.t[0] = {slot(0), Lb + 0 * LM};    // Menc -> Mcat rows 0-1023
    p.t[1] = {slot(2), Lb + 2 * LM};    // Mdec
    p.t[2] = p.t[0]; p.t[3] = p.t[0]; p.t[4] = p.t[0]; p.t[5] = p.t[0];
    transposeB_kernel<<<dim3(16, 16, 2), 256, 0, stream>>>(p);
  }
  {
    G4 p;
    p.g[0] = {Lb + 2 * LM, slot(0), Lb + 1 * LM, slot(4)};  // Mtot -> Mcat rows 1024+
    p.g[1] = p.g[0]; p.g[2] = p.g[0]; p.g[3] = p.g[0];
    chaingemm4_kernel<<<dim3(16, 16, 1), 256, 0, stream>>>(p);
  }

  // fused single-pass big GEMM: both outputs from x in one dispatch.
  gemmbig_kernel<<<1024, 256, 0, stream>>>(Qh, Lb, O0, O1);
}

// Round 16
// 246.275 us; speedup vs baseline: 3.7469x; 1.0278x over previous
//
#include <hip/hip_runtime.h>
#include <hip/hip_bf16.h>
#include <cstdint>
#include <cstddef>

#define H 512
#define NFEAT 1024
#define BATCH 16384
#define LM ((size_t)1 << 20)   // elems per 1024x1024 matrix
#define KOP 576                // padded K for the build GEMM (513 used)

using bf16 = __hip_bfloat16;
using bf16x8 = __attribute__((ext_vector_type(8))) __bf16;
using f32x4 = __attribute__((ext_vector_type(4))) float;
using f32x16 = __attribute__((ext_vector_type(16))) float;

// ---------------------------------------------------------------------------
// async global -> LDS, 16 bytes per lane
// ---------------------------------------------------------------------------
__device__ __forceinline__ void gload16(void* lds, const void* g) {
  __builtin_amdgcn_global_load_lds(
      (__attribute__((address_space(1))) void*)g,
      (__attribute__((address_space(3))) void*)lds,
      16, 0, 0);
}

// ---------------------------------------------------------------------------
// prep: per matrix, compute a[], b[] for core = diag(d) + a*1^T + b*u^T
// Closed-form Cayley (rank-2 Woodbury), verified R0-R15.
// ---------------------------------------------------------------------------
__global__ void prep_kernel(const float* __restrict__ er, const float* __restrict__ ed,
                            const float* __restrict__ dr, const float* __restrict__ dd,
                            float* __restrict__ ab) {
  const int mat = blockIdx.x;          // 0..7
  const int lane = threadIdx.x;        // 0..63
  const float* u = (mat < 4) ? (er + mat * H) : (dr + (mat - 4) * H);
  const float* d = (mat < 4) ? (ed + mat * H) : (dd + (mat - 4) * H);

  double s = 0.0, q = 0.0;
  for (int k = 0; k < 8; ++k) {
    double v = (double)u[lane + 64 * k];
    s += v;
    q += v * v;
  }
  for (int off = 32; off; off >>= 1) {
    s += __shfl_down(s, off);
    q += __shfl_down(q, off);
  }
  s = __shfl(s, 0);
  q = __shfl(q, 0);

  const double det = 1.0 - s * s + (double)H * q;
  const double cuv = 2.0 * (1.0 + s) / det;
  const double cuu = -2.0 * (double)H / det;
  const double cvv = -2.0 * q / det;
  const double cvu = -2.0 * (1.0 - s) / det;

  float* a = ab + mat * 1024;
  float* b = a + H;
  for (int k = 0; k < 8; ++k) {
    int idx = lane + 64 * k;
    double ui = (double)u[idx], di = (double)d[idx];
    a[idx] = (float)(di * (cuv * ui + cvv));
    b[idx] = (float)(di * (cuu * ui + cvu));
  }
}

// ---------------------------------------------------------------------------
// prep2: stride-4-residue inclusive prefix tables over a, a_rev, d, d_rev.
// ---------------------------------------------------------------------------
__global__ __launch_bounds__(256) void prep2_kernel(
    const float* __restrict__ er, const float* __restrict__ ed,
    const float* __restrict__ dr, const float* __restrict__ dd,
    const float* __restrict__ ab, float* __restrict__ Tpref) {
  __shared__ float buf[4][512];
  __shared__ float tmp[4][512];
  const int mat = blockIdx.x;
  const float* d = (mat < 4) ? (ed + mat * H) : (dd + (mat - 4) * H);
  const float* a = ab + mat * 1024;
  const int t = threadIdx.x;
  for (int m = t; m < 512; m += 256) {
    buf[0][m] = a[m];
    buf[1][m] = a[511 - m];
    buf[2][m] = d[m];
    buf[3][m] = d[511 - m];
  }
  __syncthreads();
  for (int s = 4; s <= 256; s <<= 1) {
    for (int m = t; m < 512; m += 256)
#pragma unroll
      for (int q = 0; q < 4; ++q) tmp[q][m] = (m >= s) ? buf[q][m - s] : 0.f;
    __syncthreads();
    for (int m = t; m < 512; m += 256)
#pragma unroll
      for (int q = 0; q < 4; ++q) buf[q][m] += tmp[q][m];
    __syncthreads();
  }
  float* tp = Tpref + mat * 2048;
  for (int m = t; m < 512; m += 256) {
    tp[m] = buf[0][m];
    tp[512 + m] = buf[1][m];
    tp[1024 + m] = buf[2][m];
    tp[1536 + m] = buf[3][m];
  }
}

// ---------------------------------------------------------------------------
// genops v2: K=513 (padded KOP=576) operands for the sea-GEMM.
// 2-pass variant: A single-bf16 (Ah), B split (Bh, Bl).
// ---------------------------------------------------------------------------
__global__ __launch_bounds__(256) void genops_kernel(
    const float* __restrict__ er, const float* __restrict__ dr,
    const float* __restrict__ ab,
    bf16* __restrict__ Ah, bf16* __restrict__ Bh, bf16* __restrict__ Bl) {
  const int x = blockIdx.x;            // 0..1023
  const int mat = blockIdx.y;          // 0..7
  const float* u = (mat < 4) ? (er + mat * H) : (dr + (mat - 4) * H);
  const float* b = ab + mat * 1024 + H;
  const int t = threadIdx.x;
  const size_t base = ((size_t)mat * 1024 + x) * KOP;
  for (int k = t; k < KOP; k += 256) {
    float av = 0.f, bv = 0.f;
    if (k <= 128) {
      const int o = 4 * k;
      const int ia = x - o;
      av = (ia >= 0 && ia < 512) ? b[ia] : 0.f;
      bv = (ia >= 0 && ia < 512) ? u[ia] : 0.f;
    } else if (k <= 256) {
      const int o = 4 * (k - 129) + 1;
      const int ia = 511 - x + o;
      const int ib = x - o;
      av = (ia >= 0 && ia < 512) ? u[ia] : 0.f;
      bv = (ib >= 0 && ib < 512) ? b[ib] : 0.f;
    } else if (k <= 384) {
      const int o = 4 * (k - 257) + 2;
      const int ia = 511 - x + o;
      av = (ia >= 0 && ia < 512) ? b[ia] : 0.f;
      bv = (ia >= 0 && ia < 512) ? u[ia] : 0.f;
    } else if (k <= 512) {
      const int o = 4 * (k - 385) + 3;
      const int ia = x - o;
      const int ib = 511 - x + o;
      av = (ia >= 0 && ia < 512) ? u[ia] : 0.f;
      bv = (ib >= 0 && ib < 512) ? b[ib] : 0.f;
    }
    Ah[base + k] = __float2bfloat16(av);
    const bf16 bh = __float2bfloat16(bv);
    Bh[base + k] = bh;
    Bl[base + k] = __float2bfloat16(bv - __bfloat162float(bh));
  }
}

// ---------------------------------------------------------------------------
// buildgemm v2: L[mat] = Aop @ Bop^T (2-pass: A single, B split) with
// a-part / diagonal terms fused in the epilogue.  128x128 tile, BK=64.
// ---------------------------------------------------------------------------
__global__ __launch_bounds__(256) void buildgemm_kernel(
    const bf16* __restrict__ Ah, const bf16* __restrict__ Bh,
    const bf16* __restrict__ Bl,
    const float* __restrict__ ed, const float* __restrict__ dd,
    const float* __restrict__ Tpref, bf16* __restrict__ Lbase) {
  __shared__ __align__(16) bf16 smem[3 * 8192];
  __shared__ float pa[512], parev[512], pd[512], pdrev[512], sdl[512];
  bf16* sAh = smem;
  bf16* sBh = smem + 8192;
  bf16* sBl = smem + 16384;

  const int tid = threadIdx.x;
  const int lane = tid & 63;
  const int wave = tid >> 6;
  const int wr = wave >> 1;
  const int wc = wave & 1;
  const int mat = blockIdx.z;
  const int row0 = blockIdx.x * 128;
  const int col0 = blockIdx.y * 128;

  {
    const float* tp = Tpref + mat * 2048;
    const float* d = (mat < 4) ? (ed + mat * H) : (dd + (mat - 4) * H);
    for (int m = tid; m < 512; m += 256) {
      pa[m] = tp[m];
      parev[m] = tp[512 + m];
      pd[m] = tp[1024 + m];
      pdrev[m] = tp[1536 + m];
      sdl[m] = d[m];
    }
  }

  const size_t OPS = (size_t)mat * 1024 * KOP;
  const int srow = tid >> 3;
  const int sce = (((tid * 16) ^ (((tid >> 3) & 7) << 4)) & 127) >> 1;
  const size_t abase = OPS + (size_t)(row0 + srow) * KOP + sce;
  const size_t bbase = OPS + (size_t)(col0 + srow) * KOP + sce;
  const int dst0 = tid * 8;

  f32x16 acc[2][2] = {};

  for (int kt = 0; kt < 9; ++kt) {
    const int k0 = kt * 64;
#pragma unroll
    for (int q = 0; q < 4; ++q) {
      const size_t ga = abase + (size_t)(32 * q) * KOP + k0;
      const size_t gb = bbase + (size_t)(32 * q) * KOP + k0;
      const int dq = q * 2048 + dst0;
      gload16(sAh + dq, Ah + ga);
      gload16(sBh + dq, Bh + gb);
      gload16(sBl + dq, Bl + gb);
    }
    __syncthreads();

    const int l31 = lane & 31;
    const int kh16 = (lane >> 5) * 16;
#pragma unroll
    for (int ks = 0; ks < 4; ++ks) {
      bf16x8 fah[2], fbh[2], fbl[2];
#pragma unroll
      for (int m = 0; m < 2; ++m) {
        const int arow = wr * 64 + m * 32 + l31;
        const int abk = (arow * 128 + ks * 32 + kh16) ^ ((arow & 7) << 4);
        fah[m] = *(const bf16x8*)((const char*)sAh + abk);
        const int brow = wc * 64 + m * 32 + l31;
        const int bbk = (brow * 128 + ks * 32 + kh16) ^ ((brow & 7) << 4);
        fbh[m] = *(const bf16x8*)((const char*)sBh + bbk);
        fbl[m] = *(const bf16x8*)((const char*)sBl + bbk);
      }
#pragma unroll
      for (int m = 0; m < 2; ++m)
#pragma unroll
        for (int n = 0; n < 2; ++n) {
          acc[m][n] = __builtin_amdgcn_mfma_f32_32x32x16_bf16(fah[m], fbh[n], acc[m][n], 0, 0, 0);
          acc[m][n] = __builtin_amdgcn_mfma_f32_32x32x16_bf16(fah[m], fbl[n], acc[m][n], 0, 0, 0);
        }
    }
    __syncthreads();
  }

  auto apart = [&](int i, int j) -> float {
    const int lo = max(0, max(i, j) - 511);
    const int hi = min(512, min(i, j));
    if (lo > hi) return 0.f;
    float v = 0.f;
    {
      int o1 = lo + ((0 - lo) & 3), o2 = hi - (hi & 3);
      if (o1 <= o2) { int mx = i - o1, mn = i - o2; v += pa[mx] - (mn >= 4 ? pa[mn - 4] : 0.f); }
    }
    {
      int o1 = lo + ((1 - lo) & 3), o2 = hi - ((hi - 1) & 3);
      if (o1 <= o2) { int mx = j - o1, mn = j - o2; v += pa[mx] - (mn >= 4 ? pa[mn - 4] : 0.f); }
    }
    {
      int o1 = lo + ((2 - lo) & 3), o2 = hi - ((hi - 2) & 3);
      if (o1 <= o2) { int mx = i - o1, mn = i - o2; v += parev[mx] - (mn >= 4 ? parev[mn - 4] : 0.f); }
    }
    {
      int o1 = lo + ((3 - lo) & 3), o2 = hi - ((hi - 3) & 3);
      if (o1 <= o2) { int mx = j - o1, mn = j - o2; v += parev[mx] - (mn >= 4 ? parev[mn - 4] : 0.f); }
    }
    if (i == j) {
      {
        int o1 = lo + ((0 - lo) & 3), o2 = hi - (hi & 3);
        if (o1 <= o2) { int mx = i - o1, mn = i - o2; v += pd[mx] - (mn >= 4 ? pd[mn - 4] : 0.f); }
      }
      {
        int o1 = lo + ((2 - lo) & 3), o2 = hi - ((hi - 2) & 3);
        if (o1 <= o2) { int mx = i - o1, mn = i - o2; v += pdrev[mx] - (mn >= 4 ? pdrev[mn - 4] : 0.f); }
      }
    }
    const int m2 = i + j - 511;
    if (m2 >= 0 && !(m2 & 1)) {
      const int os = m2 >> 1;
      if (os >= lo && os <= hi) {
        const int r = os & 3;
        if (r == 1) v += sdl[j - os];
        else if (r == 3) v += sdl[511 - (j - os)];
      }
    }
    return v;
  };

  const int ocol0 = col0 + wc * 64 + (lane & 31);
  const int rb = (lane >> 5) << 2;
#pragma unroll
  for (int m = 0; m < 2; ++m)
#pragma unroll
    for (int n = 0; n < 2; ++n)
#pragma unroll
      for (int r = 0; r < 16; ++r) {
        const int grow = row0 + wr * 64 + m * 32 + (r & 3) + ((r >> 2) << 3) + rb;
        const int gcol = ocol0 + n * 32;
        const float v = acc[m][n][r] + apart(grow, gcol);
        const size_t off = ((size_t)mat << 21) + ((size_t)grow << 10) + (size_t)gcol;
        const bf16 hb = __float2bfloat16(v);
        Lbase[off] = hb;
        Lbase[off + LM] = __float2bfloat16(v - __bfloat162float(hb));
      }
}

// ---------------------------------------------------------------------------
// split fp32 -> hi bf16 only
// ---------------------------------------------------------------------------
__global__ void splith_kernel(const float* __restrict__ x, bf16* __restrict__ h) {
  const int n4 = BATCH * NFEAT / 4;
  int idx = blockIdx.x * blockDim.x + threadIdx.x;
  int stride = gridDim.x * blockDim.x;
  for (int i = idx; i < n4; i += stride) {
    float4 v = ((const float4*)x)[i];
    union { bf16 b[4]; short4 s; } Hu;
    Hu.b[0] = __float2bfloat16(v.x);
    Hu.b[1] = __float2bfloat16(v.y);
    Hu.b[2] = __float2bfloat16(v.z);
    Hu.b[3] = __float2bfloat16(v.w);
    ((short4*)h)[i] = Hu.s;
  }
}

// ---------------------------------------------------------------------------
// batched single-array transpose: D = S^T for one 1024x1024 bf16 array per z.
// ---------------------------------------------------------------------------
struct TPtrs { const bf16* s; bf16* d; };
struct T6 { TPtrs t[6]; };

__global__ __launch_bounds__(256) void transposeB_kernel(T6 p) {
  const bf16* S = p.t[blockIdx.z].s;
  bf16* D = p.t[blockIdx.z].d;
  __shared__ ushort tile[64][68];
  const int i0 = blockIdx.x * 64, j0 = blockIdx.y * 64;
  const int tid = threadIdx.x;
  const int rr = tid >> 4;
  const int cc = (tid & 15) * 4;
#pragma unroll
  for (int it = 0; it < 4; ++it) {
    const int row = it * 16 + rr;
    const size_t so = (size_t)(i0 + row) * 1024 + j0 + cc;
    ushort4 v = *(const ushort4*)((const ushort*)S + so);
    tile[row][cc] = v.x; tile[row][cc + 1] = v.y;
    tile[row][cc + 2] = v.z; tile[row][cc + 3] = v.w;
  }
  __syncthreads();
#pragma unroll
  for (int it = 0; it < 4; ++it) {
    const int row = it * 16 + rr;
    ushort4 o;
    o.x = tile[cc][row];     o.y = tile[cc + 1][row];
    o.z = tile[cc + 2][row]; o.w = tile[cc + 3][row];
    const size_t dofs = (size_t)(j0 + row) * 1024 + i0 + cc;
    *(ushort4*)((ushort*)D + dofs) = o;
  }
}

// ---------------------------------------------------------------------------
// batched 2-pass chain GEMM v2 (ring-3 counted-wait, R15-gemmbig pattern):
// Y = A * B^T per z.  A single-bf16; B pair (lo at b+LM).  Output split.
// 64x64 tile, 4 waves, BK=64, ring of 3 LDS buffers; stage T+2 during T;
// one barrier per tile; vmcnt(6) (never 0 until tail).
// ---------------------------------------------------------------------------
struct GPtrs { const bf16* a; const bf16* b; bf16* yh; bf16* yl; };
struct G4 { GPtrs g[4]; };

__global__ __launch_bounds__(256) void chaingemm4_kernel(G4 p) {
  GPtrs q = p.g[blockIdx.z];
  const bf16* A = q.a;
  const bf16* Bh = q.b;
  const bf16* Bl = q.b + LM;

  __shared__ __align__(16) bf16 smem[3 * 12288];  // 72 KiB (3 ring bufs)

  const int tid = threadIdx.x;
  const int lane = tid & 63;
  const int wave = tid >> 6;
  const int wr = wave >> 1, wc = wave & 1;
  const int r0 = blockIdx.x * 64, c0 = blockIdx.y * 64;

  const int srow = tid >> 3;
  const int scol = (((tid & 7) ^ (srow & 7))) * 8;
  const int dst = tid * 8;
  const size_t ga0 = (size_t)(r0 + srow) * 1024 + scol;
  const size_t gb0 = (size_t)(c0 + srow) * 1024 + scol;

  auto STAGE = [&](int buf, int k0) {
    bf16* base = smem + buf * 12288;
    gload16(base + dst,        A + ga0 + k0);
    gload16(base + 2048 + dst, A + ga0 + 32 * 1024 + k0);
    gload16(base + 4096 + dst,        Bh + gb0 + k0);
    gload16(base + 4096 + 2048 + dst, Bh + gb0 + 32 * 1024 + k0);
    gload16(base + 8192 + dst,        Bl + gb0 + k0);
    gload16(base + 8192 + 2048 + dst, Bl + gb0 + 32 * 1024 + k0);
  };

  const int l31 = lane & 31;
  const int klg = lane >> 5;
  const int ar = wr * 32 + l31;
  const int br = wc * 32 + l31;
  int aoff[4], boff[4];
#pragma unroll
  for (int ks = 0; ks < 4; ++ks) {
    const int lgA = (ks << 1) | klg;
    aoff[ks] = ar * 64 + ((lgA ^ (ar & 7)) << 3);
    boff[ks] = br * 64 + ((lgA ^ (br & 7)) << 3);
  }

  f32x16 acc = {};

  STAGE(0, 0);
  STAGE(1, 64);
  asm volatile("s_waitcnt vmcnt(6)" ::: "memory");
  __builtin_amdgcn_s_barrier();

  for (int t = 0; t < 16; ++t) {
    const int buf = t % 3;
    if (t < 14) STAGE((t + 2) % 3, (t + 2) * 64);

    const bf16* pA = smem + buf * 12288;
    const bf16* pBh = pA + 4096;
    const bf16* pBl = pA + 8192;
#pragma unroll
    for (int ks = 0; ks < 4; ++ks) {
      bf16x8 ah = *(const bf16x8*)(pA + aoff[ks]);
      bf16x8 bh = *(const bf16x8*)(pBh + boff[ks]);
      bf16x8 bl = *(const bf16x8*)(pBl + boff[ks]);
      acc = __builtin_amdgcn_mfma_f32_32x32x16_bf16(ah, bh, acc, 0, 0, 0);
      acc = __builtin_amdgcn_mfma_f32_32x32x16_bf16(ah, bl, acc, 0, 0, 0);
    }
    if (t <= 13) {
      asm volatile("s_waitcnt vmcnt(6)" ::: "memory");
    } else if (t == 14) {
      asm volatile("s_waitcnt vmcnt(0)" ::: "memory");
    }
    __builtin_amdgcn_s_barrier();
  }

  const int oc = c0 + wc * 32 + l31;
  const int rb = (lane >> 5) << 2;
#pragma unroll
  for (int r = 0; r < 16; ++r) {
    const int gr = r0 + wr * 32 + (r & 3) + ((r >> 2) << 3) + rb;
    const size_t off = (size_t)gr * 1024 + oc;
    const float v = acc[r];
    const bf16 hb = __float2bfloat16(v);
    q.yh[off] = hb;
    q.yl[off] = __float2bfloat16(v - __bfloat162float(hb));
  }
}

// ---------------------------------------------------------------------------
// fused SINGLE-PASS big GEMM v4 (R15-validated, unchanged):
//   Y[r][c] = sum_k xh[r][k] * Mcat_h[c][k];  c<1024 -> O0, else O1.
// 256 threads (4 waves, 2Mx2N, wave 64x128), tile 128x256, BK=32,
// ring-3 LDS (72 KiB) -> 2 blocks/CU; counted vmcnt(6); 1 barrier/tile.
// ---------------------------------------------------------------------------
__global__ __launch_bounds__(256, 2) void gemmbig_kernel(
    const bf16* __restrict__ A, const bf16* __restrict__ Bh_,
    float* __restrict__ Y0, float* __restrict__ Y1) {
  __shared__ __align__(16) bf16 smem[3 * 12288];  // 72 KiB

  const int tid = threadIdx.x;
  const int lane = tid & 63;
  const int wave = tid >> 6;     // 0..3
  const int wr = wave >> 1;      // 0..1 : 64-row half
  const int wc = wave & 1;       // 0..1 : 128-col half

  const int pdisp = blockIdx.x;
  const int xcd = pdisp & 7;
  const int chk = pdisp >> 3;          // 0..127
  const int row0 = (xcd * 16 + (chk >> 3)) * 128;
  const int col0 = (chk & 7) * 256;

  const int sr = tid >> 2;                            // 0..63
  const int sc = ((tid & 3) ^ ((tid >> 3) & 3)) * 8;  // src col elem
  const size_t abase0 = (size_t)(row0 + sr) * NFEAT + sc;
  const size_t abase1 = abase0 + (size_t)64 * NFEAT;
  const size_t bbase = (size_t)(col0 + sr) * NFEAT + sc;
  const int dst = tid * 8;

  auto STAGE_A = [&](int buf, int k0) {
    bf16* base = smem + buf * 12288;
    gload16(base + dst, A + abase0 + k0);
    gload16(base + 2048 + dst, A + abase1 + k0);
  };
  auto STAGE_B = [&](int buf, int k0) {
    bf16* base = smem + buf * 12288 + 4096;
#pragma unroll
    for (int q = 0; q < 4; ++q)
      gload16(base + q * 2048 + dst, Bh_ + bbase + (size_t)(64 * q) * NFEAT + k0);
  };

  const int l15 = lane & 15;
  const int kcol = ((lane >> 4) * 16) ^ (((l15 >> 1) & 3) << 4);
  int aoff[4], boff[8];
#pragma unroll
  for (int fr = 0; fr < 4; ++fr)
    aoff[fr] = (wr * 64 + fr * 16 + l15) * 64 + kcol;
#pragma unroll
  for (int fc = 0; fc < 8; ++fc)
    boff[fc] = 8192 + (wc * 128 + fc * 16 + l15) * 64 + kcol;

  auto LD = [&](int buf, int off) {
    return *(const bf16x8*)((const char*)(smem + buf * 12288) + off);
  };

  f32x4 acc[4][8] = {};

  STAGE_A(0, 0); STAGE_B(0, 0);
  STAGE_A(1, 32); STAGE_B(1, 32);
  asm volatile("s_waitcnt vmcnt(6)" ::: "memory");
  __builtin_amdgcn_s_barrier();

  for (int T = 0; T < 32; ++T) {
    const int buf = T % 3;
    if (T < 30) {
      const int nb = (T + 2) % 3;
      STAGE_A(nb, (T + 2) * 32);
      STAGE_B(nb, (T + 2) * 32);
    }

    bf16x8 fa[4], fb[4];
#pragma unroll
    for (int fr = 0; fr < 4; ++fr) fa[fr] = LD(buf, aoff[fr]);
#pragma unroll
    for (int fc = 0; fc < 4; ++fc) fb[fc] = LD(buf, boff[fc]);
    __builtin_amdgcn_s_setprio(1);
#pragma unroll
    for (int fr = 0; fr < 4; ++fr)
#pragma unroll
      for (int fc = 0; fc < 4; ++fc)
        acc[fr][fc] = __builtin_amdgcn_mfma_f32_16x16x32_bf16(fa[fr], fb[fc], acc[fr][fc], 0, 0, 0);
    __builtin_amdgcn_s_setprio(0);
#pragma unroll
    for (int fc = 0; fc < 4; ++fc) fb[fc] = LD(buf, boff[4 + fc]);
    __builtin_amdgcn_s_setprio(1);
#pragma unroll
    for (int fr = 0; fr < 4; ++fr)
#pragma unroll
      for (int fc = 0; fc < 4; ++fc)
        acc[fr][4 + fc] = __builtin_amdgcn_mfma_f32_16x16x32_bf16(fa[fr], fb[fc], acc[fr][4 + fc], 0, 0, 0);
    __builtin_amdgcn_s_setprio(0);

    if (T <= 29) {
      asm volatile("s_waitcnt vmcnt(6)" ::: "memory");
    } else if (T == 30) {
      asm volatile("s_waitcnt vmcnt(0)" ::: "memory");
    }
    __builtin_amdgcn_s_barrier();
  }

  float* Yb = (col0 < 1024) ? Y0 : (Y1 - 1024);
  const int orow = row0 + wr * 64 + (lane >> 4) * 4;
  const int ocol = col0 + wc * 128 + l15;
#pragma unroll
  for (int fr = 0; fr < 4; ++fr)
#pragma unroll
    for (int fc = 0; fc < 8; ++fc)
#pragma unroll
      for (int r = 0; r < 4; ++r) {
        const int grow = orow + fr * 16 + r;
        const int gcol = ocol + fc * 16;
        Yb[(size_t)grow * NFEAT + (size_t)gcol] = acc[fr][fc][r];
      }
}

// ---------------------------------------------------------------------------
// launch
// ---------------------------------------------------------------------------
extern "C" void kernel_launch(void* const* d_in, const int* in_sizes, int n_in,
                              void* d_out, int out_size, void* d_ws, size_t ws_size,
                              hipStream_t stream) {
  (void)in_sizes; (void)n_in; (void)out_size; (void)ws_size;
  const float* x  = (const float*)d_in[0];
  const float* er = (const float*)d_in[1];
  const float* ed = (const float*)d_in[2];
  const float* dr = (const float*)d_in[3];
  const float* dd = (const float*)d_in[4];

  float* O0 = (float*)d_out;                       // bottleneck (fp32, 64 MB)
  float* O1 = O0 + (size_t)BATCH * NFEAT;          // out (fp32, 64 MB)

  // d_ws: L pairs [16 LM] (32MB) | ab (32KB) | Qh (32MB)
  bf16* Lb = (bf16*)d_ws;
  float* ab = (float*)(Lb + 16 * LM);
  bf16* Qh = (bf16*)(ab + 8 * 1024);

  // O0 scratch: Tpref @0 (64KB); 16 chain slots @1MB.
  float* Tpref = O0;
  bf16* SB = (bf16*)((char*)O0 + (1 << 20));
  auto slot = [&](int s) { return SB + (size_t)s * LM; };

  // O1 scratch (dead until gemmbig): sea-GEMM operands, 3 x 9.44MB.
  const size_t OPN = (size_t)8 * 1024 * KOP;
  bf16* Aoph = (bf16*)O1;
  bf16* Boph = Aoph + OPN;
  bf16* Bopl = Boph + OPN;

  prep_kernel<<<8, 64, 0, stream>>>(er, ed, dr, dd, ab);
  prep2_kernel<<<8, 256, 0, stream>>>(er, ed, dr, dd, ab, Tpref);
  genops_kernel<<<dim3(1024, 8), 256, 0, stream>>>(er, dr, ab, Aoph, Boph, Bopl);
  buildgemm_kernel<<<dim3(8, 8, 8), 256, 0, stream>>>(Aoph, Boph, Bopl,
                                                      ed, dd, Tpref, Lb);
  splith_kernel<<<4096, 256, 0, stream>>>(x, Qh);

  // ---- tree fold ----
  {
    T6 p;
    p.t[0] = {Lb + 0 * LM,  slot(0)};   // L1h -> s0  (T1e hi)
    p.t[1] = {Lb + 4 * LM,  slot(2)};   // L3h -> s2  (T2e hi)
    p.t[2] = {Lb + 5 * LM,  slot(3)};   // L3l -> s3  (T2e lo)
    p.t[3] = {Lb + 8 * LM,  slot(4)};   // L5h -> s4  (T1d hi)
    p.t[4] = {Lb + 12 * LM, slot(6)};   // L7h -> s6  (T2d hi)
    p.t[5] = {Lb + 13 * LM, slot(7)};   // L7l -> s7  (T2d lo)
    transposeB_kernel<<<dim3(16, 16, 6), 256, 0, stream>>>(p);
  }
  {
    G4 p;
    p.g[0] = {slot(0),      Lb + 2 * LM,  slot(8),  slot(9)};   // Q1e = T1e * L2^T
    p.g[1] = {Lb + 6 * LM,  slot(2),      slot(10), slot(11)};  // Q2te = L4 * T2e^T
    p.g[2] = {slot(4),      Lb + 10 * LM, slot(12), slot(13)};  // Q1d = T1d * L6^T
    p.g[3] = {Lb + 14 * LM, slot(6),      slot(14), slot(15)};  // Q2td = L8 * T2d^T
    chaingemm4_kernel<<<dim3(16, 16, 4), 256, 0, stream>>>(p);
  }
  {
    G4 p;
    p.g[0] = {slot(8),  slot(10), slot(0), slot(1)};   // Kce = Menc^T
    p.g[1] = {slot(12), slot(14), slot(2), slot(3)};   // Kcd = Mdec^T
    p.g[2] = p.g[0];
    p.g[3] = p.g[1];
    chaingemm4_kernel<<<dim3(16, 16, 2), 256, 0, stream>>>(p);
  }
  {
    T6 p;
    p.t[0] = {slot(0), Lb + 0 * LM};    // Menc -> Mcat rows 0-1023
    p.t[1] = {slot(2), Lb + 2 * LM};    // Mdec
    p.t[2] = p.t[0]; p.t[3] = p.t[0]; p.t[4] = p.t[0]; p.t[5] = p.t[0];
    transposeB_kernel<<<dim3(16, 16, 2), 256, 0, stream>>>(p);
  }
  {
    G4 p;
    p.g[0] = {Lb + 2 * LM, slot(0), Lb + 1 * LM, slot(4)};  // Mtot -> Mcat rows 1024+
    p.g[1] = p.g[0]; p.g[2] = p.g[0]; p.g[3] = p.g[0];
    chaingemm4_kernel<<<dim3(16, 16, 1), 256, 0, stream>>>(p);
  }

  // fused single-pass big GEMM: both outputs from x in one dispatch.
  gemmbig_kernel<<<1024, 256, 0, stream>>>(Qh, Lb, O0, O1);
}

// Round 17
// 237.707 us; speedup vs baseline: 3.8820x; 1.0360x over previous
//
#include <hip/hip_runtime.h>
#include <hip/hip_bf16.h>
#include <cstdint>
#include <cstddef>

#define H 512
#define NFEAT 1024
#define BATCH 16384
#define LM ((size_t)1 << 20)   // elems per 1024x1024 matrix
#define KOP 576                // padded K for the build GEMM (513 used)

using bf16 = __hip_bfloat16;
using bf16x8 = __attribute__((ext_vector_type(8))) __bf16;
using f32x4 = __attribute__((ext_vector_type(4))) float;
using f32x16 = __attribute__((ext_vector_type(16))) float;

// ---------------------------------------------------------------------------
// async global -> LDS, 16 bytes per lane
// ---------------------------------------------------------------------------
__device__ __forceinline__ void gload16(void* lds, const void* g) {
  __builtin_amdgcn_global_load_lds(
      (__attribute__((address_space(1))) void*)g,
      (__attribute__((address_space(3))) void*)lds,
      16, 0, 0);
}

// ---------------------------------------------------------------------------
// prepfused: per matrix (1 block/mat, 256 thr):
//  (a) Cayley closed form -> a[], b[]  (R0-validated math, LDS double reduce)
//  (b) stride-4-residue prefix tables over a, a_rev, d, d_rev (R2-validated)
// ---------------------------------------------------------------------------
__global__ __launch_bounds__(256) void prepfused_kernel(
    const float* __restrict__ er, const float* __restrict__ ed,
    const float* __restrict__ dr, const float* __restrict__ dd,
    float* __restrict__ ab, float* __restrict__ Tpref) {
  __shared__ double sred[256], qred[256];
  __shared__ float sa[512];
  __shared__ float buf[4][512];
  __shared__ float tmp[4][512];

  const int mat = blockIdx.x;
  const int t = threadIdx.x;
  const float* u = (mat < 4) ? (er + mat * H) : (dr + (mat - 4) * H);
  const float* d = (mat < 4) ? (ed + mat * H) : (dd + (mat - 4) * H);

  // ---- (a) reduction: s = sum(u), q = sum(u^2), in double ----
  {
    const double v0 = (double)u[t];
    const double v1 = (double)u[t + 256];
    sred[t] = v0 + v1;
    qred[t] = v0 * v0 + v1 * v1;
  }
  __syncthreads();
  for (int off = 128; off; off >>= 1) {
    if (t < off) {
      sred[t] += sred[t + off];
      qred[t] += qred[t + off];
    }
    __syncthreads();
  }
  const double s = sred[0];
  const double q = qred[0];
  const double det = 1.0 - s * s + (double)H * q;
  const double cuv = 2.0 * (1.0 + s) / det;
  const double cuu = -2.0 * (double)H / det;
  const double cvv = -2.0 * q / det;
  const double cvu = -2.0 * (1.0 - s) / det;

  float* a = ab + mat * 1024;
  float* b = a + H;
#pragma unroll
  for (int h = 0; h < 2; ++h) {
    const int idx = t + 256 * h;
    const double ui = (double)u[idx], di = (double)d[idx];
    const float av = (float)(di * (cuv * ui + cvv));
    const float bv = (float)(di * (cuu * ui + cvu));
    a[idx] = av;
    b[idx] = bv;
    sa[idx] = av;
  }
  __syncthreads();

  // ---- (b) prefix tables ----
  for (int m = t; m < 512; m += 256) {
    buf[0][m] = sa[m];
    buf[1][m] = sa[511 - m];
    buf[2][m] = d[m];
    buf[3][m] = d[511 - m];
  }
  __syncthreads();
  for (int st = 4; st <= 256; st <<= 1) {
    for (int m = t; m < 512; m += 256)
#pragma unroll
      for (int qq = 0; qq < 4; ++qq) tmp[qq][m] = (m >= st) ? buf[qq][m - st] : 0.f;
    __syncthreads();
    for (int m = t; m < 512; m += 256)
#pragma unroll
      for (int qq = 0; qq < 4; ++qq) buf[qq][m] += tmp[qq][m];
    __syncthreads();
  }
  float* tp = Tpref + mat * 2048;
  for (int m = t; m < 512; m += 256) {
    tp[m] = buf[0][m];
    tp[512 + m] = buf[1][m];
    tp[1024 + m] = buf[2][m];
    tp[1536 + m] = buf[3][m];
  }
}

// ---------------------------------------------------------------------------
// genops v3: sea-GEMM operands (A single-bf16, B split) + fused splith tail
// (x fp32 -> Qh bf16, grid-stride across the whole launch).
// ---------------------------------------------------------------------------
__global__ __launch_bounds__(256) void genops_kernel(
    const float* __restrict__ er, const float* __restrict__ dr,
    const float* __restrict__ ab,
    bf16* __restrict__ Ah, bf16* __restrict__ Bh, bf16* __restrict__ Bl,
    const float* __restrict__ x, bf16* __restrict__ Qh) {
  const int xr = blockIdx.x;           // 0..1023
  const int mat = blockIdx.y;          // 0..7
  const float* u = (mat < 4) ? (er + mat * H) : (dr + (mat - 4) * H);
  const float* b = ab + mat * 1024 + H;
  const int t = threadIdx.x;
  const size_t base = ((size_t)mat * 1024 + xr) * KOP;
  for (int k = t; k < KOP; k += 256) {
    float av = 0.f, bv = 0.f;
    if (k <= 128) {
      const int o = 4 * k;
      const int ia = xr - o;
      av = (ia >= 0 && ia < 512) ? b[ia] : 0.f;
      bv = (ia >= 0 && ia < 512) ? u[ia] : 0.f;
    } else if (k <= 256) {
      const int o = 4 * (k - 129) + 1;
      const int ia = 511 - xr + o;
      const int ib = xr - o;
      av = (ia >= 0 && ia < 512) ? u[ia] : 0.f;
      bv = (ib >= 0 && ib < 512) ? b[ib] : 0.f;
    } else if (k <= 384) {
      const int o = 4 * (k - 257) + 2;
      const int ia = 511 - xr + o;
      av = (ia >= 0 && ia < 512) ? b[ia] : 0.f;
      bv = (ia >= 0 && ia < 512) ? u[ia] : 0.f;
    } else if (k <= 512) {
      const int o = 4 * (k - 385) + 3;
      const int ia = xr - o;
      const int ib = 511 - xr + o;
      av = (ia >= 0 && ia < 512) ? u[ia] : 0.f;
      bv = (ib >= 0 && ib < 512) ? b[ib] : 0.f;
    }
    Ah[base + k] = __float2bfloat16(av);
    const bf16 bh = __float2bfloat16(bv);
    Bh[base + k] = bh;
    Bl[base + k] = __float2bfloat16(bv - __bfloat162float(bh));
  }

  // ---- fused splith: 8192 blocks x 256 threads, 2 float4 each ----
  const int n4 = BATCH * NFEAT / 4;
  const int gidx = (mat * 1024 + xr) * 256 + t;
  for (int i = gidx; i < n4; i += 8192 * 256) {
    float4 v = ((const float4*)x)[i];
    union { bf16 bb[4]; short4 sv; } Hu;
    Hu.bb[0] = __float2bfloat16(v.x);
    Hu.bb[1] = __float2bfloat16(v.y);
    Hu.bb[2] = __float2bfloat16(v.z);
    Hu.bb[3] = __float2bfloat16(v.w);
    ((short4*)Qh)[i] = Hu.sv;
  }
}

// ---------------------------------------------------------------------------
// buildgemm v2 (R16-validated): L[mat] = Aop @ Bop^T (2-pass) with
// a-part / diagonal terms fused in the epilogue.  128x128 tile, BK=64.
// ---------------------------------------------------------------------------
__global__ __launch_bounds__(256) void buildgemm_kernel(
    const bf16* __restrict__ Ah, const bf16* __restrict__ Bh,
    const bf16* __restrict__ Bl,
    const float* __restrict__ ed, const float* __restrict__ dd,
    const float* __restrict__ Tpref, bf16* __restrict__ Lbase) {
  __shared__ __align__(16) bf16 smem[3 * 8192];
  __shared__ float pa[512], parev[512], pd[512], pdrev[512], sdl[512];
  bf16* sAh = smem;
  bf16* sBh = smem + 8192;
  bf16* sBl = smem + 16384;

  const int tid = threadIdx.x;
  const int lane = tid & 63;
  const int wave = tid >> 6;
  const int wr = wave >> 1;
  const int wc = wave & 1;
  const int mat = blockIdx.z;
  const int row0 = blockIdx.x * 128;
  const int col0 = blockIdx.y * 128;

  {
    const float* tp = Tpref + mat * 2048;
    const float* d = (mat < 4) ? (ed + mat * H) : (dd + (mat - 4) * H);
    for (int m = tid; m < 512; m += 256) {
      pa[m] = tp[m];
      parev[m] = tp[512 + m];
      pd[m] = tp[1024 + m];
      pdrev[m] = tp[1536 + m];
      sdl[m] = d[m];
    }
  }

  const size_t OPS = (size_t)mat * 1024 * KOP;
  const int srow = tid >> 3;
  const int sce = (((tid * 16) ^ (((tid >> 3) & 7) << 4)) & 127) >> 1;
  const size_t abase = OPS + (size_t)(row0 + srow) * KOP + sce;
  const size_t bbase = OPS + (size_t)(col0 + srow) * KOP + sce;
  const int dst0 = tid * 8;

  f32x16 acc[2][2] = {};

  for (int kt = 0; kt < 9; ++kt) {
    const int k0 = kt * 64;
#pragma unroll
    for (int q = 0; q < 4; ++q) {
      const size_t ga = abase + (size_t)(32 * q) * KOP + k0;
      const size_t gb = bbase + (size_t)(32 * q) * KOP + k0;
      const int dq = q * 2048 + dst0;
      gload16(sAh + dq, Ah + ga);
      gload16(sBh + dq, Bh + gb);
      gload16(sBl + dq, Bl + gb);
    }
    __syncthreads();

    const int l31 = lane & 31;
    const int kh16 = (lane >> 5) * 16;
#pragma unroll
    for (int ks = 0; ks < 4; ++ks) {
      bf16x8 fah[2], fbh[2], fbl[2];
#pragma unroll
      for (int m = 0; m < 2; ++m) {
        const int arow = wr * 64 + m * 32 + l31;
        const int abk = (arow * 128 + ks * 32 + kh16) ^ ((arow & 7) << 4);
        fah[m] = *(const bf16x8*)((const char*)sAh + abk);
        const int brow = wc * 64 + m * 32 + l31;
        const int bbk = (brow * 128 + ks * 32 + kh16) ^ ((brow & 7) << 4);
        fbh[m] = *(const bf16x8*)((const char*)sBh + bbk);
        fbl[m] = *(const bf16x8*)((const char*)sBl + bbk);
      }
#pragma unroll
      for (int m = 0; m < 2; ++m)
#pragma unroll
        for (int n = 0; n < 2; ++n) {
          acc[m][n] = __builtin_amdgcn_mfma_f32_32x32x16_bf16(fah[m], fbh[n], acc[m][n], 0, 0, 0);
          acc[m][n] = __builtin_amdgcn_mfma_f32_32x32x16_bf16(fah[m], fbl[n], acc[m][n], 0, 0, 0);
        }
    }
    __syncthreads();
  }

  auto apart = [&](int i, int j) -> float {
    const int lo = max(0, max(i, j) - 511);
    const int hi = min(512, min(i, j));
    if (lo > hi) return 0.f;
    float v = 0.f;
    {
      int o1 = lo + ((0 - lo) & 3), o2 = hi - (hi & 3);
      if (o1 <= o2) { int mx = i - o1, mn = i - o2; v += pa[mx] - (mn >= 4 ? pa[mn - 4] : 0.f); }
    }
    {
      int o1 = lo + ((1 - lo) & 3), o2 = hi - ((hi - 1) & 3);
      if (o1 <= o2) { int mx = j - o1, mn = j - o2; v += pa[mx] - (mn >= 4 ? pa[mn - 4] : 0.f); }
    }
    {
      int o1 = lo + ((2 - lo) & 3), o2 = hi - ((hi - 2) & 3);
      if (o1 <= o2) { int mx = i - o1, mn = i - o2; v += parev[mx] - (mn >= 4 ? parev[mn - 4] : 0.f); }
    }
    {
      int o1 = lo + ((3 - lo) & 3), o2 = hi - ((hi - 3) & 3);
      if (o1 <= o2) { int mx = j - o1, mn = j - o2; v += parev[mx] - (mn >= 4 ? parev[mn - 4] : 0.f); }
    }
    if (i == j) {
      {
        int o1 = lo + ((0 - lo) & 3), o2 = hi - (hi & 3);
        if (o1 <= o2) { int mx = i - o1, mn = i - o2; v += pd[mx] - (mn >= 4 ? pd[mn - 4] : 0.f); }
      }
      {
        int o1 = lo + ((2 - lo) & 3), o2 = hi - ((hi - 2) & 3);
        if (o1 <= o2) { int mx = i - o1, mn = i - o2; v += pdrev[mx] - (mn >= 4 ? pdrev[mn - 4] : 0.f); }
      }
    }
    const int m2 = i + j - 511;
    if (m2 >= 0 && !(m2 & 1)) {
      const int os = m2 >> 1;
      if (os >= lo && os <= hi) {
        const int r = os & 3;
        if (r == 1) v += sdl[j - os];
        else if (r == 3) v += sdl[511 - (j - os)];
      }
    }
    return v;
  };

  const int ocol0 = col0 + wc * 64 + (lane & 31);
  const int rb = (lane >> 5) << 2;
#pragma unroll
  for (int m = 0; m < 2; ++m)
#pragma unroll
    for (int n = 0; n < 2; ++n)
#pragma unroll
      for (int r = 0; r < 16; ++r) {
        const int grow = row0 + wr * 64 + m * 32 + (r & 3) + ((r >> 2) << 3) + rb;
        const int gcol = ocol0 + n * 32;
        const float v = acc[m][n][r] + apart(grow, gcol);
        const size_t off = ((size_t)mat << 21) + ((size_t)grow << 10) + (size_t)gcol;
        const bf16 hb = __float2bfloat16(v);
        Lbase[off] = hb;
        Lbase[off + LM] = __float2bfloat16(v - __bfloat162float(hb));
      }
}

// ---------------------------------------------------------------------------
// batched single-array transpose: D = S^T for one 1024x1024 bf16 array per z.
// ---------------------------------------------------------------------------
struct TPtrs { const bf16* s; bf16* d; };
struct T6 { TPtrs t[6]; };

__global__ __launch_bounds__(256) void transposeB_kernel(T6 p) {
  const bf16* S = p.t[blockIdx.z].s;
  bf16* D = p.t[blockIdx.z].d;
  __shared__ ushort tile[64][68];
  const int i0 = blockIdx.x * 64, j0 = blockIdx.y * 64;
  const int tid = threadIdx.x;
  const int rr = tid >> 4;
  const int cc = (tid & 15) * 4;
#pragma unroll
  for (int it = 0; it < 4; ++it) {
    const int row = it * 16 + rr;
    const size_t so = (size_t)(i0 + row) * 1024 + j0 + cc;
    ushort4 v = *(const ushort4*)((const ushort*)S + so);
    tile[row][cc] = v.x; tile[row][cc + 1] = v.y;
    tile[row][cc + 2] = v.z; tile[row][cc + 3] = v.w;
  }
  __syncthreads();
#pragma unroll
  for (int it = 0; it < 4; ++it) {
    const int row = it * 16 + rr;
    ushort4 o;
    o.x = tile[cc][row];     o.y = tile[cc + 1][row];
    o.z = tile[cc + 2][row]; o.w = tile[cc + 3][row];
    const size_t dofs = (size_t)(j0 + row) * 1024 + i0 + cc;
    *(ushort4*)((ushort*)D + dofs) = o;
  }
}

// ---------------------------------------------------------------------------
// batched 2-pass chain GEMM v2 (R16-validated ring-3 counted-wait):
// Y = A * B^T per z.  A single-bf16; B pair (lo at b+LM).  Output split.
// ---------------------------------------------------------------------------
struct GPtrs { const bf16* a; const bf16* b; bf16* yh; bf16* yl; };
struct G4 { GPtrs g[4]; };

__global__ __launch_bounds__(256) void chaingemm4_kernel(G4 p) {
  GPtrs q = p.g[blockIdx.z];
  const bf16* A = q.a;
  const bf16* Bh = q.b;
  const bf16* Bl = q.b + LM;

  __shared__ __align__(16) bf16 smem[3 * 12288];  // 72 KiB (3 ring bufs)

  const int tid = threadIdx.x;
  const int lane = tid & 63;
  const int wave = tid >> 6;
  const int wr = wave >> 1, wc = wave & 1;
  const int r0 = blockIdx.x * 64, c0 = blockIdx.y * 64;

  const int srow = tid >> 3;
  const int scol = (((tid & 7) ^ (srow & 7))) * 8;
  const int dst = tid * 8;
  const size_t ga0 = (size_t)(r0 + srow) * 1024 + scol;
  const size_t gb0 = (size_t)(c0 + srow) * 1024 + scol;

  auto STAGE = [&](int buf, int k0) {
    bf16* base = smem + buf * 12288;
    gload16(base + dst,        A + ga0 + k0);
    gload16(base + 2048 + dst, A + ga0 + 32 * 1024 + k0);
    gload16(base + 4096 + dst,        Bh + gb0 + k0);
    gload16(base + 4096 + 2048 + dst, Bh + gb0 + 32 * 1024 + k0);
    gload16(base + 8192 + dst,        Bl + gb0 + k0);
    gload16(base + 8192 + 2048 + dst, Bl + gb0 + 32 * 1024 + k0);
  };

  const int l31 = lane & 31;
  const int klg = lane >> 5;
  const int ar = wr * 32 + l31;
  const int br = wc * 32 + l31;
  int aoff[4], boff[4];
#pragma unroll
  for (int ks = 0; ks < 4; ++ks) {
    const int lgA = (ks << 1) | klg;
    aoff[ks] = ar * 64 + ((lgA ^ (ar & 7)) << 3);
    boff[ks] = br * 64 + ((lgA ^ (br & 7)) << 3);
  }

  f32x16 acc = {};

  STAGE(0, 0);
  STAGE(1, 64);
  asm volatile("s_waitcnt vmcnt(6)" ::: "memory");
  __builtin_amdgcn_s_barrier();

  for (int t = 0; t < 16; ++t) {
    const int buf = t % 3;
    if (t < 14) STAGE((t + 2) % 3, (t + 2) * 64);

    const bf16* pA = smem + buf * 12288;
    const bf16* pBh = pA + 4096;
    const bf16* pBl = pA + 8192;
#pragma unroll
    for (int ks = 0; ks < 4; ++ks) {
      bf16x8 ah = *(const bf16x8*)(pA + aoff[ks]);
      bf16x8 bh = *(const bf16x8*)(pBh + boff[ks]);
      bf16x8 bl = *(const bf16x8*)(pBl + boff[ks]);
      acc = __builtin_amdgcn_mfma_f32_32x32x16_bf16(ah, bh, acc, 0, 0, 0);
      acc = __builtin_amdgcn_mfma_f32_32x32x16_bf16(ah, bl, acc, 0, 0, 0);
    }
    if (t <= 13) {
      asm volatile("s_waitcnt vmcnt(6)" ::: "memory");
    } else if (t == 14) {
      asm volatile("s_waitcnt vmcnt(0)" ::: "memory");
    }
    __builtin_amdgcn_s_barrier();
  }

  const int oc = c0 + wc * 32 + l31;
  const int rb = (lane >> 5) << 2;
#pragma unroll
  for (int r = 0; r < 16; ++r) {
    const int gr = r0 + wr * 32 + (r & 3) + ((r >> 2) << 3) + rb;
    const size_t off = (size_t)gr * 1024 + oc;
    const float v = acc[r];
    const bf16 hb = __float2bfloat16(v);
    q.yh[off] = hb;
    q.yl[off] = __float2bfloat16(v - __bfloat162float(hb));
  }
}

// ---------------------------------------------------------------------------
// fused SINGLE-PASS big GEMM v4 (R15/R16-validated, unchanged):
//   Y[r][c] = sum_k xh[r][k] * Mcat_h[c][k];  c<1024 -> O0, else O1.
// ---------------------------------------------------------------------------
__global__ __launch_bounds__(256, 2) void gemmbig_kernel(
    const bf16* __restrict__ A, const bf16* __restrict__ Bh_,
    float* __restrict__ Y0, float* __restrict__ Y1) {
  __shared__ __align__(16) bf16 smem[3 * 12288];  // 72 KiB

  const int tid = threadIdx.x;
  const int lane = tid & 63;
  const int wave = tid >> 6;
  const int wr = wave >> 1;
  const int wc = wave & 1;

  const int pdisp = blockIdx.x;
  const int xcd = pdisp & 7;
  const int chk = pdisp >> 3;
  const int row0 = (xcd * 16 + (chk >> 3)) * 128;
  const int col0 = (chk & 7) * 256;

  const int sr = tid >> 2;
  const int sc = ((tid & 3) ^ ((tid >> 3) & 3)) * 8;
  const size_t abase0 = (size_t)(row0 + sr) * NFEAT + sc;
  const size_t abase1 = abase0 + (size_t)64 * NFEAT;
  const size_t bbase = (size_t)(col0 + sr) * NFEAT + sc;
  const int dst = tid * 8;

  auto STAGE_A = [&](int buf, int k0) {
    bf16* base = smem + buf * 12288;
    gload16(base + dst, A + abase0 + k0);
    gload16(base + 2048 + dst, A + abase1 + k0);
  };
  auto STAGE_B = [&](int buf, int k0) {
    bf16* base = smem + buf * 12288 + 4096;
#pragma unroll
    for (int q = 0; q < 4; ++q)
      gload16(base + q * 2048 + dst, Bh_ + bbase + (size_t)(64 * q) * NFEAT + k0);
  };

  const int l15 = lane & 15;
  const int kcol = ((lane >> 4) * 16) ^ (((l15 >> 1) & 3) << 4);
  int aoff[4], boff[8];
#pragma unroll
  for (int fr = 0; fr < 4; ++fr)
    aoff[fr] = (wr * 64 + fr * 16 + l15) * 64 + kcol;
#pragma unroll
  for (int fc = 0; fc < 8; ++fc)
    boff[fc] = 8192 + (wc * 128 + fc * 16 + l15) * 64 + kcol;

  auto LD = [&](int buf, int off) {
    return *(const bf16x8*)((const char*)(smem + buf * 12288) + off);
  };

  f32x4 acc[4][8] = {};

  STAGE_A(0, 0); STAGE_B(0, 0);
  STAGE_A(1, 32); STAGE_B(1, 32);
  asm volatile("s_waitcnt vmcnt(6)" ::: "memory");
  __builtin_amdgcn_s_barrier();

  for (int T = 0; T < 32; ++T) {
    const int buf = T % 3;
    if (T < 30) {
      const int nb = (T + 2) % 3;
      STAGE_A(nb, (T + 2) * 32);
      STAGE_B(nb, (T + 2) * 32);
    }

    bf16x8 fa[4], fb[4];
#pragma unroll
    for (int fr = 0; fr < 4; ++fr) fa[fr] = LD(buf, aoff[fr]);
#pragma unroll
    for (int fc = 0; fc < 4; ++fc) fb[fc] = LD(buf, boff[fc]);
    __builtin_amdgcn_s_setprio(1);
#pragma unroll
    for (int fr = 0; fr < 4; ++fr)
#pragma unroll
      for (int fc = 0; fc < 4; ++fc)
        acc[fr][fc] = __builtin_amdgcn_mfma_f32_16x16x32_bf16(fa[fr], fb[fc], acc[fr][fc], 0, 0, 0);
    __builtin_amdgcn_s_setprio(0);
#pragma unroll
    for (int fc = 0; fc < 4; ++fc) fb[fc] = LD(buf, boff[4 + fc]);
    __builtin_amdgcn_s_setprio(1);
#pragma unroll
    for (int fr = 0; fr < 4; ++fr)
#pragma unroll
      for (int fc = 0; fc < 4; ++fc)
        acc[fr][4 + fc] = __builtin_amdgcn_mfma_f32_16x16x32_bf16(fa[fr], fb[fc], acc[fr][4 + fc], 0, 0, 0);
    __builtin_amdgcn_s_setprio(0);

    if (T <= 29) {
      asm volatile("s_waitcnt vmcnt(6)" ::: "memory");
    } else if (T == 30) {
      asm volatile("s_waitcnt vmcnt(0)" ::: "memory");
    }
    __builtin_amdgcn_s_barrier();
  }

  float* Yb = (col0 < 1024) ? Y0 : (Y1 - 1024);
  const int orow = row0 + wr * 64 + (lane >> 4) * 4;
  const int ocol = col0 + wc * 128 + l15;
#pragma unroll
  for (int fr = 0; fr < 4; ++fr)
#pragma unroll
    for (int fc = 0; fc < 8; ++fc)
#pragma unroll
      for (int r = 0; r < 4; ++r) {
        const int grow = orow + fr * 16 + r;
        const int gcol = ocol + fc * 16;
        Yb[(size_t)grow * NFEAT + (size_t)gcol] = acc[fr][fc][r];
      }
}

// ---------------------------------------------------------------------------
// launch
// ---------------------------------------------------------------------------
extern "C" void kernel_launch(void* const* d_in, const int* in_sizes, int n_in,
                              void* d_out, int out_size, void* d_ws, size_t ws_size,
                              hipStream_t stream) {
  (void)in_sizes; (void)n_in; (void)out_size; (void)ws_size;
  const float* x  = (const float*)d_in[0];
  const float* er = (const float*)d_in[1];
  const float* ed = (const float*)d_in[2];
  const float* dr = (const float*)d_in[3];
  const float* dd = (const float*)d_in[4];

  float* O0 = (float*)d_out;                       // bottleneck (fp32, 64 MB)
  float* O1 = O0 + (size_t)BATCH * NFEAT;          // out (fp32, 64 MB)

  // d_ws: L pairs [16 LM] (32MB) | ab (32KB) | Qh (32MB)
  bf16* Lb = (bf16*)d_ws;
  float* ab = (float*)(Lb + 16 * LM);
  bf16* Qh = (bf16*)(ab + 8 * 1024);

  // O0 scratch: Tpref @0 (64KB); 16 chain slots @1MB.
  float* Tpref = O0;
  bf16* SB = (bf16*)((char*)O0 + (1 << 20));
  auto slot = [&](int s) { return SB + (size_t)s * LM; };

  // O1 scratch (dead until gemmbig): sea-GEMM operands, 3 x 9.44MB.
  const size_t OPN = (size_t)8 * 1024 * KOP;
  bf16* Aoph = (bf16*)O1;
  bf16* Boph = Aoph + OPN;
  bf16* Bopl = Boph + OPN;

  prepfused_kernel<<<8, 256, 0, stream>>>(er, ed, dr, dd, ab, Tpref);
  genops_kernel<<<dim3(1024, 8), 256, 0, stream>>>(er, dr, ab, Aoph, Boph, Bopl, x, Qh);
  buildgemm_kernel<<<dim3(8, 8, 8), 256, 0, stream>>>(Aoph, Boph, Bopl,
                                                      ed, dd, Tpref, Lb);

  // ---- tree fold ----
  {
    T6 p;
    p.t[0] = {Lb + 0 * LM,  slot(0)};   // L1h -> s0  (T1e hi)
    p.t[1] = {Lb + 4 * LM,  slot(2)};   // L3h -> s2  (T2e hi)
    p.t[2] = {Lb + 5 * LM,  slot(3)};   // L3l -> s3  (T2e lo)
    p.t[3] = {Lb + 8 * LM,  slot(4)};   // L5h -> s4  (T1d hi)
    p.t[4] = {Lb + 12 * LM, slot(6)};   // L7h -> s6  (T2d hi)
    p.t[5] = {Lb + 13 * LM, slot(7)};   // L7l -> s7  (T2d lo)
    transposeB_kernel<<<dim3(16, 16, 6), 256, 0, stream>>>(p);
  }
  {
    G4 p;
    p.g[0] = {slot(0),      Lb + 2 * LM,  slot(8),  slot(9)};   // Q1e = T1e * L2^T
    p.g[1] = {Lb + 6 * LM,  slot(2),      slot(10), slot(11)};  // Q2te = L4 * T2e^T
    p.g[2] = {slot(4),      Lb + 10 * LM, slot(12), slot(13)};  // Q1d = T1d * L6^T
    p.g[3] = {Lb + 14 * LM, slot(6),      slot(14), slot(15)};  // Q2td = L8 * T2d^T
    chaingemm4_kernel<<<dim3(16, 16, 4), 256, 0, stream>>>(p);
  }
  {
    G4 p;
    p.g[0] = {slot(8),  slot(10), slot(0), slot(1)};   // Kce = Menc^T
    p.g[1] = {slot(12), slot(14), slot(2), slot(3)};   // Kcd = Mdec^T
    p.g[2] = p.g[0];
    p.g[3] = p.g[1];
    chaingemm4_kernel<<<dim3(16, 16, 2), 256, 0, stream>>>(p);
  }
  {
    T6 p;
    p.t[0] = {slot(0), Lb + 0 * LM};    // Menc -> Mcat rows 0-1023
    p.t[1] = {slot(2), Lb + 2 * LM};    // Mdec
    p.t[2] = p.t[0]; p.t[3] = p.t[0]; p.t[4] = p.t[0]; p.t[5] = p.t[0];
    transposeB_kernel<<<dim3(16, 16, 2), 256, 0, stream>>>(p);
  }
  {
    G4 p;
    p.g[0] = {Lb + 2 * LM, slot(0), Lb + 1 * LM, slot(4)};  // Mtot -> Mcat rows 1024+
    p.g[1] = p.g[0]; p.g[2] = p.g[0]; p.g[3] = p.g[0];
    chaingemm4_kernel<<<dim3(16, 16, 1), 256, 0, stream>>>(p);
  }

  // fused single-pass big GEMM: both outputs from x in one dispatch.
  gemmbig_kernel<<<1024, 256, 0, stream>>>(Qh, Lb, O0, O1);
}